// Round 3
// baseline (625.933 us; speedup 1.0000x reference)
//
#include <hip/hip_runtime.h>
#include <hip/hip_bf16.h>
#include <math.h>

// Problem constants (from reference)
#define B_    2
#define S_    2048
#define DIM_  2048
#define H_    16
#define NOPE_ 128
#define ROPE_ 64
#define VDIM_ 128
#define QR_   1024
#define KVR_  512
#define TOK_  (B_ * S_)   // 4096 token rows

typedef __attribute__((ext_vector_type(8))) short short8;   // 8 bf16 (4 VGPRs)
typedef __attribute__((ext_vector_type(4))) float f32x4;    // MFMA acc

// fp32 -> bf16 (round-to-nearest-even), raw ushort
__device__ __forceinline__ unsigned short f2bf(float f) {
  union { float f; unsigned u; } v; v.f = f;
  unsigned r = v.u + 0x7fffu + ((v.u >> 16) & 1u);
  return (unsigned short)(r >> 16);
}
__device__ __forceinline__ unsigned pk2(float lo, float hi) {
  return (unsigned)f2bf(lo) | ((unsigned)f2bf(hi) << 16);
}

// async global->LDS, 16 B per lane; dest = wave-uniform base + lane*16.
__device__ __forceinline__ void gl_lds16(const unsigned short* g, unsigned short* lds_base) {
  __builtin_amdgcn_global_load_lds(
      (const __attribute__((address_space(1))) void*)g,
      (__attribute__((address_space(3))) void*)lds_base,
      16, 0, 0);
}

__device__ __forceinline__ void store_out(float* p, float v) { *p = v; }
__device__ __forceinline__ void store_out(unsigned short* p, float v) { *p = f2bf(v); }

// ---------------------------------------------------------------------------
// fp32 -> bf16 bulk cast. n8 = elements/8.
// ---------------------------------------------------------------------------
__global__ __launch_bounds__(256) void cvt_bf16(const float* __restrict__ in,
                                                unsigned short* __restrict__ o, int n8) {
  const int idx = blockIdx.x * 256 + threadIdx.x;
  if (idx >= n8) return;
  float4 f0 = *(const float4*)(in + (size_t)idx * 8);
  float4 f1 = *(const float4*)(in + (size_t)idx * 8 + 4);
  uint4 u;
  u.x = pk2(f0.x, f0.y); u.y = pk2(f0.z, f0.w);
  u.z = pk2(f1.x, f1.y); u.w = pk2(f1.z, f1.w);
  *(uint4*)&o[(size_t)idx * 8] = u;
}

// ---------------------------------------------------------------------------
// MFMA GEMM: C[M x N] = A[M x K] @ B[N x K]^T. bf16 in, OutT out.
// Tile 128 x (NT*32), BK=32, 256 threads = 4 waves; wave does 64 x (NT*16).
// ---------------------------------------------------------------------------
template <typename OutT, int NT>
__global__ __launch_bounds__(256) void gemm_bf16(const unsigned short* __restrict__ A,
                                                 const unsigned short* __restrict__ Bm,
                                                 OutT* __restrict__ C,
                                                 int M, int N, int K) {
  constexpr int BN = NT * 32;
  __shared__ unsigned short As[128 * 32];
  __shared__ unsigned short Bs[BN * 32];
  const int tid  = threadIdx.x;
  const int wave = tid >> 6;
  const int lane = tid & 63;
  const int quad = lane >> 4;
  const int l15  = lane & 15;
  const int m0 = blockIdx.y * 128;
  const int n0 = blockIdx.x * BN;
  const int wm = (wave & 1) * 64;
  const int wn = (wave >> 1) * (NT * 16);

  f32x4 acc[4][NT];
#pragma unroll
  for (int i = 0; i < 4; ++i)
#pragma unroll
    for (int j = 0; j < NT; ++j) {
      f32x4 z = {0.f, 0.f, 0.f, 0.f};
      acc[i][j] = z;
    }

  for (int k0 = 0; k0 < K; k0 += 32) {
    __syncthreads();
    // A: 512 chunk-slots, 2/thread
#pragma unroll
    for (int i = 0; i < 2; ++i) {
      const int s = i * 256 + tid;
      const int srow = s >> 2;
      const int sq = (s & 3) ^ ((srow >> 1) & 3);
      gl_lds16(A + (size_t)(m0 + srow) * K + k0 + sq * 8, &As[(i * 256 + wave * 64) * 8]);
    }
    // B: BN*4 chunk-slots
#pragma unroll
    for (int i = 0; i < BN / 64; ++i) {
      const int s = i * 256 + tid;
      const int srow = s >> 2;
      const int sq = (s & 3) ^ ((srow >> 1) & 3);
      const int rb = min(n0 + srow, N - 1);
      gl_lds16(Bm + (size_t)rb * K + k0 + sq * 8, &Bs[(i * 256 + wave * 64) * 8]);
    }
    __syncthreads();

    short8 a[4], b[NT];
#pragma unroll
    for (int i = 0; i < 4; ++i) {
      const int r = wm + i * 16 + l15;
      a[i] = *(const short8*)&As[(r * 4 + (quad ^ ((r >> 1) & 3))) * 8];
    }
#pragma unroll
    for (int j = 0; j < NT; ++j) {
      const int r = wn + j * 16 + l15;
      b[j] = *(const short8*)&Bs[(r * 4 + (quad ^ ((r >> 1) & 3))) * 8];
    }
#pragma unroll
    for (int i = 0; i < 4; ++i)
#pragma unroll
      for (int j = 0; j < NT; ++j)
        acc[i][j] = __builtin_amdgcn_mfma_f32_16x16x32_bf16(a[i], b[j], acc[i][j], 0, 0, 0);
  }

#pragma unroll
  for (int i = 0; i < 4; ++i) {
#pragma unroll
    for (int j = 0; j < NT; ++j) {
      const int col = n0 + wn + j * 16 + l15;
      if (col < N) {
#pragma unroll
        for (int r = 0; r < 4; ++r) {
          const int row = m0 + wm + i * 16 + quad * 4 + r;
          store_out(&C[(size_t)row * N + col], acc[i][j][r]);
        }
      }
    }
  }
}

// ---------------------------------------------------------------------------
// RMSNorm: fp32 in -> bf16 out
// ---------------------------------------------------------------------------
__global__ __launch_bounds__(256) void rmsnorm_bf16(const float* __restrict__ x,
                                                    const float* __restrict__ w,
                                                    unsigned short* __restrict__ o, int n) {
  __shared__ float red[256];
  const int row = blockIdx.x;
  const float* p = x + (size_t)row * n;
  float s = 0.f;
  for (int i = threadIdx.x; i < n; i += 256) { float v = p[i]; s += v * v; }
  red[threadIdx.x] = s;
  __syncthreads();
  for (int off = 128; off > 0; off >>= 1) {
    if (threadIdx.x < off) red[threadIdx.x] += red[threadIdx.x + off];
    __syncthreads();
  }
  const float inv = rsqrtf(red[0] / (float)n + 1e-6f);
  unsigned short* po = o + (size_t)row * n;
  for (int i = threadIdx.x; i < n; i += 256) po[i] = f2bf(p[i] * inv * w[i]);
}

// ---------------------------------------------------------------------------
// Interleaved RoPE: fp32 in -> bf16 out. Layout (rows, heads*64); pos = row % S.
// ---------------------------------------------------------------------------
__global__ void rope_bf16(const float* __restrict__ xin, unsigned short* __restrict__ xout,
                          int heads, int total_pairs) {
  int idx = blockIdx.x * blockDim.x + threadIdx.x;
  if (idx >= total_pairs) return;
  const int i = idx & 31;
  const int h = (idx >> 5) % heads;
  const int row = idx / (32 * heads);
  const int pos = row & (S_ - 1);
  const float freq = expf(-9.210340371976184f * (float)i / 32.0f);
  const float ang = (float)pos * freq;
  const float c = cosf(ang), sn = sinf(ang);
  const float* p = xin + ((size_t)row * heads + h) * 64 + 2 * i;
  unsigned short* q = xout + ((size_t)row * heads + h) * 64 + 2 * i;
  const float x1 = p[0], x2 = p[1];
  q[0] = f2bf(x1 * c - x2 * sn);
  q[1] = f2bf(x1 * sn + x2 * c);
}

// ---------------------------------------------------------------------------
// One-shot V transpose: kv_up V-part [tok][h*256+128..256) -> vt_g[b][h][feat][key]
// ---------------------------------------------------------------------------
__global__ __launch_bounds__(256) void transpose_v(const unsigned short* __restrict__ kv_up,
                                                   unsigned short* __restrict__ vt_g) {
  __shared__ unsigned short T[128 * 72];
  const int tid = threadIdx.x;
  const int k0 = blockIdx.x * 64;
  const int h = blockIdx.y, b = blockIdx.z;
  const size_t tok0 = (size_t)b * S_;
#pragma unroll
  for (int i = 0; i < 2; ++i) {
    const int u = i * 256 + tid;           // 512 units: key-pair kp, 8-feat group c8
    const int kp = u >> 4, c8 = u & 15;
    const unsigned short* p0 =
        kv_up + (tok0 + k0 + 2 * kp) * (size_t)(H_ * 256) + h * 256 + NOPE_ + c8 * 8;
    union { uint4 v; unsigned short s[8]; } r0, r1;
    r0.v = *(const uint4*)p0;
    r1.v = *(const uint4*)(p0 + H_ * 256);
#pragma unroll
    for (int j = 0; j < 8; ++j)
      *(unsigned*)&T[(c8 * 8 + j) * 72 + 2 * kp] = (unsigned)r0.s[j] | ((unsigned)r1.s[j] << 16);
  }
  __syncthreads();
#pragma unroll
  for (int i = 0; i < 4; ++i) {
    const int sl = i * 256 + tid;          // 1024 out-chunks
    const int f = sl >> 3, c = sl & 7;
    *(uint4*)(vt_g + ((size_t)(b * H_ + h) * 128 + f) * S_ + k0 + c * 8) =
        *(const uint4*)&T[f * 72 + c * 8];
  }
}

// ---------------------------------------------------------------------------
// MFMA flash attention: balanced pairs + double-buffered K + same-iter V.
// R2 post-mortem: 183µs with Occupancy 11.5% = 1 block/CU = 1 wave/SIMD ->
// all dependency chains (shfl reduce, exp2, Ps LDS round-trip) fully exposed
// (VALUBusy 31%, 69% stall). Fix: LDS 91KB -> 73KB so TWO blocks fit per CU
// (grid 512 = 2/CU exactly, all resident). Only K is double-buffered
// (consumed right after the top barrier); V is staged for the CURRENT tile
// at the top and consumed after QK^T+softmax (~2000cy of cover) -> single
// 16KB Vt buffer. 3 barriers/iter, counted vmcnt (never 0 in main loop):
//   barrier#1 (WAR all bufs) ; stage V(cur) [4] ; stage K(nxt) [6]
//   vmcnt(10) = prev K landed ; barrier#2 ; QK^T + softmax + Ps
//   vmcnt(6)  = my V landed   ; barrier#3 ; PV
// Causal mask only on the diagonal tile (uniform branch).
// attn_o aliases q_nope (disjoint rows/heads, reads precede writes).
// ---------------------------------------------------------------------------
#define LV 72    // Ps stride (64 + 8 pad)

__global__ __launch_bounds__(256) void flash_attn_mfma(const unsigned short* q_nope,
                                                       const unsigned short* __restrict__ q_pe,
                                                       const unsigned short* __restrict__ kv_up,
                                                       const unsigned short* __restrict__ k_rope,
                                                       const unsigned short* __restrict__ vt_g,
                                                       unsigned short* attn_o) {
  __shared__ unsigned short Ksn[2][64 * 16 * 8];  // 2 x 16 KB keys x 128 nope-feats
  __shared__ unsigned short Ksr[2][64 * 8 * 8];   // 2 x  8 KB keys x 64 rope-feats
  __shared__ unsigned short Vt[128 * 8 * 8];      //     16 KB feats x 64 keys
  __shared__ unsigned short Ps[64 * LV];          //      9 KB
                                                  // total 73 KB -> 2 blocks/CU

  const int tid  = threadIdx.x;
  const int wave = tid >> 6;
  const int lane = tid & 63;
  const int quad = lane >> 4;
  const int l15  = lane & 15;
  const int pair = blockIdx.x;   // 0..15
  const int h  = blockIdx.y;
  const int b  = blockIdx.z;
  const size_t tok0 = (size_t)b * S_;
  // 1/sqrt(192) * log2(e): softmax in exp2 domain
  const float scale2 = 0.07216878364870323f * 1.4426950408889634f;
  const int qtA = 31 - pair;     // phase-0 strip
  const int qtB = pair;          // phase-1 strip
  const int n0  = qtA + 1;       // iterations in phase 0; total always 33

  auto LOADQ = [&](short8* qf, int qt) {
    const size_t qrow = tok0 + qt * 64 + wave * 16 + l15;
    const unsigned short* pn = q_nope + qrow * (size_t)(H_ * NOPE_) + h * NOPE_;
    const unsigned short* pp = q_pe + qrow * (size_t)(H_ * ROPE_) + h * ROPE_;
#pragma unroll
    for (int s = 0; s < 4; ++s) qf[s] = *(const short8*)(pn + s * 32 + quad * 8);
#pragma unroll
    for (int s = 4; s < 6; ++s) qf[s] = *(const short8*)(pp + (s - 4) * 32 + quad * 8);
  };

  // K staging: 6 global_load_lds per thread (Ksn 4 + Ksr 2).
  auto STAGE_K = [&](int bi, int kt) {
    const int k0 = kt * 64;
#pragma unroll
    for (int i = 0; i < 4; ++i) {
      const int sl = i * 256 + tid;
      const int key = sl >> 4;
      const int c = (sl & 15) ^ (key & 15);
      gl_lds16(kv_up + (tok0 + k0 + key) * (size_t)(H_ * 256) + h * 256 + c * 8,
               &Ksn[bi][(i * 256 + wave * 64) * 8]);
    }
#pragma unroll
    for (int i = 0; i < 2; ++i) {
      const int sl = i * 256 + tid;
      const int key = sl >> 3;
      const int c = (sl & 7) ^ (key & 7);
      gl_lds16(k_rope + (tok0 + k0 + key) * (size_t)ROPE_ + c * 8,
               &Ksr[bi][(i * 256 + wave * 64) * 8]);
    }
  };
  // V staging: 4 global_load_lds per thread.
  auto STAGE_V = [&](int kt) {
    const int k0 = kt * 64;
#pragma unroll
    for (int i = 0; i < 4; ++i) {
      const int sl = i * 256 + tid;
      const int f = sl >> 3;
      const int c = (sl & 7) ^ (f & 7);
      gl_lds16(vt_g + ((size_t)(b * H_ + h) * 128 + f) * S_ + k0 + c * 8,
               &Vt[(i * 256 + wave * 64) * 8]);
    }
  };

  short8 qf[6];
  LOADQ(qf, qtA);

  float m_st[4], l_st[4];
  f32x4 o[8];
#pragma unroll
  for (int r = 0; r < 4; ++r) { m_st[r] = -1e30f; l_st[r] = 0.f; }
#pragma unroll
  for (int nt = 0; nt < 8; ++nt) { f32x4 z = {0.f, 0.f, 0.f, 0.f}; o[nt] = z; }

  auto EPI = [&](int qt) {
    float invl[4];
#pragma unroll
    for (int r = 0; r < 4; ++r) invl[r] = 1.f / l_st[r];
#pragma unroll
    for (int nt = 0; nt < 8; ++nt)
#pragma unroll
      for (int r = 0; r < 4; ++r) {
        const size_t row = tok0 + qt * 64 + wave * 16 + quad * 4 + r;
        attn_o[row * (size_t)(H_ * VDIM_) + h * VDIM_ + nt * 16 + l15] =
            f2bf(o[nt][r] * invl[r]);
      }
  };

  STAGE_K(0, 0);  // prologue: K tile 0 -> buf 0 (6 outstanding)

  for (int it = 0; it < 33; ++it) {
    const int cur = it & 1;
    const int nxt = cur ^ 1;
    const bool ph1 = (it >= n0);
    const int qt = ph1 ? qtB : qtA;
    const int kt = ph1 ? (it - n0) : it;
    const bool last = (it + 1 >= 33);

    // #1 WAR: all waves done reading Vt (prev PV), Ksn/Ksr[nxt] (prev QK^T).
    __builtin_amdgcn_s_barrier();
    asm volatile("" ::: "memory");

    STAGE_V(kt);                                    // 4 loads, current tile
    if (!last) {
      const bool p1n = (it + 1 >= n0);
      const int kt2 = p1n ? (it + 1 - n0) : (it + 1);
      STAGE_K(nxt, kt2);                            // 6 loads, next tile
      asm volatile("s_waitcnt vmcnt(10)" ::: "memory");  // prev K landed
    } else {
      asm volatile("s_waitcnt vmcnt(4)" ::: "memory");   // prev K landed
    }
    // #2 RAW: ALL waves' K loads for tile `it` landed.
    __builtin_amdgcn_s_barrier();
    asm volatile("" ::: "memory");
    __builtin_amdgcn_sched_barrier(0);

    // --- S = Q K^T (wave strip 16 x 64) ---
    f32x4 sacc[4];
#pragma unroll
    for (int nt = 0; nt < 4; ++nt) { f32x4 z = {0.f, 0.f, 0.f, 0.f}; sacc[nt] = z; }
#pragma unroll
    for (int s = 0; s < 4; ++s) {
#pragma unroll
      for (int nt = 0; nt < 4; ++nt) {
        const int key = nt * 16 + l15;
        short8 kb = *(const short8*)&Ksn[cur][(key * 16 + ((s * 4 + quad) ^ (key & 15))) * 8];
        sacc[nt] = __builtin_amdgcn_mfma_f32_16x16x32_bf16(qf[s], kb, sacc[nt], 0, 0, 0);
      }
    }
#pragma unroll
    for (int s = 4; s < 6; ++s) {
#pragma unroll
      for (int nt = 0; nt < 4; ++nt) {
        const int key = nt * 16 + l15;
        short8 kb = *(const short8*)&Ksr[cur][(key * 8 + (((s - 4) * 4 + quad) ^ (key & 7))) * 8];
        sacc[nt] = __builtin_amdgcn_mfma_f32_16x16x32_bf16(qf[s], kb, sacc[nt], 0, 0, 0);
      }
    }

    float sc[4][4];
#pragma unroll
    for (int nt = 0; nt < 4; ++nt)
#pragma unroll
      for (int r = 0; r < 4; ++r) sc[nt][r] = sacc[nt][r] * scale2;
    if (kt == qt) {  // uniform branch: only the diagonal tile pays the mask
#pragma unroll
      for (int nt = 0; nt < 4; ++nt)
#pragma unroll
        for (int r = 0; r < 4; ++r)
          if ((nt * 16 + l15) > (wave * 16 + quad * 4 + r)) sc[nt][r] = -1e30f;
    }

    float mt[4];
#pragma unroll
    for (int r = 0; r < 4; ++r)
      mt[r] = fmaxf(fmaxf(sc[0][r], sc[1][r]), fmaxf(sc[2][r], sc[3][r]));
#pragma unroll
    for (int mask = 1; mask <= 8; mask <<= 1)
#pragma unroll
      for (int r = 0; r < 4; ++r) mt[r] = fmaxf(mt[r], __shfl_xor(mt[r], mask, 64));

    float al[4], rs[4];
#pragma unroll
    for (int r = 0; r < 4; ++r) {
      const float mn = fmaxf(m_st[r], mt[r]);
      al[r] = exp2f(m_st[r] - mn);
      m_st[r] = mn;
      rs[r] = 0.f;
    }
#pragma unroll
    for (int nt = 0; nt < 4; ++nt)
#pragma unroll
      for (int r = 0; r < 4; ++r) {
        const float p = exp2f(sc[nt][r] - m_st[r]);
        sc[nt][r] = p;
        rs[r] += p;
      }
#pragma unroll
    for (int mask = 1; mask <= 8; mask <<= 1)
#pragma unroll
      for (int r = 0; r < 4; ++r) rs[r] += __shfl_xor(rs[r], mask, 64);
#pragma unroll
    for (int r = 0; r < 4; ++r) l_st[r] = l_st[r] * al[r] + rs[r];

    // --- P transpose via LDS (wave-private rows; no block barrier needed) ---
#pragma unroll
    for (int nt = 0; nt < 4; ++nt)
#pragma unroll
      for (int r = 0; r < 4; ++r)
        Ps[(wave * 16 + quad * 4 + r) * LV + nt * 16 + l15] = f2bf(sc[nt][r]);
    __builtin_amdgcn_wave_barrier();  // pin order; same-wave DS ops complete in order

    // --- O *= alpha (covers V landing) ---
#pragma unroll
    for (int nt = 0; nt < 8; ++nt)
#pragma unroll
      for (int r = 0; r < 4; ++r) o[nt][r] *= al[r];

    // #3 RAW: ALL waves' V loads for tile `it` landed.
    if (!last) {
      asm volatile("s_waitcnt vmcnt(6)" ::: "memory");   // my V landed
    } else {
      asm volatile("s_waitcnt vmcnt(0)" ::: "memory");
    }
    __builtin_amdgcn_s_barrier();
    asm volatile("" ::: "memory");
    __builtin_amdgcn_sched_barrier(0);

    // --- O += P V ---
#pragma unroll
    for (int s = 0; s < 2; ++s) {
      short8 pa = *(const short8*)&Ps[(wave * 16 + l15) * LV + s * 32 + quad * 8];
#pragma unroll
      for (int nt = 0; nt < 8; ++nt) {
        const int f = nt * 16 + l15;
        short8 vb = *(const short8*)&Vt[(f * 8 + ((s * 4 + quad) ^ (f & 7))) * 8];
        o[nt] = __builtin_amdgcn_mfma_f32_16x16x32_bf16(pa, vb, o[nt], 0, 0, 0);
      }
    }

    // Phase boundary: flush strip A, reload Q for strip B, reset state.
    if (it == n0 - 1) {
      EPI(qtA);
      LOADQ(qf, qtB);
#pragma unroll
      for (int r = 0; r < 4; ++r) { m_st[r] = -1e30f; l_st[r] = 0.f; }
#pragma unroll
      for (int nt = 0; nt < 8; ++nt) { f32x4 z = {0.f, 0.f, 0.f, 0.f}; o[nt] = z; }
    }
  }

  EPI(qtB);
}

// ---------------------------------------------------------------------------
// Launch
// ---------------------------------------------------------------------------
extern "C" void kernel_launch(void* const* d_in, const int* in_sizes, int n_in,
                              void* d_out, int out_size, void* d_ws, size_t ws_size,
                              hipStream_t stream) {
  (void)in_sizes; (void)n_in;
  const float* x         = (const float*)d_in[0];
  const float* wq_down   = (const float*)d_in[1];
  const float* q_norm_w  = (const float*)d_in[2];
  const float* wq_up     = (const float*)d_in[3];
  const float* wq_rope   = (const float*)d_in[4];
  const float* wkv_down  = (const float*)d_in[5];
  const float* kv_norm_w = (const float*)d_in[6];
  const float* wkv_up    = (const float*)d_in[7];
  const float* wk_rope   = (const float*)d_in[8];
  const float* wo        = (const float*)d_in[9];
  float* out = (float*)d_out;

  // ---- workspace carve (identical layout to the passing run)
  const size_t SZ_XBF   = (size_t)TOK_ * DIM_ * 2;
  const size_t SZ_WQD   = (size_t)QR_ * DIM_ * 2;
  const size_t SZ_WKVD  = (size_t)KVR_ * DIM_ * 2;
  const size_t SZ_WKR   = (size_t)ROPE_ * DIM_ * 2;
  const size_t SZ_WQU   = (size_t)H_ * NOPE_ * QR_ * 2;
  const size_t SZ_WQR   = (size_t)H_ * ROPE_ * QR_ * 2;
  const size_t SZ_WKVU  = (size_t)H_ * (NOPE_ + VDIM_) * KVR_ * 2;
  const size_t SZ_WO    = (size_t)DIM_ * H_ * VDIM_ * 2;
  const size_t SZ_QC    = (size_t)TOK_ * QR_ * 4;   // aliases: q_pe fp32, then vt_g
  const size_t SZ_KVC   = (size_t)TOK_ * KVR_ * 4;
  const size_t SZ_QCN   = (size_t)TOK_ * QR_ * 2;
  const size_t SZ_KVCN  = (size_t)TOK_ * KVR_ * 2;
  const size_t SZ_QNOPE = (size_t)TOK_ * H_ * NOPE_ * 2; // aliases attn_o bf16
  const size_t SZ_QPEB  = (size_t)TOK_ * H_ * ROPE_ * 2;
  const size_t SZ_KRF   = (size_t)TOK_ * ROPE_ * 4;
  const size_t SZ_KRB   = (size_t)TOK_ * ROPE_ * 2;
  const size_t SZ_KVUP  = (size_t)TOK_ * H_ * (NOPE_ + VDIM_) * 2;
  const size_t NEED = SZ_XBF + SZ_WQD + SZ_WKVD + SZ_WKR + SZ_WQU + SZ_WQR + SZ_WKVU +
                      SZ_WO + SZ_QC + SZ_KVC + SZ_QCN + SZ_KVCN + SZ_QNOPE + SZ_QPEB +
                      SZ_KRF + SZ_KRB + SZ_KVUP;
  if (ws_size < NEED) {
    hipMemsetAsync(d_out, 0, (size_t)out_size * sizeof(float), stream);
    return;
  }
  char* p = (char*)d_ws;
  unsigned short* x_bf    = (unsigned short*)p; p += SZ_XBF;
  unsigned short* wqd_bf  = (unsigned short*)p; p += SZ_WQD;
  unsigned short* wkvd_bf = (unsigned short*)p; p += SZ_WKVD;
  unsigned short* wkr_bf  = (unsigned short*)p; p += SZ_WKR;
  unsigned short* wqu_bf  = (unsigned short*)p; p += SZ_WQU;
  unsigned short* wqr_bf  = (unsigned short*)p; p += SZ_WQR;
  unsigned short* wkvu_bf = (unsigned short*)p; p += SZ_WKVU;
  unsigned short* wo_bf   = (unsigned short*)p; p += SZ_WO;
  float*          q_c     = (float*)p;          p += SZ_QC;
  float*          kv_c    = (float*)p;          p += SZ_KVC;
  unsigned short* q_cn    = (unsigned short*)p; p += SZ_QCN;
  unsigned short* kv_cn   = (unsigned short*)p; p += SZ_KVCN;
  unsigned short* q_nope  = (unsigned short*)p; p += SZ_QNOPE;
  unsigned short* q_pe_bf = (unsigned short*)p; p += SZ_QPEB;
  float*          k_ropef = (float*)p;          p += SZ_KRF;
  unsigned short* k_ropeb = (unsigned short*)p; p += SZ_KRB;
  unsigned short* kv_upbf = (unsigned short*)p; p += SZ_KVUP;
  float*          q_pe_f  = q_c;                   // q_c dead after rmsnorm
  unsigned short* vt_g    = (unsigned short*)q_c;  // q_pe_f dead after rope_q
  unsigned short* attn_o  = q_nope;                // q_nope dead after flash

  const dim3 blk(256);
  // ---- one-time bf16 casts
  cvt_bf16<<<(TOK_ * DIM_ / 8 + 255) / 256, blk, 0, stream>>>(x, x_bf, TOK_ * DIM_ / 8);
  cvt_bf16<<<(QR_ * DIM_ / 8 + 255) / 256, blk, 0, stream>>>(wq_down, wqd_bf, QR_ * DIM_ / 8);
  cvt_bf16<<<(KVR_ * DIM_ / 8 + 255) / 256, blk, 0, stream>>>(wkv_down, wkvd_bf, KVR_ * DIM_ / 8);
  cvt_bf16<<<(ROPE_ * DIM_ / 8 + 255) / 256, blk, 0, stream>>>(wk_rope, wkr_bf, ROPE_ * DIM_ / 8);
  cvt_bf16<<<(H_ * NOPE_ * QR_ / 8 + 255) / 256, blk, 0, stream>>>(wq_up, wqu_bf, H_ * NOPE_ * QR_ / 8);
  cvt_bf16<<<(H_ * ROPE_ * QR_ / 8 + 255) / 256, blk, 0, stream>>>(wq_rope, wqr_bf, H_ * ROPE_ * QR_ / 8);
  cvt_bf16<<<(H_ * (NOPE_ + VDIM_) * KVR_ / 8 + 255) / 256, blk, 0, stream>>>(wkv_up, wkvu_bf,
                                                                              H_ * (NOPE_ + VDIM_) * KVR_ / 8);
  cvt_bf16<<<(DIM_ * H_ * VDIM_ / 8 + 255) / 256, blk, 0, stream>>>(wo, wo_bf, DIM_ * H_ * VDIM_ / 8);

  // ---- down projections
  gemm_bf16<float, 4><<<dim3(QR_ / 128, TOK_ / 128), blk, 0, stream>>>(x_bf, wqd_bf, q_c, TOK_, QR_, DIM_);
  gemm_bf16<float, 2><<<dim3(KVR_ / 64, TOK_ / 128), blk, 0, stream>>>(x_bf, wkvd_bf, kv_c, TOK_, KVR_, DIM_);
  gemm_bf16<float, 2><<<dim3(1, TOK_ / 128), blk, 0, stream>>>(x_bf, wkr_bf, k_ropef, TOK_, ROPE_, DIM_);

  // ---- RMSNorms
  rmsnorm_bf16<<<TOK_, blk, 0, stream>>>(q_c, q_norm_w, q_cn, QR_);
  rmsnorm_bf16<<<TOK_, blk, 0, stream>>>(kv_c, kv_norm_w, kv_cn, KVR_);

  // ---- up projections
  gemm_bf16<unsigned short, 4><<<dim3(H_ * NOPE_ / 128, TOK_ / 128), blk, 0, stream>>>(
      q_cn, wqu_bf, q_nope, TOK_, H_ * NOPE_, QR_);
  gemm_bf16<float, 4><<<dim3(H_ * ROPE_ / 128, TOK_ / 128), blk, 0, stream>>>(
      q_cn, wqr_bf, q_pe_f, TOK_, H_ * ROPE_, QR_);
  gemm_bf16<unsigned short, 4><<<dim3(H_ * (NOPE_ + VDIM_) / 128, TOK_ / 128), blk, 0, stream>>>(
      kv_cn, wkvu_bf, kv_upbf, TOK_, H_ * (NOPE_ + VDIM_), KVR_);

  // ---- RoPE (q first: frees q_c region for vt_g)
  {
    const int pairs_q = TOK_ * H_ * 32;
    rope_bf16<<<(pairs_q + 255) / 256, blk, 0, stream>>>(q_pe_f, q_pe_bf, H_, pairs_q);
    const int pairs_k = TOK_ * 32;
    rope_bf16<<<(pairs_k + 255) / 256, blk, 0, stream>>>(k_ropef, k_ropeb, 1, pairs_k);
  }

  // ---- V transpose (after rope_q; vt_g aliases q_c region)
  transpose_v<<<dim3(S_ / 64, H_, B_), blk, 0, stream>>>(kv_upbf, vt_g);

  // ---- attention (balanced pairs, 2 blocks/CU: grid.x = 16)
  flash_attn_mfma<<<dim3(16, H_, B_), blk, 0, stream>>>(q_nope, q_pe_bf, kv_upbf, k_ropeb, vt_g, attn_o);

  // ---- output projection
  gemm_bf16<float, 4><<<dim3(DIM_ / 128, TOK_ / 128), blk, 0, stream>>>(attn_o, wo_bf, out, TOK_, DIM_, H_ * VDIM_);
}

// Round 4
// 566.959 us; speedup vs baseline: 1.1040x; 1.1040x over previous
//
#include <hip/hip_runtime.h>
#include <hip/hip_bf16.h>
#include <math.h>

// Problem constants (from reference)
#define B_    2
#define S_    2048
#define DIM_  2048
#define H_    16
#define NOPE_ 128
#define ROPE_ 64
#define VDIM_ 128
#define QR_   1024
#define KVR_  512
#define TOK_  (B_ * S_)   // 4096 token rows

typedef __attribute__((ext_vector_type(8))) short short8;   // 8 bf16 (4 VGPRs)
typedef __attribute__((ext_vector_type(4))) float f32x4;    // MFMA acc

// fp32 -> bf16 (round-to-nearest-even), raw ushort
__device__ __forceinline__ unsigned short f2bf(float f) {
  union { float f; unsigned u; } v; v.f = f;
  unsigned r = v.u + 0x7fffu + ((v.u >> 16) & 1u);
  return (unsigned short)(r >> 16);
}
__device__ __forceinline__ unsigned pk2(float lo, float hi) {
  return (unsigned)f2bf(lo) | ((unsigned)f2bf(hi) << 16);
}

// async global->LDS, 16 B per lane; dest = wave-uniform base + lane*16.
__device__ __forceinline__ void gl_lds16(const unsigned short* g, unsigned short* lds_base) {
  __builtin_amdgcn_global_load_lds(
      (const __attribute__((address_space(1))) void*)g,
      (__attribute__((address_space(3))) void*)lds_base,
      16, 0, 0);
}

__device__ __forceinline__ void store_out(float* p, float v) { *p = v; }
__device__ __forceinline__ void store_out(unsigned short* p, float v) { *p = f2bf(v); }

// ---------------------------------------------------------------------------
// fp32 -> bf16 bulk cast. n8 = elements/8.
// ---------------------------------------------------------------------------
__global__ __launch_bounds__(256) void cvt_bf16(const float* __restrict__ in,
                                                unsigned short* __restrict__ o, int n8) {
  const int idx = blockIdx.x * 256 + threadIdx.x;
  if (idx >= n8) return;
  float4 f0 = *(const float4*)(in + (size_t)idx * 8);
  float4 f1 = *(const float4*)(in + (size_t)idx * 8 + 4);
  uint4 u;
  u.x = pk2(f0.x, f0.y); u.y = pk2(f0.z, f0.w);
  u.z = pk2(f1.x, f1.y); u.w = pk2(f1.z, f1.w);
  *(uint4*)&o[(size_t)idx * 8] = u;
}

// ---------------------------------------------------------------------------
// MFMA GEMM: C[M x N] = A[M x K] @ B[N x K]^T. bf16 in, OutT out.
// Tile 128 x (NT*32), BK=32, 256 threads = 4 waves; wave does 64 x (NT*16).
// ---------------------------------------------------------------------------
template <typename OutT, int NT>
__global__ __launch_bounds__(256) void gemm_bf16(const unsigned short* __restrict__ A,
                                                 const unsigned short* __restrict__ Bm,
                                                 OutT* __restrict__ C,
                                                 int M, int N, int K) {
  constexpr int BN = NT * 32;
  __shared__ unsigned short As[128 * 32];
  __shared__ unsigned short Bs[BN * 32];
  const int tid  = threadIdx.x;
  const int wave = tid >> 6;
  const int lane = tid & 63;
  const int quad = lane >> 4;
  const int l15  = lane & 15;
  const int m0 = blockIdx.y * 128;
  const int n0 = blockIdx.x * BN;
  const int wm = (wave & 1) * 64;
  const int wn = (wave >> 1) * (NT * 16);

  f32x4 acc[4][NT];
#pragma unroll
  for (int i = 0; i < 4; ++i)
#pragma unroll
    for (int j = 0; j < NT; ++j) {
      f32x4 z = {0.f, 0.f, 0.f, 0.f};
      acc[i][j] = z;
    }

  for (int k0 = 0; k0 < K; k0 += 32) {
    __syncthreads();
    // A: 512 chunk-slots, 2/thread
#pragma unroll
    for (int i = 0; i < 2; ++i) {
      const int s = i * 256 + tid;
      const int srow = s >> 2;
      const int sq = (s & 3) ^ ((srow >> 1) & 3);
      gl_lds16(A + (size_t)(m0 + srow) * K + k0 + sq * 8, &As[(i * 256 + wave * 64) * 8]);
    }
    // B: BN*4 chunk-slots
#pragma unroll
    for (int i = 0; i < BN / 64; ++i) {
      const int s = i * 256 + tid;
      const int srow = s >> 2;
      const int sq = (s & 3) ^ ((srow >> 1) & 3);
      const int rb = min(n0 + srow, N - 1);
      gl_lds16(Bm + (size_t)rb * K + k0 + sq * 8, &Bs[(i * 256 + wave * 64) * 8]);
    }
    __syncthreads();

    short8 a[4], b[NT];
#pragma unroll
    for (int i = 0; i < 4; ++i) {
      const int r = wm + i * 16 + l15;
      a[i] = *(const short8*)&As[(r * 4 + (quad ^ ((r >> 1) & 3))) * 8];
    }
#pragma unroll
    for (int j = 0; j < NT; ++j) {
      const int r = wn + j * 16 + l15;
      b[j] = *(const short8*)&Bs[(r * 4 + (quad ^ ((r >> 1) & 3))) * 8];
    }
#pragma unroll
    for (int i = 0; i < 4; ++i)
#pragma unroll
      for (int j = 0; j < NT; ++j)
        acc[i][j] = __builtin_amdgcn_mfma_f32_16x16x32_bf16(a[i], b[j], acc[i][j], 0, 0, 0);
  }

#pragma unroll
  for (int i = 0; i < 4; ++i) {
#pragma unroll
    for (int j = 0; j < NT; ++j) {
      const int col = n0 + wn + j * 16 + l15;
      if (col < N) {
#pragma unroll
        for (int r = 0; r < 4; ++r) {
          const int row = m0 + wm + i * 16 + quad * 4 + r;
          store_out(&C[(size_t)row * N + col], acc[i][j][r]);
        }
      }
    }
  }
}

// ---------------------------------------------------------------------------
// RMSNorm: fp32 in -> bf16 out
// ---------------------------------------------------------------------------
__global__ __launch_bounds__(256) void rmsnorm_bf16(const float* __restrict__ x,
                                                    const float* __restrict__ w,
                                                    unsigned short* __restrict__ o, int n) {
  __shared__ float red[256];
  const int row = blockIdx.x;
  const float* p = x + (size_t)row * n;
  float s = 0.f;
  for (int i = threadIdx.x; i < n; i += 256) { float v = p[i]; s += v * v; }
  red[threadIdx.x] = s;
  __syncthreads();
  for (int off = 128; off > 0; off >>= 1) {
    if (threadIdx.x < off) red[threadIdx.x] += red[threadIdx.x + off];
    __syncthreads();
  }
  const float inv = rsqrtf(red[0] / (float)n + 1e-6f);
  unsigned short* po = o + (size_t)row * n;
  for (int i = threadIdx.x; i < n; i += 256) po[i] = f2bf(p[i] * inv * w[i]);
}

// ---------------------------------------------------------------------------
// Interleaved RoPE: fp32 in -> bf16 out. Layout (rows, heads*64); pos = row % S.
// ---------------------------------------------------------------------------
__global__ void rope_bf16(const float* __restrict__ xin, unsigned short* __restrict__ xout,
                          int heads, int total_pairs) {
  int idx = blockIdx.x * blockDim.x + threadIdx.x;
  if (idx >= total_pairs) return;
  const int i = idx & 31;
  const int h = (idx >> 5) % heads;
  const int row = idx / (32 * heads);
  const int pos = row & (S_ - 1);
  const float freq = expf(-9.210340371976184f * (float)i / 32.0f);
  const float ang = (float)pos * freq;
  const float c = cosf(ang), sn = sinf(ang);
  const float* p = xin + ((size_t)row * heads + h) * 64 + 2 * i;
  unsigned short* q = xout + ((size_t)row * heads + h) * 64 + 2 * i;
  const float x1 = p[0], x2 = p[1];
  q[0] = f2bf(x1 * c - x2 * sn);
  q[1] = f2bf(x1 * sn + x2 * c);
}

// ---------------------------------------------------------------------------
// One-shot V transpose: kv_up V-part [tok][h*256+128..256) -> vt_g[b][h][feat][key]
// ---------------------------------------------------------------------------
__global__ __launch_bounds__(256) void transpose_v(const unsigned short* __restrict__ kv_up,
                                                   unsigned short* __restrict__ vt_g) {
  __shared__ unsigned short T[128 * 72];
  const int tid = threadIdx.x;
  const int k0 = blockIdx.x * 64;
  const int h = blockIdx.y, b = blockIdx.z;
  const size_t tok0 = (size_t)b * S_;
#pragma unroll
  for (int i = 0; i < 2; ++i) {
    const int u = i * 256 + tid;           // 512 units: key-pair kp, 8-feat group c8
    const int kp = u >> 4, c8 = u & 15;
    const unsigned short* p0 =
        kv_up + (tok0 + k0 + 2 * kp) * (size_t)(H_ * 256) + h * 256 + NOPE_ + c8 * 8;
    union { uint4 v; unsigned short s[8]; } r0, r1;
    r0.v = *(const uint4*)p0;
    r1.v = *(const uint4*)(p0 + H_ * 256);
#pragma unroll
    for (int j = 0; j < 8; ++j)
      *(unsigned*)&T[(c8 * 8 + j) * 72 + 2 * kp] = (unsigned)r0.s[j] | ((unsigned)r1.s[j] << 16);
  }
  __syncthreads();
#pragma unroll
  for (int i = 0; i < 4; ++i) {
    const int sl = i * 256 + tid;          // 1024 out-chunks
    const int f = sl >> 3, c = sl & 7;
    *(uint4*)(vt_g + ((size_t)(b * H_ + h) * 128 + f) * S_ + k0 + c * 8) =
        *(const uint4*)&T[f * 72 + c * 8];
  }
}

// ---------------------------------------------------------------------------
// MFMA flash attention: 8-wave block, 128-row Q-tile, 64-key K/V tiles.
// R3 post-mortem: the CP never co-scheduled 2 blocks/CU (Occupancy stuck at
// 11.4% despite 73KB LDS) -> build the TLP into ONE workgroup instead:
// 512 threads = 8 waves = 2 waves/SIMD guaranteed. Each wave owns 16 of the
// 128 Q-rows; all 8 share each staged K/V tile (2x amortization: FETCH
// halves, MFMA per staged tile doubles). Block p handles q-tiles {15-p, p}
// sequentially -> every block exactly 34 iterations (balanced).
// Causal diagonal spans 2 K-tiles: at kt==2qt lower 4 waves mask normally;
// at kt==2qt+1 lower 4 waves are fully masked -> wave-uniform skip (their
// SIMD co-wave gets the whole SIMD that iteration).
// 3 barriers/iter, counted vmcnt (never 0 in main loop):
//   barrier#1 (WAR) ; stage V(cur) [2] ; stage K(nxt) [3]
//   vmcnt(5) = prev K landed ; barrier#2 ; QK^T + softmax + Ps
//   vmcnt(3) = my V landed   ; barrier#3 ; PV
// LDS 82 KB; 1 block/CU; grid 256 = 1/CU exactly.
// attn_o aliases q_nope: tile 15-p is read only by block p itself at start;
// all reads precede the phase-boundary write.
// ---------------------------------------------------------------------------
#define LV 72    // Ps stride (64 + 8 pad)

__global__ __launch_bounds__(512) void flash_attn_mfma(const unsigned short* q_nope,
                                                       const unsigned short* __restrict__ q_pe,
                                                       const unsigned short* __restrict__ kv_up,
                                                       const unsigned short* __restrict__ k_rope,
                                                       const unsigned short* __restrict__ vt_g,
                                                       unsigned short* attn_o) {
  __shared__ unsigned short Ksn[2][64 * 16 * 8];  // 2 x 16 KB keys x 128 nope-feats
  __shared__ unsigned short Ksr[2][64 * 8 * 8];   // 2 x  8 KB keys x 64 rope-feats
  __shared__ unsigned short Vt[128 * 8 * 8];      //     16 KB feats x 64 keys
  __shared__ unsigned short Ps[128 * LV];         //     18 KB (128 q-rows)
                                                  // total 82 KB

  const int tid  = threadIdx.x;
  const int wave = tid >> 6;    // 0..7
  const int lane = tid & 63;
  const int quad = lane >> 4;
  const int l15  = lane & 15;
  const int pair = blockIdx.x;  // 0..7
  const int h  = blockIdx.y;
  const int b  = blockIdx.z;
  const size_t tok0 = (size_t)b * S_;
  // 1/sqrt(192) * log2(e): softmax in exp2 domain
  const float scale2 = 0.07216878364870323f * 1.4426950408889634f;
  const int qtA = 15 - pair;    // phase-0 q-tile (128 rows)
  const int qtB = pair;         // phase-1 q-tile
  const int n0  = 2 * qtA + 2;  // iterations in phase 0; total always 34

  auto LOADQ = [&](short8* qf, int qt) {
    const size_t qrow = tok0 + qt * 128 + wave * 16 + l15;
    const unsigned short* pn = q_nope + qrow * (size_t)(H_ * NOPE_) + h * NOPE_;
    const unsigned short* pp = q_pe + qrow * (size_t)(H_ * ROPE_) + h * ROPE_;
#pragma unroll
    for (int s = 0; s < 4; ++s) qf[s] = *(const short8*)(pn + s * 32 + quad * 8);
#pragma unroll
    for (int s = 4; s < 6; ++s) qf[s] = *(const short8*)(pp + (s - 4) * 32 + quad * 8);
  };

  // K staging: 3 global_load_lds per thread (Ksn 2 + Ksr 1).
  auto STAGE_K = [&](int bi, int kt) {
    const int k0 = kt * 64;
#pragma unroll
    for (int i = 0; i < 2; ++i) {
      const int sl = i * 512 + tid;          // 1024 chunk-slots
      const int key = sl >> 4;
      const int c = (sl & 15) ^ (key & 15);
      gl_lds16(kv_up + (tok0 + k0 + key) * (size_t)(H_ * 256) + h * 256 + c * 8,
               &Ksn[bi][(i * 512 + wave * 64) * 8]);
    }
    {
      const int sl = tid;                    // 512 chunk-slots
      const int key = sl >> 3;
      const int c = (sl & 7) ^ (key & 7);
      gl_lds16(k_rope + (tok0 + k0 + key) * (size_t)ROPE_ + c * 8,
               &Ksr[bi][(wave * 64) * 8]);
    }
  };
  // V staging: 2 global_load_lds per thread.
  auto STAGE_V = [&](int kt) {
    const int k0 = kt * 64;
#pragma unroll
    for (int i = 0; i < 2; ++i) {
      const int sl = i * 512 + tid;          // 1024 chunk-slots
      const int f = sl >> 3;
      const int c = (sl & 7) ^ (f & 7);
      gl_lds16(vt_g + ((size_t)(b * H_ + h) * 128 + f) * S_ + k0 + c * 8,
               &Vt[(i * 512 + wave * 64) * 8]);
    }
  };

  short8 qf[6];
  LOADQ(qf, qtA);

  float m_st[4], l_st[4];
  f32x4 o[8];
#pragma unroll
  for (int r = 0; r < 4; ++r) { m_st[r] = -1e30f; l_st[r] = 0.f; }
#pragma unroll
  for (int nt = 0; nt < 8; ++nt) { f32x4 z = {0.f, 0.f, 0.f, 0.f}; o[nt] = z; }

  auto EPI = [&](int qt) {
    float invl[4];
#pragma unroll
    for (int r = 0; r < 4; ++r) invl[r] = 1.f / l_st[r];
#pragma unroll
    for (int nt = 0; nt < 8; ++nt)
#pragma unroll
      for (int r = 0; r < 4; ++r) {
        const size_t row = tok0 + qt * 128 + wave * 16 + quad * 4 + r;
        attn_o[row * (size_t)(H_ * VDIM_) + h * VDIM_ + nt * 16 + l15] =
            f2bf(o[nt][r] * invl[r]);
      }
  };

  STAGE_K(0, 0);  // prologue: K tile 0 -> buf 0 (3 outstanding)

  for (int it = 0; it < 34; ++it) {
    const int cur = it & 1;
    const int nxt = cur ^ 1;
    const bool ph1 = (it >= n0);
    const int qt = ph1 ? qtB : qtA;
    const int kt = ph1 ? (it - n0) : it;
    const bool last = (it + 1 >= 34);
    // kt==2qt+1: keys all above the lower 4 waves' rows -> those waves idle.
    const bool active = !(kt == 2 * qt + 1 && wave < 4);

    // #1 WAR: all waves done reading Vt (prev PV), Ksn/Ksr[nxt] (prev QK^T).
    __builtin_amdgcn_s_barrier();
    asm volatile("" ::: "memory");

    STAGE_V(kt);                                    // 2 loads, current tile
    if (!last) {
      const bool p1n = (it + 1 >= n0);
      const int kt2 = p1n ? (it + 1 - n0) : (it + 1);
      STAGE_K(nxt, kt2);                            // 3 loads, next tile
      asm volatile("s_waitcnt vmcnt(5)" ::: "memory");   // prev K landed
    } else {
      asm volatile("s_waitcnt vmcnt(2)" ::: "memory");   // prev K landed
    }
    // #2 RAW: ALL waves' K loads for tile `it` landed.
    __builtin_amdgcn_s_barrier();
    asm volatile("" ::: "memory");
    __builtin_amdgcn_sched_barrier(0);

    if (active) {
      // --- S = Q K^T (wave strip 16 x 64) ---
      f32x4 sacc[4];
#pragma unroll
      for (int nt = 0; nt < 4; ++nt) { f32x4 z = {0.f, 0.f, 0.f, 0.f}; sacc[nt] = z; }
#pragma unroll
      for (int s = 0; s < 4; ++s) {
#pragma unroll
        for (int nt = 0; nt < 4; ++nt) {
          const int key = nt * 16 + l15;
          short8 kb = *(const short8*)&Ksn[cur][(key * 16 + ((s * 4 + quad) ^ (key & 15))) * 8];
          sacc[nt] = __builtin_amdgcn_mfma_f32_16x16x32_bf16(qf[s], kb, sacc[nt], 0, 0, 0);
        }
      }
#pragma unroll
      for (int s = 4; s < 6; ++s) {
#pragma unroll
        for (int nt = 0; nt < 4; ++nt) {
          const int key = nt * 16 + l15;
          short8 kb = *(const short8*)&Ksr[cur][(key * 8 + (((s - 4) * 4 + quad) ^ (key & 7))) * 8];
          sacc[nt] = __builtin_amdgcn_mfma_f32_16x16x32_bf16(qf[s], kb, sacc[nt], 0, 0, 0);
        }
      }

      float sc[4][4];
#pragma unroll
      for (int nt = 0; nt < 4; ++nt)
#pragma unroll
        for (int r = 0; r < 4; ++r) sc[nt][r] = sacc[nt][r] * scale2;
      if (kt >= 2 * qt) {  // diagonal tiles only (uniform branch)
        const int koff = (kt - 2 * qt) * 64;
        const int rw = wave * 16 + quad * 4;
#pragma unroll
        for (int nt = 0; nt < 4; ++nt)
#pragma unroll
          for (int r = 0; r < 4; ++r)
            if ((koff + nt * 16 + l15) > (rw + r)) sc[nt][r] = -1e30f;
      }

      float mt[4];
#pragma unroll
      for (int r = 0; r < 4; ++r)
        mt[r] = fmaxf(fmaxf(sc[0][r], sc[1][r]), fmaxf(sc[2][r], sc[3][r]));
#pragma unroll
      for (int mask = 1; mask <= 8; mask <<= 1)
#pragma unroll
        for (int r = 0; r < 4; ++r) mt[r] = fmaxf(mt[r], __shfl_xor(mt[r], mask, 64));

      float al[4], rs[4];
#pragma unroll
      for (int r = 0; r < 4; ++r) {
        const float mn = fmaxf(m_st[r], mt[r]);
        al[r] = exp2f(m_st[r] - mn);
        m_st[r] = mn;
        rs[r] = 0.f;
      }
#pragma unroll
      for (int nt = 0; nt < 4; ++nt)
#pragma unroll
        for (int r = 0; r < 4; ++r) {
          const float p = exp2f(sc[nt][r] - m_st[r]);
          sc[nt][r] = p;
          rs[r] += p;
        }
#pragma unroll
      for (int mask = 1; mask <= 8; mask <<= 1)
#pragma unroll
        for (int r = 0; r < 4; ++r) rs[r] += __shfl_xor(rs[r], mask, 64);
#pragma unroll
      for (int r = 0; r < 4; ++r) l_st[r] = l_st[r] * al[r] + rs[r];

      // --- P transpose via LDS (wave-private rows) ---
#pragma unroll
      for (int nt = 0; nt < 4; ++nt)
#pragma unroll
        for (int r = 0; r < 4; ++r)
          Ps[(wave * 16 + quad * 4 + r) * LV + nt * 16 + l15] = f2bf(sc[nt][r]);
      __builtin_amdgcn_wave_barrier();  // pin order; same-wave DS ops in order

      // --- O *= alpha (covers V landing) ---
#pragma unroll
      for (int nt = 0; nt < 8; ++nt)
#pragma unroll
        for (int r = 0; r < 4; ++r) o[nt][r] *= al[r];
    }

    // #3 RAW: ALL waves' V loads for tile `it` landed.
    if (!last) {
      asm volatile("s_waitcnt vmcnt(3)" ::: "memory");   // my V landed
    } else {
      asm volatile("s_waitcnt vmcnt(0)" ::: "memory");
    }
    __builtin_amdgcn_s_barrier();
    asm volatile("" ::: "memory");
    __builtin_amdgcn_sched_barrier(0);

    if (active) {
      // --- O += P V ---
#pragma unroll
      for (int s = 0; s < 2; ++s) {
        short8 pa = *(const short8*)&Ps[(wave * 16 + l15) * LV + s * 32 + quad * 8];
#pragma unroll
        for (int nt = 0; nt < 8; ++nt) {
          const int f = nt * 16 + l15;
          short8 vb = *(const short8*)&Vt[(f * 8 + ((s * 4 + quad) ^ (f & 7))) * 8];
          o[nt] = __builtin_amdgcn_mfma_f32_16x16x32_bf16(pa, vb, o[nt], 0, 0, 0);
        }
      }
    }

    // Phase boundary: flush q-tile A, reload Q for tile B, reset state.
    if (it == n0 - 1) {
      EPI(qtA);
      LOADQ(qf, qtB);
#pragma unroll
      for (int r = 0; r < 4; ++r) { m_st[r] = -1e30f; l_st[r] = 0.f; }
#pragma unroll
      for (int nt = 0; nt < 8; ++nt) { f32x4 z = {0.f, 0.f, 0.f, 0.f}; o[nt] = z; }
    }
  }

  EPI(qtB);
}

// ---------------------------------------------------------------------------
// Launch
// ---------------------------------------------------------------------------
extern "C" void kernel_launch(void* const* d_in, const int* in_sizes, int n_in,
                              void* d_out, int out_size, void* d_ws, size_t ws_size,
                              hipStream_t stream) {
  (void)in_sizes; (void)n_in;
  const float* x         = (const float*)d_in[0];
  const float* wq_down   = (const float*)d_in[1];
  const float* q_norm_w  = (const float*)d_in[2];
  const float* wq_up     = (const float*)d_in[3];
  const float* wq_rope   = (const float*)d_in[4];
  const float* wkv_down  = (const float*)d_in[5];
  const float* kv_norm_w = (const float*)d_in[6];
  const float* wkv_up    = (const float*)d_in[7];
  const float* wk_rope   = (const float*)d_in[8];
  const float* wo        = (const float*)d_in[9];
  float* out = (float*)d_out;

  // ---- workspace carve (identical layout to the passing run)
  const size_t SZ_XBF   = (size_t)TOK_ * DIM_ * 2;
  const size_t SZ_WQD   = (size_t)QR_ * DIM_ * 2;
  const size_t SZ_WKVD  = (size_t)KVR_ * DIM_ * 2;
  const size_t SZ_WKR   = (size_t)ROPE_ * DIM_ * 2;
  const size_t SZ_WQU   = (size_t)H_ * NOPE_ * QR_ * 2;
  const size_t SZ_WQR   = (size_t)H_ * ROPE_ * QR_ * 2;
  const size_t SZ_WKVU  = (size_t)H_ * (NOPE_ + VDIM_) * KVR_ * 2;
  const size_t SZ_WO    = (size_t)DIM_ * H_ * VDIM_ * 2;
  const size_t SZ_QC    = (size_t)TOK_ * QR_ * 4;   // aliases: q_pe fp32, then vt_g
  const size_t SZ_KVC   = (size_t)TOK_ * KVR_ * 4;
  const size_t SZ_QCN   = (size_t)TOK_ * QR_ * 2;
  const size_t SZ_KVCN  = (size_t)TOK_ * KVR_ * 2;
  const size_t SZ_QNOPE = (size_t)TOK_ * H_ * NOPE_ * 2; // aliases attn_o bf16
  const size_t SZ_QPEB  = (size_t)TOK_ * H_ * ROPE_ * 2;
  const size_t SZ_KRF   = (size_t)TOK_ * ROPE_ * 4;
  const size_t SZ_KRB   = (size_t)TOK_ * ROPE_ * 2;
  const size_t SZ_KVUP  = (size_t)TOK_ * H_ * (NOPE_ + VDIM_) * 2;
  const size_t NEED = SZ_XBF + SZ_WQD + SZ_WKVD + SZ_WKR + SZ_WQU + SZ_WQR + SZ_WKVU +
                      SZ_WO + SZ_QC + SZ_KVC + SZ_QCN + SZ_KVCN + SZ_QNOPE + SZ_QPEB +
                      SZ_KRF + SZ_KRB + SZ_KVUP;
  if (ws_size < NEED) {
    hipMemsetAsync(d_out, 0, (size_t)out_size * sizeof(float), stream);
    return;
  }
  char* p = (char*)d_ws;
  unsigned short* x_bf    = (unsigned short*)p; p += SZ_XBF;
  unsigned short* wqd_bf  = (unsigned short*)p; p += SZ_WQD;
  unsigned short* wkvd_bf = (unsigned short*)p; p += SZ_WKVD;
  unsigned short* wkr_bf  = (unsigned short*)p; p += SZ_WKR;
  unsigned short* wqu_bf  = (unsigned short*)p; p += SZ_WQU;
  unsigned short* wqr_bf  = (unsigned short*)p; p += SZ_WQR;
  unsigned short* wkvu_bf = (unsigned short*)p; p += SZ_WKVU;
  unsigned short* wo_bf   = (unsigned short*)p; p += SZ_WO;
  float*          q_c     = (float*)p;          p += SZ_QC;
  float*          kv_c    = (float*)p;          p += SZ_KVC;
  unsigned short* q_cn    = (unsigned short*)p; p += SZ_QCN;
  unsigned short* kv_cn   = (unsigned short*)p; p += SZ_KVCN;
  unsigned short* q_nope  = (unsigned short*)p; p += SZ_QNOPE;
  unsigned short* q_pe_bf = (unsigned short*)p; p += SZ_QPEB;
  float*          k_ropef = (float*)p;          p += SZ_KRF;
  unsigned short* k_ropeb = (unsigned short*)p; p += SZ_KRB;
  unsigned short* kv_upbf = (unsigned short*)p; p += SZ_KVUP;
  float*          q_pe_f  = q_c;                   // q_c dead after rmsnorm
  unsigned short* vt_g    = (unsigned short*)q_c;  // q_pe_f dead after rope_q
  unsigned short* attn_o  = q_nope;                // q_nope dead after flash

  const dim3 blk(256);
  // ---- one-time bf16 casts
  cvt_bf16<<<(TOK_ * DIM_ / 8 + 255) / 256, blk, 0, stream>>>(x, x_bf, TOK_ * DIM_ / 8);
  cvt_bf16<<<(QR_ * DIM_ / 8 + 255) / 256, blk, 0, stream>>>(wq_down, wqd_bf, QR_ * DIM_ / 8);
  cvt_bf16<<<(KVR_ * DIM_ / 8 + 255) / 256, blk, 0, stream>>>(wkv_down, wkvd_bf, KVR_ * DIM_ / 8);
  cvt_bf16<<<(ROPE_ * DIM_ / 8 + 255) / 256, blk, 0, stream>>>(wk_rope, wkr_bf, ROPE_ * DIM_ / 8);
  cvt_bf16<<<(H_ * NOPE_ * QR_ / 8 + 255) / 256, blk, 0, stream>>>(wq_up, wqu_bf, H_ * NOPE_ * QR_ / 8);
  cvt_bf16<<<(H_ * ROPE_ * QR_ / 8 + 255) / 256, blk, 0, stream>>>(wq_rope, wqr_bf, H_ * ROPE_ * QR_ / 8);
  cvt_bf16<<<(H_ * (NOPE_ + VDIM_) * KVR_ / 8 + 255) / 256, blk, 0, stream>>>(wkv_up, wkvu_bf,
                                                                              H_ * (NOPE_ + VDIM_) * KVR_ / 8);
  cvt_bf16<<<(DIM_ * H_ * VDIM_ / 8 + 255) / 256, blk, 0, stream>>>(wo, wo_bf, DIM_ * H_ * VDIM_ / 8);

  // ---- down projections
  gemm_bf16<float, 4><<<dim3(QR_ / 128, TOK_ / 128), blk, 0, stream>>>(x_bf, wqd_bf, q_c, TOK_, QR_, DIM_);
  gemm_bf16<float, 2><<<dim3(KVR_ / 64, TOK_ / 128), blk, 0, stream>>>(x_bf, wkvd_bf, kv_c, TOK_, KVR_, DIM_);
  gemm_bf16<float, 2><<<dim3(1, TOK_ / 128), blk, 0, stream>>>(x_bf, wkr_bf, k_ropef, TOK_, ROPE_, DIM_);

  // ---- RMSNorms
  rmsnorm_bf16<<<TOK_, blk, 0, stream>>>(q_c, q_norm_w, q_cn, QR_);
  rmsnorm_bf16<<<TOK_, blk, 0, stream>>>(kv_c, kv_norm_w, kv_cn, KVR_);

  // ---- up projections
  gemm_bf16<unsigned short, 4><<<dim3(H_ * NOPE_ / 128, TOK_ / 128), blk, 0, stream>>>(
      q_cn, wqu_bf, q_nope, TOK_, H_ * NOPE_, QR_);
  gemm_bf16<float, 4><<<dim3(H_ * ROPE_ / 128, TOK_ / 128), blk, 0, stream>>>(
      q_cn, wqr_bf, q_pe_f, TOK_, H_ * ROPE_, QR_);
  gemm_bf16<unsigned short, 4><<<dim3(H_ * (NOPE_ + VDIM_) / 128, TOK_ / 128), blk, 0, stream>>>(
      kv_cn, wkvu_bf, kv_upbf, TOK_, H_ * (NOPE_ + VDIM_), KVR_);

  // ---- RoPE (q first: frees q_c region for vt_g)
  {
    const int pairs_q = TOK_ * H_ * 32;
    rope_bf16<<<(pairs_q + 255) / 256, blk, 0, stream>>>(q_pe_f, q_pe_bf, H_, pairs_q);
    const int pairs_k = TOK_ * 32;
    rope_bf16<<<(pairs_k + 255) / 256, blk, 0, stream>>>(k_ropef, k_ropeb, 1, pairs_k);
  }

  // ---- V transpose (after rope_q; vt_g aliases q_c region)
  transpose_v<<<dim3(S_ / 64, H_, B_), blk, 0, stream>>>(kv_upbf, vt_g);

  // ---- attention (8-wave blocks, 128-row q-tiles: grid.x = 8)
  flash_attn_mfma<<<dim3(8, H_, B_), dim3(512), 0, stream>>>(q_nope, q_pe_bf, kv_upbf, k_ropeb, vt_g, attn_o);

  // ---- output projection
  gemm_bf16<float, 4><<<dim3(DIM_ / 128, TOK_ / 128), blk, 0, stream>>>(attn_o, wo_bf, out, TOK_, DIM_, H_ * VDIM_);
}

// Round 5
// 475.888 us; speedup vs baseline: 1.3153x; 1.1914x over previous
//
#include <hip/hip_runtime.h>
#include <hip/hip_bf16.h>
#include <math.h>

// Problem constants (from reference)
#define B_    2
#define S_    2048
#define DIM_  2048
#define H_    16
#define NOPE_ 128
#define ROPE_ 64
#define VDIM_ 128
#define QR_   1024
#define KVR_  512
#define TOK_  (B_ * S_)   // 4096 token rows

typedef __attribute__((ext_vector_type(8))) short short8;   // 8 bf16 (4 VGPRs)
typedef __attribute__((ext_vector_type(4))) float f32x4;    // MFMA acc

// fp32 -> bf16 (round-to-nearest-even), raw ushort
__device__ __forceinline__ unsigned short f2bf(float f) {
  union { float f; unsigned u; } v; v.f = f;
  unsigned r = v.u + 0x7fffu + ((v.u >> 16) & 1u);
  return (unsigned short)(r >> 16);
}
__device__ __forceinline__ unsigned pk2(float lo, float hi) {
  return (unsigned)f2bf(lo) | ((unsigned)f2bf(hi) << 16);
}

// async global->LDS, 16 B per lane; dest = wave-uniform base + lane*16.
__device__ __forceinline__ void gl_lds16(const unsigned short* g, unsigned short* lds_base) {
  __builtin_amdgcn_global_load_lds(
      (const __attribute__((address_space(1))) void*)g,
      (__attribute__((address_space(3))) void*)lds_base,
      16, 0, 0);
}

__device__ __forceinline__ void store_out(float* p, float v) { *p = v; }
__device__ __forceinline__ void store_out(unsigned short* p, float v) { *p = f2bf(v); }

// ---------------------------------------------------------------------------
// ONE-SHOT cast: all 8 fp32->bf16 conversions in a single launch.
// Segment bounds are compile-time (chunks of 8 elements).
// ---------------------------------------------------------------------------
#define C_X    (TOK_ * DIM_ / 8)                  // 1048576
#define C_WQD  (QR_ * DIM_ / 8)                   //  262144
#define C_WKVD (KVR_ * DIM_ / 8)                  //  131072
#define C_WKR  (ROPE_ * DIM_ / 8)                 //   16384
#define C_WQU  (H_ * NOPE_ * QR_ / 8)             //  262144
#define C_WQR  (H_ * ROPE_ * QR_ / 8)             //  131072
#define C_WKVU (H_ * (NOPE_ + VDIM_) * KVR_ / 8)  //  262144
#define C_WO   (DIM_ * H_ * VDIM_ / 8)            //  524288
#define C_TOT  (C_X + C_WQD + C_WKVD + C_WKR + C_WQU + C_WQR + C_WKVU + C_WO)

__global__ __launch_bounds__(256) void cvt_all(
    const float* __restrict__ x, const float* __restrict__ wqd, const float* __restrict__ wkvd,
    const float* __restrict__ wkr, const float* __restrict__ wqu, const float* __restrict__ wqr,
    const float* __restrict__ wkvu, const float* __restrict__ wo,
    unsigned short* __restrict__ xo, unsigned short* __restrict__ wqdo,
    unsigned short* __restrict__ wkvdo, unsigned short* __restrict__ wkro,
    unsigned short* __restrict__ wquo, unsigned short* __restrict__ wqro,
    unsigned short* __restrict__ wkvuo, unsigned short* __restrict__ woo) {
  int i = blockIdx.x * 256 + threadIdx.x;
  if (i >= C_TOT) return;
  const float* in; unsigned short* out;
  if (i < C_X) { in = x; out = xo; }
  else if ((i -= C_X) < C_WQD) { in = wqd; out = wqdo; }
  else if ((i -= C_WQD) < C_WKVD) { in = wkvd; out = wkvdo; }
  else if ((i -= C_WKVD) < C_WKR) { in = wkr; out = wkro; }
  else if ((i -= C_WKR) < C_WQU) { in = wqu; out = wquo; }
  else if ((i -= C_WQU) < C_WQR) { in = wqr; out = wqro; }
  else if ((i -= C_WQR) < C_WKVU) { in = wkvu; out = wkvuo; }
  else { i -= C_WKVU; in = wo; out = woo; }
  float4 f0 = *(const float4*)(in + (size_t)i * 8);
  float4 f1 = *(const float4*)(in + (size_t)i * 8 + 4);
  uint4 u;
  u.x = pk2(f0.x, f0.y); u.y = pk2(f0.z, f0.w);
  u.z = pk2(f1.x, f1.y); u.w = pk2(f1.z, f1.w);
  *(uint4*)&out[(size_t)i * 8] = u;
}

// ---------------------------------------------------------------------------
// MFMA GEMM: C[M x N] = A[M x K] @ B[N x K]^T. bf16 in, OutT out.
// Tile 128 x (NT*32), BK=32, 256 threads = 4 waves; wave does 64 x (NT*16).
// ---------------------------------------------------------------------------
template <typename OutT, int NT>
__global__ __launch_bounds__(256) void gemm_bf16(const unsigned short* __restrict__ A,
                                                 const unsigned short* __restrict__ Bm,
                                                 OutT* __restrict__ C,
                                                 int M, int N, int K) {
  constexpr int BN = NT * 32;
  __shared__ unsigned short As[128 * 32];
  __shared__ unsigned short Bs[BN * 32];
  const int tid  = threadIdx.x;
  const int wave = tid >> 6;
  const int lane = tid & 63;
  const int quad = lane >> 4;
  const int l15  = lane & 15;
  const int m0 = blockIdx.y * 128;
  const int n0 = blockIdx.x * BN;
  const int wm = (wave & 1) * 64;
  const int wn = (wave >> 1) * (NT * 16);

  f32x4 acc[4][NT];
#pragma unroll
  for (int i = 0; i < 4; ++i)
#pragma unroll
    for (int j = 0; j < NT; ++j) {
      f32x4 z = {0.f, 0.f, 0.f, 0.f};
      acc[i][j] = z;
    }

  for (int k0 = 0; k0 < K; k0 += 32) {
    __syncthreads();
#pragma unroll
    for (int i = 0; i < 2; ++i) {
      const int s = i * 256 + tid;
      const int srow = s >> 2;
      const int sq = (s & 3) ^ ((srow >> 1) & 3);
      gl_lds16(A + (size_t)(m0 + srow) * K + k0 + sq * 8, &As[(i * 256 + wave * 64) * 8]);
    }
#pragma unroll
    for (int i = 0; i < BN / 64; ++i) {
      const int s = i * 256 + tid;
      const int srow = s >> 2;
      const int sq = (s & 3) ^ ((srow >> 1) & 3);
      const int rb = min(n0 + srow, N - 1);
      gl_lds16(Bm + (size_t)rb * K + k0 + sq * 8, &Bs[(i * 256 + wave * 64) * 8]);
    }
    __syncthreads();

    short8 a[4], b[NT];
#pragma unroll
    for (int i = 0; i < 4; ++i) {
      const int r = wm + i * 16 + l15;
      a[i] = *(const short8*)&As[(r * 4 + (quad ^ ((r >> 1) & 3))) * 8];
    }
#pragma unroll
    for (int j = 0; j < NT; ++j) {
      const int r = wn + j * 16 + l15;
      b[j] = *(const short8*)&Bs[(r * 4 + (quad ^ ((r >> 1) & 3))) * 8];
    }
#pragma unroll
    for (int i = 0; i < 4; ++i)
#pragma unroll
      for (int j = 0; j < NT; ++j)
        acc[i][j] = __builtin_amdgcn_mfma_f32_16x16x32_bf16(a[i], b[j], acc[i][j], 0, 0, 0);
  }

#pragma unroll
  for (int i = 0; i < 4; ++i) {
#pragma unroll
    for (int j = 0; j < NT; ++j) {
      const int col = n0 + wn + j * 16 + l15;
      if (col < N) {
#pragma unroll
        for (int r = 0; r < 4; ++r) {
          const int row = m0 + wm + i * 16 + quad * 4 + r;
          store_out(&C[(size_t)row * N + col], acc[i][j][r]);
        }
      }
    }
  }
}

// ---------------------------------------------------------------------------
// FUSED down-projection GEMM: x_bf [4096 x 2048] @ {wq_down, wkv_down, wk_rope}^T
// One launch, 13 n-tiles x 32 m-tiles. Per-block routing (uniform):
//   tiles 0-7  -> q_c   (N=1024), tiles 8-11 -> kv_c (N=512), tile 12 -> k_ropef (N=64)
// fp32 out everywhere (rmsnorm / rope read fp32 as before).
// ---------------------------------------------------------------------------
__global__ __launch_bounds__(256) void gemm_down(const unsigned short* __restrict__ A,
                                                 const unsigned short* __restrict__ Bq,
                                                 const unsigned short* __restrict__ Bkv,
                                                 const unsigned short* __restrict__ Bkr,
                                                 float* __restrict__ Cq,
                                                 float* __restrict__ Ckv,
                                                 float* __restrict__ Ckr) {
  constexpr int K = DIM_;
  __shared__ unsigned short As[128 * 32];
  __shared__ unsigned short Bs[128 * 32];
  const int tid  = threadIdx.x;
  const int wave = tid >> 6;
  const int lane = tid & 63;
  const int quad = lane >> 4;
  const int l15  = lane & 15;
  const int m0 = blockIdx.y * 128;
  const int t  = blockIdx.x;   // 0..12

  const unsigned short* Bm; float* C; int n0, NB;
  if (t < 8)       { Bm = Bq;  C = Cq;  n0 = t * 128;        NB = QR_;  }
  else if (t < 12) { Bm = Bkv; C = Ckv; n0 = (t - 8) * 128;  NB = KVR_; }
  else             { Bm = Bkr; C = Ckr; n0 = 0;              NB = ROPE_; }

  const int wm = (wave & 1) * 64;
  const int wn = (wave >> 1) * 64;

  f32x4 acc[4][4];
#pragma unroll
  for (int i = 0; i < 4; ++i)
#pragma unroll
    for (int j = 0; j < 4; ++j) { f32x4 z = {0.f, 0.f, 0.f, 0.f}; acc[i][j] = z; }

  for (int k0 = 0; k0 < K; k0 += 32) {
    __syncthreads();
#pragma unroll
    for (int i = 0; i < 2; ++i) {
      const int s = i * 256 + tid;
      const int srow = s >> 2;
      const int sq = (s & 3) ^ ((srow >> 1) & 3);
      gl_lds16(A + (size_t)(m0 + srow) * K + k0 + sq * 8, &As[(i * 256 + wave * 64) * 8]);
    }
#pragma unroll
    for (int i = 0; i < 2; ++i) {
      const int s = i * 256 + tid;
      const int srow = s >> 2;
      const int sq = (s & 3) ^ ((srow >> 1) & 3);
      const int rb = min(n0 + srow, NB - 1);
      gl_lds16(Bm + (size_t)rb * K + k0 + sq * 8, &Bs[(i * 256 + wave * 64) * 8]);
    }
    __syncthreads();

    short8 a[4], b[4];
#pragma unroll
    for (int i = 0; i < 4; ++i) {
      const int r = wm + i * 16 + l15;
      a[i] = *(const short8*)&As[(r * 4 + (quad ^ ((r >> 1) & 3))) * 8];
    }
#pragma unroll
    for (int j = 0; j < 4; ++j) {
      const int r = wn + j * 16 + l15;
      b[j] = *(const short8*)&Bs[(r * 4 + (quad ^ ((r >> 1) & 3))) * 8];
    }
#pragma unroll
    for (int i = 0; i < 4; ++i)
#pragma unroll
      for (int j = 0; j < 4; ++j)
        acc[i][j] = __builtin_amdgcn_mfma_f32_16x16x32_bf16(a[i], b[j], acc[i][j], 0, 0, 0);
  }

#pragma unroll
  for (int i = 0; i < 4; ++i) {
#pragma unroll
    for (int j = 0; j < 4; ++j) {
      const int col = n0 + wn + j * 16 + l15;
      if (col < NB) {
#pragma unroll
        for (int r = 0; r < 4; ++r) {
          const int row = m0 + wm + i * 16 + quad * 4 + r;
          C[(size_t)row * NB + col] = acc[i][j][r];
        }
      }
    }
  }
}

// ---------------------------------------------------------------------------
// FUSED q up-projection GEMM: q_cn [4096 x 1024] @ {wq_up, wq_rope}^T
// tiles 0-15 -> q_nope (bf16, N=2048); tiles 16-23 -> q_pe_f (fp32, N=1024).
// ---------------------------------------------------------------------------
__global__ __launch_bounds__(256) void gemm_upq(const unsigned short* __restrict__ A,
                                                const unsigned short* __restrict__ Bn,
                                                const unsigned short* __restrict__ Br,
                                                unsigned short* __restrict__ Cn,
                                                float* __restrict__ Cr) {
  constexpr int K = QR_;
  __shared__ unsigned short As[128 * 32];
  __shared__ unsigned short Bs[128 * 32];
  const int tid  = threadIdx.x;
  const int wave = tid >> 6;
  const int lane = tid & 63;
  const int quad = lane >> 4;
  const int l15  = lane & 15;
  const int m0 = blockIdx.y * 128;
  const int t  = blockIdx.x;   // 0..23
  const bool isn = (t < 16);
  const unsigned short* Bm = isn ? Bn : Br;
  const int n0 = isn ? t * 128 : (t - 16) * 128;
  const int NB = isn ? (H_ * NOPE_) : (H_ * ROPE_);

  const int wm = (wave & 1) * 64;
  const int wn = (wave >> 1) * 64;

  f32x4 acc[4][4];
#pragma unroll
  for (int i = 0; i < 4; ++i)
#pragma unroll
    for (int j = 0; j < 4; ++j) { f32x4 z = {0.f, 0.f, 0.f, 0.f}; acc[i][j] = z; }

  for (int k0 = 0; k0 < K; k0 += 32) {
    __syncthreads();
#pragma unroll
    for (int i = 0; i < 2; ++i) {
      const int s = i * 256 + tid;
      const int srow = s >> 2;
      const int sq = (s & 3) ^ ((srow >> 1) & 3);
      gl_lds16(A + (size_t)(m0 + srow) * K + k0 + sq * 8, &As[(i * 256 + wave * 64) * 8]);
    }
#pragma unroll
    for (int i = 0; i < 2; ++i) {
      const int s = i * 256 + tid;
      const int srow = s >> 2;
      const int sq = (s & 3) ^ ((srow >> 1) & 3);
      const int rb = min(n0 + srow, NB - 1);
      gl_lds16(Bm + (size_t)rb * K + k0 + sq * 8, &Bs[(i * 256 + wave * 64) * 8]);
    }
    __syncthreads();

    short8 a[4], b[4];
#pragma unroll
    for (int i = 0; i < 4; ++i) {
      const int r = wm + i * 16 + l15;
      a[i] = *(const short8*)&As[(r * 4 + (quad ^ ((r >> 1) & 3))) * 8];
    }
#pragma unroll
    for (int j = 0; j < 4; ++j) {
      const int r = wn + j * 16 + l15;
      b[j] = *(const short8*)&Bs[(r * 4 + (quad ^ ((r >> 1) & 3))) * 8];
    }
#pragma unroll
    for (int i = 0; i < 4; ++i)
#pragma unroll
      for (int j = 0; j < 4; ++j)
        acc[i][j] = __builtin_amdgcn_mfma_f32_16x16x32_bf16(a[i], b[j], acc[i][j], 0, 0, 0);
  }

#pragma unroll
  for (int i = 0; i < 4; ++i) {
#pragma unroll
    for (int j = 0; j < 4; ++j) {
      const int col = n0 + wn + j * 16 + l15;
#pragma unroll
      for (int r = 0; r < 4; ++r) {
        const int row = m0 + wm + i * 16 + quad * 4 + r;
        if (isn) Cn[(size_t)row * (H_ * NOPE_) + col] = f2bf(acc[i][j][r]);
        else     Cr[(size_t)row * (H_ * ROPE_) + col] = acc[i][j][r];
      }
    }
  }
}

// ---------------------------------------------------------------------------
// RMSNorm (both q and kv in one launch): grid (TOK_, 2).
// ---------------------------------------------------------------------------
__global__ __launch_bounds__(256) void rmsnorm2(const float* __restrict__ xq,
                                                const float* __restrict__ wq,
                                                unsigned short* __restrict__ oq,
                                                const float* __restrict__ xkv,
                                                const float* __restrict__ wkv,
                                                unsigned short* __restrict__ okv) {
  __shared__ float red[256];
  const bool isq = (blockIdx.y == 0);
  const int n = isq ? QR_ : KVR_;
  const float* x = isq ? xq : xkv;
  const float* w = isq ? wq : wkv;
  unsigned short* o = isq ? oq : okv;
  const int row = blockIdx.x;
  const float* p = x + (size_t)row * n;
  float s = 0.f;
  for (int i = threadIdx.x; i < n; i += 256) { float v = p[i]; s += v * v; }
  red[threadIdx.x] = s;
  __syncthreads();
  for (int off = 128; off > 0; off >>= 1) {
    if (threadIdx.x < off) red[threadIdx.x] += red[threadIdx.x + off];
    __syncthreads();
  }
  const float inv = rsqrtf(red[0] / (float)n + 1e-6f);
  unsigned short* po = o + (size_t)row * n;
  for (int i = threadIdx.x; i < n; i += 256) po[i] = f2bf(p[i] * inv * w[i]);
}

// ---------------------------------------------------------------------------
// Interleaved RoPE, q and k fused in one launch. pos = row % S.
// ---------------------------------------------------------------------------
#define PAIRS_Q (TOK_ * H_ * 32)
#define PAIRS_K (TOK_ * 32)

__global__ void rope_all(const float* __restrict__ qin, unsigned short* __restrict__ qout,
                         const float* __restrict__ kin, unsigned short* __restrict__ kout) {
  int idx = blockIdx.x * blockDim.x + threadIdx.x;
  if (idx >= PAIRS_Q + PAIRS_K) return;
  int heads, id;
  const float* xin; unsigned short* xout;
  if (idx < PAIRS_Q) { heads = H_; xin = qin; xout = qout; id = idx; }
  else { heads = 1; xin = kin; xout = kout; id = idx - PAIRS_Q; }
  const int i = id & 31;
  const int h = (id >> 5) % heads;
  const int row = id / (32 * heads);
  const int pos = row & (S_ - 1);
  const float freq = expf(-9.210340371976184f * (float)i / 32.0f);
  const float ang = (float)pos * freq;
  const float c = cosf(ang), sn = sinf(ang);
  const float* p = xin + ((size_t)row * heads + h) * 64 + 2 * i;
  unsigned short* q = xout + ((size_t)row * heads + h) * 64 + 2 * i;
  const float x1 = p[0], x2 = p[1];
  q[0] = f2bf(x1 * c - x2 * sn);
  q[1] = f2bf(x1 * sn + x2 * c);
}

// ---------------------------------------------------------------------------
// One-shot V transpose: kv_up V-part [tok][h*256+128..256) -> vt_g[b][h][feat][key]
// ---------------------------------------------------------------------------
__global__ __launch_bounds__(256) void transpose_v(const unsigned short* __restrict__ kv_up,
                                                   unsigned short* __restrict__ vt_g) {
  __shared__ unsigned short T[128 * 72];
  const int tid = threadIdx.x;
  const int k0 = blockIdx.x * 64;
  const int h = blockIdx.y, b = blockIdx.z;
  const size_t tok0 = (size_t)b * S_;
#pragma unroll
  for (int i = 0; i < 2; ++i) {
    const int u = i * 256 + tid;
    const int kp = u >> 4, c8 = u & 15;
    const unsigned short* p0 =
        kv_up + (tok0 + k0 + 2 * kp) * (size_t)(H_ * 256) + h * 256 + NOPE_ + c8 * 8;
    union { uint4 v; unsigned short s[8]; } r0, r1;
    r0.v = *(const uint4*)p0;
    r1.v = *(const uint4*)(p0 + H_ * 256);
#pragma unroll
    for (int j = 0; j < 8; ++j)
      *(unsigned*)&T[(c8 * 8 + j) * 72 + 2 * kp] = (unsigned)r0.s[j] | ((unsigned)r1.s[j] << 16);
  }
  __syncthreads();
#pragma unroll
  for (int i = 0; i < 4; ++i) {
    const int sl = i * 256 + tid;
    const int f = sl >> 3, c = sl & 7;
    *(uint4*)(vt_g + ((size_t)(b * H_ + h) * 128 + f) * S_ + k0 + c * 8) =
        *(const uint4*)&T[f * 72 + c * 8];
  }
}

// ---------------------------------------------------------------------------
// MFMA flash attention: 8-wave block, 128-row Q-tile, 64-key K/V tiles.
// (R4-verified structure; R5 adds s_setprio around MFMA clusters.)
// ---------------------------------------------------------------------------
#define LV 72    // Ps stride (64 + 8 pad)

__global__ __launch_bounds__(512) void flash_attn_mfma(const unsigned short* q_nope,
                                                       const unsigned short* __restrict__ q_pe,
                                                       const unsigned short* __restrict__ kv_up,
                                                       const unsigned short* __restrict__ k_rope,
                                                       const unsigned short* __restrict__ vt_g,
                                                       unsigned short* attn_o) {
  __shared__ unsigned short Ksn[2][64 * 16 * 8];  // 2 x 16 KB keys x 128 nope-feats
  __shared__ unsigned short Ksr[2][64 * 8 * 8];   // 2 x  8 KB keys x 64 rope-feats
  __shared__ unsigned short Vt[128 * 8 * 8];      //     16 KB feats x 64 keys
  __shared__ unsigned short Ps[128 * LV];         //     18 KB (128 q-rows)

  const int tid  = threadIdx.x;
  const int wave = tid >> 6;    // 0..7
  const int lane = tid & 63;
  const int quad = lane >> 4;
  const int l15  = lane & 15;
  const int pair = blockIdx.x;  // 0..7
  const int h  = blockIdx.y;
  const int b  = blockIdx.z;
  const size_t tok0 = (size_t)b * S_;
  const float scale2 = 0.07216878364870323f * 1.4426950408889634f;
  const int qtA = 15 - pair;
  const int qtB = pair;
  const int n0  = 2 * qtA + 2;  // iterations in phase 0; total always 34

  auto LOADQ = [&](short8* qf, int qt) {
    const size_t qrow = tok0 + qt * 128 + wave * 16 + l15;
    const unsigned short* pn = q_nope + qrow * (size_t)(H_ * NOPE_) + h * NOPE_;
    const unsigned short* pp = q_pe + qrow * (size_t)(H_ * ROPE_) + h * ROPE_;
#pragma unroll
    for (int s = 0; s < 4; ++s) qf[s] = *(const short8*)(pn + s * 32 + quad * 8);
#pragma unroll
    for (int s = 4; s < 6; ++s) qf[s] = *(const short8*)(pp + (s - 4) * 32 + quad * 8);
  };

  auto STAGE_K = [&](int bi, int kt) {
    const int k0 = kt * 64;
#pragma unroll
    for (int i = 0; i < 2; ++i) {
      const int sl = i * 512 + tid;
      const int key = sl >> 4;
      const int c = (sl & 15) ^ (key & 15);
      gl_lds16(kv_up + (tok0 + k0 + key) * (size_t)(H_ * 256) + h * 256 + c * 8,
               &Ksn[bi][(i * 512 + wave * 64) * 8]);
    }
    {
      const int sl = tid;
      const int key = sl >> 3;
      const int c = (sl & 7) ^ (key & 7);
      gl_lds16(k_rope + (tok0 + k0 + key) * (size_t)ROPE_ + c * 8,
               &Ksr[bi][(wave * 64) * 8]);
    }
  };
  auto STAGE_V = [&](int kt) {
    const int k0 = kt * 64;
#pragma unroll
    for (int i = 0; i < 2; ++i) {
      const int sl = i * 512 + tid;
      const int f = sl >> 3;
      const int c = (sl & 7) ^ (f & 7);
      gl_lds16(vt_g + ((size_t)(b * H_ + h) * 128 + f) * S_ + k0 + c * 8,
               &Vt[(i * 512 + wave * 64) * 8]);
    }
  };

  short8 qf[6];
  LOADQ(qf, qtA);

  float m_st[4], l_st[4];
  f32x4 o[8];
#pragma unroll
  for (int r = 0; r < 4; ++r) { m_st[r] = -1e30f; l_st[r] = 0.f; }
#pragma unroll
  for (int nt = 0; nt < 8; ++nt) { f32x4 z = {0.f, 0.f, 0.f, 0.f}; o[nt] = z; }

  auto EPI = [&](int qt) {
    float invl[4];
#pragma unroll
    for (int r = 0; r < 4; ++r) invl[r] = 1.f / l_st[r];
#pragma unroll
    for (int nt = 0; nt < 8; ++nt)
#pragma unroll
      for (int r = 0; r < 4; ++r) {
        const size_t row = tok0 + qt * 128 + wave * 16 + quad * 4 + r;
        attn_o[row * (size_t)(H_ * VDIM_) + h * VDIM_ + nt * 16 + l15] =
            f2bf(o[nt][r] * invl[r]);
      }
  };

  STAGE_K(0, 0);

  for (int it = 0; it < 34; ++it) {
    const int cur = it & 1;
    const int nxt = cur ^ 1;
    const bool ph1 = (it >= n0);
    const int qt = ph1 ? qtB : qtA;
    const int kt = ph1 ? (it - n0) : it;
    const bool last = (it + 1 >= 34);
    const bool active = !(kt == 2 * qt + 1 && wave < 4);

    __builtin_amdgcn_s_barrier();
    asm volatile("" ::: "memory");

    STAGE_V(kt);
    if (!last) {
      const bool p1n = (it + 1 >= n0);
      const int kt2 = p1n ? (it + 1 - n0) : (it + 1);
      STAGE_K(nxt, kt2);
      asm volatile("s_waitcnt vmcnt(5)" ::: "memory");
    } else {
      asm volatile("s_waitcnt vmcnt(2)" ::: "memory");
    }
    __builtin_amdgcn_s_barrier();
    asm volatile("" ::: "memory");
    __builtin_amdgcn_sched_barrier(0);

    if (active) {
      f32x4 sacc[4];
#pragma unroll
      for (int nt = 0; nt < 4; ++nt) { f32x4 z = {0.f, 0.f, 0.f, 0.f}; sacc[nt] = z; }
      __builtin_amdgcn_s_setprio(1);
#pragma unroll
      for (int s = 0; s < 4; ++s) {
#pragma unroll
        for (int nt = 0; nt < 4; ++nt) {
          const int key = nt * 16 + l15;
          short8 kb = *(const short8*)&Ksn[cur][(key * 16 + ((s * 4 + quad) ^ (key & 15))) * 8];
          sacc[nt] = __builtin_amdgcn_mfma_f32_16x16x32_bf16(qf[s], kb, sacc[nt], 0, 0, 0);
        }
      }
#pragma unroll
      for (int s = 4; s < 6; ++s) {
#pragma unroll
        for (int nt = 0; nt < 4; ++nt) {
          const int key = nt * 16 + l15;
          short8 kb = *(const short8*)&Ksr[cur][(key * 8 + (((s - 4) * 4 + quad) ^ (key & 7))) * 8];
          sacc[nt] = __builtin_amdgcn_mfma_f32_16x16x32_bf16(qf[s], kb, sacc[nt], 0, 0, 0);
        }
      }
      __builtin_amdgcn_s_setprio(0);

      float sc[4][4];
#pragma unroll
      for (int nt = 0; nt < 4; ++nt)
#pragma unroll
        for (int r = 0; r < 4; ++r) sc[nt][r] = sacc[nt][r] * scale2;
      if (kt >= 2 * qt) {
        const int koff = (kt - 2 * qt) * 64;
        const int rw = wave * 16 + quad * 4;
#pragma unroll
        for (int nt = 0; nt < 4; ++nt)
#pragma unroll
          for (int r = 0; r < 4; ++r)
            if ((koff + nt * 16 + l15) > (rw + r)) sc[nt][r] = -1e30f;
      }

      float mt[4];
#pragma unroll
      for (int r = 0; r < 4; ++r)
        mt[r] = fmaxf(fmaxf(sc[0][r], sc[1][r]), fmaxf(sc[2][r], sc[3][r]));
#pragma unroll
      for (int mask = 1; mask <= 8; mask <<= 1)
#pragma unroll
        for (int r = 0; r < 4; ++r) mt[r] = fmaxf(mt[r], __shfl_xor(mt[r], mask, 64));

      float al[4], rs[4];
#pragma unroll
      for (int r = 0; r < 4; ++r) {
        const float mn = fmaxf(m_st[r], mt[r]);
        al[r] = exp2f(m_st[r] - mn);
        m_st[r] = mn;
        rs[r] = 0.f;
      }
#pragma unroll
      for (int nt = 0; nt < 4; ++nt)
#pragma unroll
        for (int r = 0; r < 4; ++r) {
          const float p = exp2f(sc[nt][r] - m_st[r]);
          sc[nt][r] = p;
          rs[r] += p;
        }
#pragma unroll
      for (int mask = 1; mask <= 8; mask <<= 1)
#pragma unroll
        for (int r = 0; r < 4; ++r) rs[r] += __shfl_xor(rs[r], mask, 64);
#pragma unroll
      for (int r = 0; r < 4; ++r) l_st[r] = l_st[r] * al[r] + rs[r];

#pragma unroll
      for (int nt = 0; nt < 4; ++nt)
#pragma unroll
        for (int r = 0; r < 4; ++r)
          Ps[(wave * 16 + quad * 4 + r) * LV + nt * 16 + l15] = f2bf(sc[nt][r]);
      __builtin_amdgcn_wave_barrier();

#pragma unroll
      for (int nt = 0; nt < 8; ++nt)
#pragma unroll
        for (int r = 0; r < 4; ++r) o[nt][r] *= al[r];
    }

    if (!last) {
      asm volatile("s_waitcnt vmcnt(3)" ::: "memory");
    } else {
      asm volatile("s_waitcnt vmcnt(0)" ::: "memory");
    }
    __builtin_amdgcn_s_barrier();
    asm volatile("" ::: "memory");
    __builtin_amdgcn_sched_barrier(0);

    if (active) {
      __builtin_amdgcn_s_setprio(1);
#pragma unroll
      for (int s = 0; s < 2; ++s) {
        short8 pa = *(const short8*)&Ps[(wave * 16 + l15) * LV + s * 32 + quad * 8];
#pragma unroll
        for (int nt = 0; nt < 8; ++nt) {
          const int f = nt * 16 + l15;
          short8 vb = *(const short8*)&Vt[(f * 8 + ((s * 4 + quad) ^ (f & 7))) * 8];
          o[nt] = __builtin_amdgcn_mfma_f32_16x16x32_bf16(pa, vb, o[nt], 0, 0, 0);
        }
      }
      __builtin_amdgcn_s_setprio(0);
    }

    if (it == n0 - 1) {
      EPI(qtA);
      LOADQ(qf, qtB);
#pragma unroll
      for (int r = 0; r < 4; ++r) { m_st[r] = -1e30f; l_st[r] = 0.f; }
#pragma unroll
      for (int nt = 0; nt < 8; ++nt) { f32x4 z = {0.f, 0.f, 0.f, 0.f}; o[nt] = z; }
    }
  }

  EPI(qtB);
}

// ---------------------------------------------------------------------------
// Launch
// ---------------------------------------------------------------------------
extern "C" void kernel_launch(void* const* d_in, const int* in_sizes, int n_in,
                              void* d_out, int out_size, void* d_ws, size_t ws_size,
                              hipStream_t stream) {
  (void)in_sizes; (void)n_in;
  const float* x         = (const float*)d_in[0];
  const float* wq_down   = (const float*)d_in[1];
  const float* q_norm_w  = (const float*)d_in[2];
  const float* wq_up     = (const float*)d_in[3];
  const float* wq_rope   = (const float*)d_in[4];
  const float* wkv_down  = (const float*)d_in[5];
  const float* kv_norm_w = (const float*)d_in[6];
  const float* wkv_up    = (const float*)d_in[7];
  const float* wk_rope   = (const float*)d_in[8];
  const float* wo        = (const float*)d_in[9];
  float* out = (float*)d_out;

  // ---- workspace carve (identical layout to the passing run)
  const size_t SZ_XBF   = (size_t)TOK_ * DIM_ * 2;
  const size_t SZ_WQD   = (size_t)QR_ * DIM_ * 2;
  const size_t SZ_WKVD  = (size_t)KVR_ * DIM_ * 2;
  const size_t SZ_WKR   = (size_t)ROPE_ * DIM_ * 2;
  const size_t SZ_WQU   = (size_t)H_ * NOPE_ * QR_ * 2;
  const size_t SZ_WQR   = (size_t)H_ * ROPE_ * QR_ * 2;
  const size_t SZ_WKVU  = (size_t)H_ * (NOPE_ + VDIM_) * KVR_ * 2;
  const size_t SZ_WO    = (size_t)DIM_ * H_ * VDIM_ * 2;
  const size_t SZ_QC    = (size_t)TOK_ * QR_ * 4;   // aliases: q_pe fp32, then vt_g
  const size_t SZ_KVC   = (size_t)TOK_ * KVR_ * 4;
  const size_t SZ_QCN   = (size_t)TOK_ * QR_ * 2;
  const size_t SZ_KVCN  = (size_t)TOK_ * KVR_ * 2;
  const size_t SZ_QNOPE = (size_t)TOK_ * H_ * NOPE_ * 2; // aliases attn_o bf16
  const size_t SZ_QPEB  = (size_t)TOK_ * H_ * ROPE_ * 2;
  const size_t SZ_KRF   = (size_t)TOK_ * ROPE_ * 4;
  const size_t SZ_KRB   = (size_t)TOK_ * ROPE_ * 2;
  const size_t SZ_KVUP  = (size_t)TOK_ * H_ * (NOPE_ + VDIM_) * 2;
  const size_t NEED = SZ_XBF + SZ_WQD + SZ_WKVD + SZ_WKR + SZ_WQU + SZ_WQR + SZ_WKVU +
                      SZ_WO + SZ_QC + SZ_KVC + SZ_QCN + SZ_KVCN + SZ_QNOPE + SZ_QPEB +
                      SZ_KRF + SZ_KRB + SZ_KVUP;
  if (ws_size < NEED) {
    hipMemsetAsync(d_out, 0, (size_t)out_size * sizeof(float), stream);
    return;
  }
  char* p = (char*)d_ws;
  unsigned short* x_bf    = (unsigned short*)p; p += SZ_XBF;
  unsigned short* wqd_bf  = (unsigned short*)p; p += SZ_WQD;
  unsigned short* wkvd_bf = (unsigned short*)p; p += SZ_WKVD;
  unsigned short* wkr_bf  = (unsigned short*)p; p += SZ_WKR;
  unsigned short* wqu_bf  = (unsigned short*)p; p += SZ_WQU;
  unsigned short* wqr_bf  = (unsigned short*)p; p += SZ_WQR;
  unsigned short* wkvu_bf = (unsigned short*)p; p += SZ_WKVU;
  unsigned short* wo_bf   = (unsigned short*)p; p += SZ_WO;
  float*          q_c     = (float*)p;          p += SZ_QC;
  float*          kv_c    = (float*)p;          p += SZ_KVC;
  unsigned short* q_cn    = (unsigned short*)p; p += SZ_QCN;
  unsigned short* kv_cn   = (unsigned short*)p; p += SZ_KVCN;
  unsigned short* q_nope  = (unsigned short*)p; p += SZ_QNOPE;
  unsigned short* q_pe_bf = (unsigned short*)p; p += SZ_QPEB;
  float*          k_ropef = (float*)p;          p += SZ_KRF;
  unsigned short* k_ropeb = (unsigned short*)p; p += SZ_KRB;
  unsigned short* kv_upbf = (unsigned short*)p; p += SZ_KVUP;
  float*          q_pe_f  = q_c;                   // q_c dead after rmsnorm
  unsigned short* vt_g    = (unsigned short*)q_c;  // q_pe_f dead after rope_q
  unsigned short* attn_o  = q_nope;                // q_nope dead after flash

  const dim3 blk(256);

  // ---- all fp32->bf16 casts in ONE launch
  cvt_all<<<(C_TOT + 255) / 256, blk, 0, stream>>>(
      x, wq_down, wkv_down, wk_rope, wq_up, wq_rope, wkv_up, wo,
      x_bf, wqd_bf, wkvd_bf, wkr_bf, wqu_bf, wqr_bf, wkvu_bf, wo_bf);

  // ---- fused down projections (q_c | kv_c | k_ropef)
  gemm_down<<<dim3(13, TOK_ / 128), blk, 0, stream>>>(x_bf, wqd_bf, wkvd_bf, wkr_bf,
                                                      q_c, kv_c, k_ropef);

  // ---- both RMSNorms in one launch
  rmsnorm2<<<dim3(TOK_, 2), blk, 0, stream>>>(q_c, q_norm_w, q_cn, kv_c, kv_norm_w, kv_cn);

  // ---- fused q up projections (q_nope bf16 | q_pe_f fp32)
  gemm_upq<<<dim3(24, TOK_ / 128), blk, 0, stream>>>(q_cn, wqu_bf, wqr_bf, q_nope, q_pe_f);

  // ---- kv up projection
  gemm_bf16<unsigned short, 4><<<dim3(H_ * (NOPE_ + VDIM_) / 128, TOK_ / 128), blk, 0, stream>>>(
      kv_cn, wkvu_bf, kv_upbf, TOK_, H_ * (NOPE_ + VDIM_), KVR_);

  // ---- RoPE q+k in one launch (q first in index space; frees q_c for vt_g after)
  rope_all<<<(PAIRS_Q + PAIRS_K + 255) / 256, blk, 0, stream>>>(q_pe_f, q_pe_bf, k_ropef, k_ropeb);

  // ---- V transpose (vt_g aliases q_c region; rope_all already consumed q_pe_f)
  transpose_v<<<dim3(S_ / 64, H_, B_), blk, 0, stream>>>(kv_upbf, vt_g);

  // ---- attention (8-wave blocks, 128-row q-tiles)
  flash_attn_mfma<<<dim3(8, H_, B_), dim3(512), 0, stream>>>(q_nope, q_pe_bf, kv_upbf, k_ropeb, vt_g, attn_o);

  // ---- output projection
  gemm_bf16<float, 4><<<dim3(DIM_ / 128, TOK_ / 128), blk, 0, stream>>>(attn_o, wo_bf, out, TOK_, DIM_, H_ * VDIM_);
}

// Round 6
// 439.619 us; speedup vs baseline: 1.4238x; 1.0825x over previous
//
#include <hip/hip_runtime.h>
#include <hip/hip_bf16.h>
#include <math.h>

// Problem constants (from reference)
#define B_    2
#define S_    2048
#define DIM_  2048
#define H_    16
#define NOPE_ 128
#define ROPE_ 64
#define VDIM_ 128
#define QR_   1024
#define KVR_  512
#define TOK_  (B_ * S_)   // 4096 token rows

typedef __attribute__((ext_vector_type(8))) short short8;   // 8 bf16 (4 VGPRs)
typedef __attribute__((ext_vector_type(4))) float f32x4;    // MFMA acc

// fp32 -> bf16 (round-to-nearest-even), raw ushort
__device__ __forceinline__ unsigned short f2bf(float f) {
  union { float f; unsigned u; } v; v.f = f;
  unsigned r = v.u + 0x7fffu + ((v.u >> 16) & 1u);
  return (unsigned short)(r >> 16);
}
__device__ __forceinline__ unsigned pk2(float lo, float hi) {
  return (unsigned)f2bf(lo) | ((unsigned)f2bf(hi) << 16);
}

// async global->LDS, 16 B per lane; dest = wave-uniform base + lane*16.
__device__ __forceinline__ void gl_lds16(const unsigned short* g, unsigned short* lds_base) {
  __builtin_amdgcn_global_load_lds(
      (const __attribute__((address_space(1))) void*)g,
      (__attribute__((address_space(3))) void*)lds_base,
      16, 0, 0);
}

__device__ __forceinline__ void store_out(float* p, float v) { *p = v; }
__device__ __forceinline__ void store_out(unsigned short* p, float v) { *p = f2bf(v); }

// ---------------------------------------------------------------------------
// ONE-SHOT cast: all 8 fp32->bf16 conversions in a single launch.
// ---------------------------------------------------------------------------
#define C_X    (TOK_ * DIM_ / 8)
#define C_WQD  (QR_ * DIM_ / 8)
#define C_WKVD (KVR_ * DIM_ / 8)
#define C_WKR  (ROPE_ * DIM_ / 8)
#define C_WQU  (H_ * NOPE_ * QR_ / 8)
#define C_WQR  (H_ * ROPE_ * QR_ / 8)
#define C_WKVU (H_ * (NOPE_ + VDIM_) * KVR_ / 8)
#define C_WO   (DIM_ * H_ * VDIM_ / 8)
#define C_TOT  (C_X + C_WQD + C_WKVD + C_WKR + C_WQU + C_WQR + C_WKVU + C_WO)

__global__ __launch_bounds__(256) void cvt_all(
    const float* __restrict__ x, const float* __restrict__ wqd, const float* __restrict__ wkvd,
    const float* __restrict__ wkr, const float* __restrict__ wqu, const float* __restrict__ wqr,
    const float* __restrict__ wkvu, const float* __restrict__ wo,
    unsigned short* __restrict__ xo, unsigned short* __restrict__ wqdo,
    unsigned short* __restrict__ wkvdo, unsigned short* __restrict__ wkro,
    unsigned short* __restrict__ wquo, unsigned short* __restrict__ wqro,
    unsigned short* __restrict__ wkvuo, unsigned short* __restrict__ woo) {
  int i = blockIdx.x * 256 + threadIdx.x;
  if (i >= C_TOT) return;
  const float* in; unsigned short* out;
  if (i < C_X) { in = x; out = xo; }
  else if ((i -= C_X) < C_WQD) { in = wqd; out = wqdo; }
  else if ((i -= C_WQD) < C_WKVD) { in = wkvd; out = wkvdo; }
  else if ((i -= C_WKVD) < C_WKR) { in = wkr; out = wkro; }
  else if ((i -= C_WKR) < C_WQU) { in = wqu; out = wquo; }
  else if ((i -= C_WQU) < C_WQR) { in = wqr; out = wqro; }
  else if ((i -= C_WQR) < C_WKVU) { in = wkvu; out = wkvuo; }
  else { i -= C_WKVU; in = wo; out = woo; }
  float4 f0 = *(const float4*)(in + (size_t)i * 8);
  float4 f1 = *(const float4*)(in + (size_t)i * 8 + 4);
  uint4 u;
  u.x = pk2(f0.x, f0.y); u.y = pk2(f0.z, f0.w);
  u.z = pk2(f1.x, f1.y); u.w = pk2(f1.z, f1.w);
  *(uint4*)&out[(size_t)i * 8] = u;
}

// ---------------------------------------------------------------------------
// MFMA GEMM: C[M x N] = A[M x K] @ B[N x K]^T. bf16 in, OutT out.
// ---------------------------------------------------------------------------
template <typename OutT, int NT>
__global__ __launch_bounds__(256) void gemm_bf16(const unsigned short* __restrict__ A,
                                                 const unsigned short* __restrict__ Bm,
                                                 OutT* __restrict__ C,
                                                 int M, int N, int K) {
  constexpr int BN = NT * 32;
  __shared__ unsigned short As[128 * 32];
  __shared__ unsigned short Bs[BN * 32];
  const int tid  = threadIdx.x;
  const int wave = tid >> 6;
  const int lane = tid & 63;
  const int quad = lane >> 4;
  const int l15  = lane & 15;
  const int m0 = blockIdx.y * 128;
  const int n0 = blockIdx.x * BN;
  const int wm = (wave & 1) * 64;
  const int wn = (wave >> 1) * (NT * 16);

  f32x4 acc[4][NT];
#pragma unroll
  for (int i = 0; i < 4; ++i)
#pragma unroll
    for (int j = 0; j < NT; ++j) {
      f32x4 z = {0.f, 0.f, 0.f, 0.f};
      acc[i][j] = z;
    }

  for (int k0 = 0; k0 < K; k0 += 32) {
    __syncthreads();
#pragma unroll
    for (int i = 0; i < 2; ++i) {
      const int s = i * 256 + tid;
      const int srow = s >> 2;
      const int sq = (s & 3) ^ ((srow >> 1) & 3);
      gl_lds16(A + (size_t)(m0 + srow) * K + k0 + sq * 8, &As[(i * 256 + wave * 64) * 8]);
    }
#pragma unroll
    for (int i = 0; i < BN / 64; ++i) {
      const int s = i * 256 + tid;
      const int srow = s >> 2;
      const int sq = (s & 3) ^ ((srow >> 1) & 3);
      const int rb = min(n0 + srow, N - 1);
      gl_lds16(Bm + (size_t)rb * K + k0 + sq * 8, &Bs[(i * 256 + wave * 64) * 8]);
    }
    __syncthreads();

    short8 a[4], b[NT];
#pragma unroll
    for (int i = 0; i < 4; ++i) {
      const int r = wm + i * 16 + l15;
      a[i] = *(const short8*)&As[(r * 4 + (quad ^ ((r >> 1) & 3))) * 8];
    }
#pragma unroll
    for (int j = 0; j < NT; ++j) {
      const int r = wn + j * 16 + l15;
      b[j] = *(const short8*)&Bs[(r * 4 + (quad ^ ((r >> 1) & 3))) * 8];
    }
#pragma unroll
    for (int i = 0; i < 4; ++i)
#pragma unroll
      for (int j = 0; j < NT; ++j)
        acc[i][j] = __builtin_amdgcn_mfma_f32_16x16x32_bf16(a[i], b[j], acc[i][j], 0, 0, 0);
  }

#pragma unroll
  for (int i = 0; i < 4; ++i) {
#pragma unroll
    for (int j = 0; j < NT; ++j) {
      const int col = n0 + wn + j * 16 + l15;
      if (col < N) {
#pragma unroll
        for (int r = 0; r < 4; ++r) {
          const int row = m0 + wm + i * 16 + quad * 4 + r;
          store_out(&C[(size_t)row * N + col], acc[i][j][r]);
        }
      }
    }
  }
}

// ---------------------------------------------------------------------------
// FUSED down-projection GEMM: x_bf @ {wq_down, wkv_down, wk_rope}^T (13 n-tiles)
// ---------------------------------------------------------------------------
__global__ __launch_bounds__(256) void gemm_down(const unsigned short* __restrict__ A,
                                                 const unsigned short* __restrict__ Bq,
                                                 const unsigned short* __restrict__ Bkv,
                                                 const unsigned short* __restrict__ Bkr,
                                                 float* __restrict__ Cq,
                                                 float* __restrict__ Ckv,
                                                 float* __restrict__ Ckr) {
  constexpr int K = DIM_;
  __shared__ unsigned short As[128 * 32];
  __shared__ unsigned short Bs[128 * 32];
  const int tid  = threadIdx.x;
  const int wave = tid >> 6;
  const int lane = tid & 63;
  const int quad = lane >> 4;
  const int l15  = lane & 15;
  const int m0 = blockIdx.y * 128;
  const int t  = blockIdx.x;   // 0..12

  const unsigned short* Bm; float* C; int n0, NB;
  if (t < 8)       { Bm = Bq;  C = Cq;  n0 = t * 128;        NB = QR_;  }
  else if (t < 12) { Bm = Bkv; C = Ckv; n0 = (t - 8) * 128;  NB = KVR_; }
  else             { Bm = Bkr; C = Ckr; n0 = 0;              NB = ROPE_; }

  const int wm = (wave & 1) * 64;
  const int wn = (wave >> 1) * 64;

  f32x4 acc[4][4];
#pragma unroll
  for (int i = 0; i < 4; ++i)
#pragma unroll
    for (int j = 0; j < 4; ++j) { f32x4 z = {0.f, 0.f, 0.f, 0.f}; acc[i][j] = z; }

  for (int k0 = 0; k0 < K; k0 += 32) {
    __syncthreads();
#pragma unroll
    for (int i = 0; i < 2; ++i) {
      const int s = i * 256 + tid;
      const int srow = s >> 2;
      const int sq = (s & 3) ^ ((srow >> 1) & 3);
      gl_lds16(A + (size_t)(m0 + srow) * K + k0 + sq * 8, &As[(i * 256 + wave * 64) * 8]);
    }
#pragma unroll
    for (int i = 0; i < 2; ++i) {
      const int s = i * 256 + tid;
      const int srow = s >> 2;
      const int sq = (s & 3) ^ ((srow >> 1) & 3);
      const int rb = min(n0 + srow, NB - 1);
      gl_lds16(Bm + (size_t)rb * K + k0 + sq * 8, &Bs[(i * 256 + wave * 64) * 8]);
    }
    __syncthreads();

    short8 a[4], b[4];
#pragma unroll
    for (int i = 0; i < 4; ++i) {
      const int r = wm + i * 16 + l15;
      a[i] = *(const short8*)&As[(r * 4 + (quad ^ ((r >> 1) & 3))) * 8];
    }
#pragma unroll
    for (int j = 0; j < 4; ++j) {
      const int r = wn + j * 16 + l15;
      b[j] = *(const short8*)&Bs[(r * 4 + (quad ^ ((r >> 1) & 3))) * 8];
    }
#pragma unroll
    for (int i = 0; i < 4; ++i)
#pragma unroll
      for (int j = 0; j < 4; ++j)
        acc[i][j] = __builtin_amdgcn_mfma_f32_16x16x32_bf16(a[i], b[j], acc[i][j], 0, 0, 0);
  }

#pragma unroll
  for (int i = 0; i < 4; ++i) {
#pragma unroll
    for (int j = 0; j < 4; ++j) {
      const int col = n0 + wn + j * 16 + l15;
      if (col < NB) {
#pragma unroll
        for (int r = 0; r < 4; ++r) {
          const int row = m0 + wm + i * 16 + quad * 4 + r;
          C[(size_t)row * NB + col] = acc[i][j][r];
        }
      }
    }
  }
}

// ---------------------------------------------------------------------------
// FUSED q up-projection GEMM: q_cn @ {wq_up, wq_rope}^T (24 n-tiles)
// ---------------------------------------------------------------------------
__global__ __launch_bounds__(256) void gemm_upq(const unsigned short* __restrict__ A,
                                                const unsigned short* __restrict__ Bn,
                                                const unsigned short* __restrict__ Br,
                                                unsigned short* __restrict__ Cn,
                                                float* __restrict__ Cr) {
  constexpr int K = QR_;
  __shared__ unsigned short As[128 * 32];
  __shared__ unsigned short Bs[128 * 32];
  const int tid  = threadIdx.x;
  const int wave = tid >> 6;
  const int lane = tid & 63;
  const int quad = lane >> 4;
  const int l15  = lane & 15;
  const int m0 = blockIdx.y * 128;
  const int t  = blockIdx.x;   // 0..23
  const bool isn = (t < 16);
  const unsigned short* Bm = isn ? Bn : Br;
  const int n0 = isn ? t * 128 : (t - 16) * 128;
  const int NB = isn ? (H_ * NOPE_) : (H_ * ROPE_);

  const int wm = (wave & 1) * 64;
  const int wn = (wave >> 1) * 64;

  f32x4 acc[4][4];
#pragma unroll
  for (int i = 0; i < 4; ++i)
#pragma unroll
    for (int j = 0; j < 4; ++j) { f32x4 z = {0.f, 0.f, 0.f, 0.f}; acc[i][j] = z; }

  for (int k0 = 0; k0 < K; k0 += 32) {
    __syncthreads();
#pragma unroll
    for (int i = 0; i < 2; ++i) {
      const int s = i * 256 + tid;
      const int srow = s >> 2;
      const int sq = (s & 3) ^ ((srow >> 1) & 3);
      gl_lds16(A + (size_t)(m0 + srow) * K + k0 + sq * 8, &As[(i * 256 + wave * 64) * 8]);
    }
#pragma unroll
    for (int i = 0; i < 2; ++i) {
      const int s = i * 256 + tid;
      const int srow = s >> 2;
      const int sq = (s & 3) ^ ((srow >> 1) & 3);
      const int rb = min(n0 + srow, NB - 1);
      gl_lds16(Bm + (size_t)rb * K + k0 + sq * 8, &Bs[(i * 256 + wave * 64) * 8]);
    }
    __syncthreads();

    short8 a[4], b[4];
#pragma unroll
    for (int i = 0; i < 4; ++i) {
      const int r = wm + i * 16 + l15;
      a[i] = *(const short8*)&As[(r * 4 + (quad ^ ((r >> 1) & 3))) * 8];
    }
#pragma unroll
    for (int j = 0; j < 4; ++j) {
      const int r = wn + j * 16 + l15;
      b[j] = *(const short8*)&Bs[(r * 4 + (quad ^ ((r >> 1) & 3))) * 8];
    }
#pragma unroll
    for (int i = 0; i < 4; ++i)
#pragma unroll
      for (int j = 0; j < 4; ++j)
        acc[i][j] = __builtin_amdgcn_mfma_f32_16x16x32_bf16(a[i], b[j], acc[i][j], 0, 0, 0);
  }

#pragma unroll
  for (int i = 0; i < 4; ++i) {
#pragma unroll
    for (int j = 0; j < 4; ++j) {
      const int col = n0 + wn + j * 16 + l15;
#pragma unroll
      for (int r = 0; r < 4; ++r) {
        const int row = m0 + wm + i * 16 + quad * 4 + r;
        if (isn) Cn[(size_t)row * (H_ * NOPE_) + col] = f2bf(acc[i][j][r]);
        else     Cr[(size_t)row * (H_ * ROPE_) + col] = acc[i][j][r];
      }
    }
  }
}

// ---------------------------------------------------------------------------
// RMSNorm (both q and kv in one launch): grid (TOK_, 2).
// ---------------------------------------------------------------------------
__global__ __launch_bounds__(256) void rmsnorm2(const float* __restrict__ xq,
                                                const float* __restrict__ wq,
                                                unsigned short* __restrict__ oq,
                                                const float* __restrict__ xkv,
                                                const float* __restrict__ wkv,
                                                unsigned short* __restrict__ okv) {
  __shared__ float red[256];
  const bool isq = (blockIdx.y == 0);
  const int n = isq ? QR_ : KVR_;
  const float* x = isq ? xq : xkv;
  const float* w = isq ? wq : wkv;
  unsigned short* o = isq ? oq : okv;
  const int row = blockIdx.x;
  const float* p = x + (size_t)row * n;
  float s = 0.f;
  for (int i = threadIdx.x; i < n; i += 256) { float v = p[i]; s += v * v; }
  red[threadIdx.x] = s;
  __syncthreads();
  for (int off = 128; off > 0; off >>= 1) {
    if (threadIdx.x < off) red[threadIdx.x] += red[threadIdx.x + off];
    __syncthreads();
  }
  const float inv = rsqrtf(red[0] / (float)n + 1e-6f);
  unsigned short* po = o + (size_t)row * n;
  for (int i = threadIdx.x; i < n; i += 256) po[i] = f2bf(p[i] * inv * w[i]);
}

// ---------------------------------------------------------------------------
// Interleaved RoPE, q and k fused in one launch. pos = row % S.
// ---------------------------------------------------------------------------
#define PAIRS_Q (TOK_ * H_ * 32)
#define PAIRS_K (TOK_ * 32)

__global__ void rope_all(const float* __restrict__ qin, unsigned short* __restrict__ qout,
                         const float* __restrict__ kin, unsigned short* __restrict__ kout) {
  int idx = blockIdx.x * blockDim.x + threadIdx.x;
  if (idx >= PAIRS_Q + PAIRS_K) return;
  int heads, id;
  const float* xin; unsigned short* xout;
  if (idx < PAIRS_Q) { heads = H_; xin = qin; xout = qout; id = idx; }
  else { heads = 1; xin = kin; xout = kout; id = idx - PAIRS_Q; }
  const int i = id & 31;
  const int h = (id >> 5) % heads;
  const int row = id / (32 * heads);
  const int pos = row & (S_ - 1);
  const float freq = expf(-9.210340371976184f * (float)i / 32.0f);
  const float ang = (float)pos * freq;
  const float c = cosf(ang), sn = sinf(ang);
  const float* p = xin + ((size_t)row * heads + h) * 64 + 2 * i;
  unsigned short* q = xout + ((size_t)row * heads + h) * 64 + 2 * i;
  const float x1 = p[0], x2 = p[1];
  q[0] = f2bf(x1 * c - x2 * sn);
  q[1] = f2bf(x1 * sn + x2 * c);
}

// ---------------------------------------------------------------------------
// One-shot V transpose: kv_up V-part -> vt_g[b][h][feat][key]
// ---------------------------------------------------------------------------
__global__ __launch_bounds__(256) void transpose_v(const unsigned short* __restrict__ kv_up,
                                                   unsigned short* __restrict__ vt_g) {
  __shared__ unsigned short T[128 * 72];
  const int tid = threadIdx.x;
  const int k0 = blockIdx.x * 64;
  const int h = blockIdx.y, b = blockIdx.z;
  const size_t tok0 = (size_t)b * S_;
#pragma unroll
  for (int i = 0; i < 2; ++i) {
    const int u = i * 256 + tid;
    const int kp = u >> 4, c8 = u & 15;
    const unsigned short* p0 =
        kv_up + (tok0 + k0 + 2 * kp) * (size_t)(H_ * 256) + h * 256 + NOPE_ + c8 * 8;
    union { uint4 v; unsigned short s[8]; } r0, r1;
    r0.v = *(const uint4*)p0;
    r1.v = *(const uint4*)(p0 + H_ * 256);
#pragma unroll
    for (int j = 0; j < 8; ++j)
      *(unsigned*)&T[(c8 * 8 + j) * 72 + 2 * kp] = (unsigned)r0.s[j] | ((unsigned)r1.s[j] << 16);
  }
  __syncthreads();
#pragma unroll
  for (int i = 0; i < 4; ++i) {
    const int sl = i * 256 + tid;
    const int f = sl >> 3, c = sl & 7;
    *(uint4*)(vt_g + ((size_t)(b * H_ + h) * 128 + f) * S_ + k0 + c * 8) =
        *(const uint4*)&T[f * 72 + c * 8];
  }
}

// ---------------------------------------------------------------------------
// MFMA flash attention: 8-wave block, 128-row Q-tile, *** 128-key K/V tiles ***.
// R5 post-mortem: 9360 cyc/iter at KVBLK=64, of which ~7700 is fixed per-iter
// overhead (3 barriers, 2 vmcnt waits, 8-stage shfl chains, Ps round-trip) --
// none scales with keys. KVBLK=128 halves iterations (34 -> 17, exactly 17
// for every block: phase-A qtA+1 tiles + phase-B qtB+1 tiles, qtA=15-p,
// qtB=p) so the fixed overhead per key halves; cross-lane reduce stays 4
// stages (extra keys fold into the in-register tree). PV runs in two 64-key
// halves through the same 18KB Ps buffer (wave-private rows; same-wave DS
// ordering makes read-then-overwrite safe).
// LDS: Ksn 2x32 + Ksr 2x16 + Vt 32 + Ps 18 = 146 KB (1 block/CU, unchanged).
// XCD co-location swizzle: remap linear block id so the 8 blocks sharing
// (h,b) (same K/V working set) get ids congruent mod 8 -> same XCD L2 under
// round-robin dispatch (heuristic only; correctness unaffected). 4 groups x
// 8 blocks = 32 blocks per XCD = its 32 CUs.
// Sync per iter (counted vmcnt, never 0 in main loop):
//   barrier#1 (WAR) ; stage V(cur) [4] ; stage K(nxt) [6]
//   vmcnt(10) = cur K landed ; barrier#2 ; QK^T(48 MFMA) + softmax + Ps half0
//   vmcnt(6)  = my V landed  ; barrier#3 ; PV kb0,1 ; Ps half1 ; PV kb2,3
// attn_o aliases q_nope: all cross-tile reads are same-block, read-before-
// write in program order (pairing {15-p, p}, p in 0..7 -> disjoint blocks).
// ---------------------------------------------------------------------------
#define LV 72    // Ps stride (64 + 8 pad)

__global__ __launch_bounds__(512) void flash_attn_mfma(const unsigned short* q_nope,
                                                       const unsigned short* __restrict__ q_pe,
                                                       const unsigned short* __restrict__ kv_up,
                                                       const unsigned short* __restrict__ k_rope,
                                                       const unsigned short* __restrict__ vt_g,
                                                       unsigned short* attn_o) {
  __shared__ unsigned short Ksn[2][128 * 16 * 8];  // 2 x 32 KB: 128 keys x 128 nope-feats
  __shared__ unsigned short Ksr[2][128 * 8 * 8];   // 2 x 16 KB: 128 keys x 64 rope-feats
  __shared__ unsigned short Vt[128 * 16 * 8];      //     32 KB: 128 feats x 128 keys
  __shared__ unsigned short Ps[128 * LV];          //     18 KB (128 q-rows x 64 keys)

  const int tid  = threadIdx.x;
  const int wave = tid >> 6;    // 0..7
  const int lane = tid & 63;
  const int quad = lane >> 4;
  const int l15  = lane & 15;
  // XCD co-location swizzle: l = 0..255; c = l&7 (xcd under round-robin),
  // m = l>>3; 4 (h,b) groups per xcd, 8 pair-members per group.
  const int l   = blockIdx.x + 8 * blockIdx.y + 128 * blockIdx.z;
  const int c_  = l & 7;
  const int m_  = l >> 3;
  const int pair = m_ & 7;             // 0..7
  const int hb   = c_ * 4 + (m_ >> 3); // 0..31
  const int h  = hb & 15;
  const int b  = hb >> 4;
  const size_t tok0 = (size_t)b * S_;
  const float scale2 = 0.07216878364870323f * 1.4426950408889634f;  // 1/sqrt(192)*log2e
  const int qtA = 15 - pair;    // phase-0 q-tile (128 rows); also # K-tiles - 1
  const int qtB = pair;
  const int nA  = qtA + 1;      // iterations in phase 0; total always 17

  auto LOADQ = [&](short8* qf, int qt) {
    const size_t qrow = tok0 + qt * 128 + wave * 16 + l15;
    const unsigned short* pn = q_nope + qrow * (size_t)(H_ * NOPE_) + h * NOPE_;
    const unsigned short* pp = q_pe + qrow * (size_t)(H_ * ROPE_) + h * ROPE_;
#pragma unroll
    for (int s = 0; s < 4; ++s) qf[s] = *(const short8*)(pn + s * 32 + quad * 8);
#pragma unroll
    for (int s = 4; s < 6; ++s) qf[s] = *(const short8*)(pp + (s - 4) * 32 + quad * 8);
  };

  // K staging: 6 loads/thread (Ksn 4 + Ksr 2). 128 keys.
  auto STAGE_K = [&](int bi, int kt) {
    const int k0 = kt * 128;
#pragma unroll
    for (int i = 0; i < 4; ++i) {
      const int sl = i * 512 + tid;          // 2048 slots: key 0..127, chunk 0..15
      const int key = sl >> 4;
      const int c = (sl & 15) ^ (key & 15);
      gl_lds16(kv_up + (tok0 + k0 + key) * (size_t)(H_ * 256) + h * 256 + c * 8,
               &Ksn[bi][(i * 512 + wave * 64) * 8]);
    }
#pragma unroll
    for (int i = 0; i < 2; ++i) {
      const int sl = i * 512 + tid;          // 1024 slots: key 0..127, chunk 0..7
      const int key = sl >> 3;
      const int c = (sl & 7) ^ (key & 7);
      gl_lds16(k_rope + (tok0 + k0 + key) * (size_t)ROPE_ + c * 8,
               &Ksr[bi][(i * 512 + wave * 64) * 8]);
    }
  };
  // V staging: 4 loads/thread. 128 feats x 128 keys (16 chunks of 8 keys).
  auto STAGE_V = [&](int kt) {
    const int k0 = kt * 128;
#pragma unroll
    for (int i = 0; i < 4; ++i) {
      const int sl = i * 512 + tid;          // 2048 slots: feat 0..127, chunk 0..15
      const int f = sl >> 4;
      const int c = (sl & 15) ^ (f & 15);
      gl_lds16(vt_g + ((size_t)(b * H_ + h) * 128 + f) * S_ + k0 + c * 8,
               &Vt[(i * 512 + wave * 64) * 8]);
    }
  };

  short8 qf[6];
  LOADQ(qf, qtA);

  float m_st[4], l_st[4];
  f32x4 o[8];
#pragma unroll
  for (int r = 0; r < 4; ++r) { m_st[r] = -1e30f; l_st[r] = 0.f; }
#pragma unroll
  for (int nt = 0; nt < 8; ++nt) { f32x4 z = {0.f, 0.f, 0.f, 0.f}; o[nt] = z; }

  auto EPI = [&](int qt) {
    float invl[4];
#pragma unroll
    for (int r = 0; r < 4; ++r) invl[r] = 1.f / l_st[r];
#pragma unroll
    for (int nt = 0; nt < 8; ++nt)
#pragma unroll
      for (int r = 0; r < 4; ++r) {
        const size_t row = tok0 + qt * 128 + wave * 16 + quad * 4 + r;
        attn_o[row * (size_t)(H_ * VDIM_) + h * VDIM_ + nt * 16 + l15] =
            f2bf(o[nt][r] * invl[r]);
      }
  };

  STAGE_K(0, 0);   // prologue: 6 outstanding

  for (int it = 0; it < 17; ++it) {
    const int cur = it & 1;
    const int nxt = cur ^ 1;
    const bool ph1 = (it >= nA);
    const int qt = ph1 ? qtB : qtA;
    const int kt = ph1 ? (it - nA) : it;
    const bool last = (it + 1 >= 17);

    // #1 WAR: all waves done reading Vt (prev PV) and Ksn/Ksr[nxt] (prev QK^T).
    __builtin_amdgcn_s_barrier();
    asm volatile("" ::: "memory");

    STAGE_V(kt);                                    // 4 loads, current tile
    if (!last) {
      const int it2 = it + 1;
      const int kt2 = (it2 >= nA) ? (it2 - nA) : it2;
      STAGE_K(nxt, kt2);                            // 6 loads, next tile
      asm volatile("s_waitcnt vmcnt(10)" ::: "memory");  // cur K landed (mine)
    } else {
      asm volatile("s_waitcnt vmcnt(4)" ::: "memory");
    }
    // #2 RAW: ALL waves' K loads for tile `it` landed.
    __builtin_amdgcn_s_barrier();
    asm volatile("" ::: "memory");
    __builtin_amdgcn_sched_barrier(0);

    // --- S = Q K^T (wave strip 16 x 128): 48 MFMA ---
    f32x4 sacc[8];
#pragma unroll
    for (int nt = 0; nt < 8; ++nt) { f32x4 z = {0.f, 0.f, 0.f, 0.f}; sacc[nt] = z; }
    __builtin_amdgcn_s_setprio(1);
#pragma unroll
    for (int s = 0; s < 4; ++s) {
#pragma unroll
      for (int nt = 0; nt < 8; ++nt) {
        const int key = nt * 16 + l15;
        short8 kb = *(const short8*)&Ksn[cur][(key * 16 + ((s * 4 + quad) ^ (key & 15))) * 8];
        sacc[nt] = __builtin_amdgcn_mfma_f32_16x16x32_bf16(qf[s], kb, sacc[nt], 0, 0, 0);
      }
    }
#pragma unroll
    for (int s = 4; s < 6; ++s) {
#pragma unroll
      for (int nt = 0; nt < 8; ++nt) {
        const int key = nt * 16 + l15;
        short8 kb = *(const short8*)&Ksr[cur][(key * 8 + (((s - 4) * 4 + quad) ^ (key & 7))) * 8];
        sacc[nt] = __builtin_amdgcn_mfma_f32_16x16x32_bf16(qf[s], kb, sacc[nt], 0, 0, 0);
      }
    }
    __builtin_amdgcn_s_setprio(0);

    float sc[8][4];
#pragma unroll
    for (int nt = 0; nt < 8; ++nt)
#pragma unroll
      for (int r = 0; r < 4; ++r) sc[nt][r] = sacc[nt][r] * scale2;
    if (kt == qt) {  // diagonal tile (uniform branch); tile == q-tile width
      const int rw = wave * 16 + quad * 4;
#pragma unroll
      for (int nt = 0; nt < 8; ++nt)
#pragma unroll
        for (int r = 0; r < 4; ++r)
          if ((nt * 16 + l15) > (rw + r)) sc[nt][r] = -1e30f;
    }

    float mt[4];
#pragma unroll
    for (int r = 0; r < 4; ++r) {
      float a0 = fmaxf(fmaxf(sc[0][r], sc[1][r]), fmaxf(sc[2][r], sc[3][r]));
      float a1 = fmaxf(fmaxf(sc[4][r], sc[5][r]), fmaxf(sc[6][r], sc[7][r]));
      mt[r] = fmaxf(a0, a1);
    }
#pragma unroll
    for (int mask = 1; mask <= 8; mask <<= 1)
#pragma unroll
      for (int r = 0; r < 4; ++r) mt[r] = fmaxf(mt[r], __shfl_xor(mt[r], mask, 64));

    float al[4], rs[4];
#pragma unroll
    for (int r = 0; r < 4; ++r) {
      const float mn = fmaxf(m_st[r], mt[r]);
      al[r] = exp2f(m_st[r] - mn);
      m_st[r] = mn;
      rs[r] = 0.f;
    }
#pragma unroll
    for (int nt = 0; nt < 8; ++nt)
#pragma unroll
      for (int r = 0; r < 4; ++r) {
        const float p = exp2f(sc[nt][r] - m_st[r]);
        sc[nt][r] = p;
        rs[r] += p;
      }
#pragma unroll
    for (int mask = 1; mask <= 8; mask <<= 1)
#pragma unroll
      for (int r = 0; r < 4; ++r) rs[r] += __shfl_xor(rs[r], mask, 64);
#pragma unroll
    for (int r = 0; r < 4; ++r) l_st[r] = l_st[r] * al[r] + rs[r];

    // --- P half0 (keys 0..63) -> Ps (wave-private rows) ---
#pragma unroll
    for (int nt = 0; nt < 4; ++nt)
#pragma unroll
      for (int r = 0; r < 4; ++r)
        Ps[(wave * 16 + quad * 4 + r) * LV + nt * 16 + l15] = f2bf(sc[nt][r]);
    __builtin_amdgcn_wave_barrier();

    // --- O *= alpha (covers V landing) ---
#pragma unroll
    for (int nt = 0; nt < 8; ++nt)
#pragma unroll
      for (int r = 0; r < 4; ++r) o[nt][r] *= al[r];

    // #3 RAW: ALL waves' V loads landed.
    if (!last) {
      asm volatile("s_waitcnt vmcnt(6)" ::: "memory");
    } else {
      asm volatile("s_waitcnt vmcnt(0)" ::: "memory");
    }
    __builtin_amdgcn_s_barrier();
    asm volatile("" ::: "memory");
    __builtin_amdgcn_sched_barrier(0);

    // --- O += P V, keys 0..63 (kb 0,1) ---
    __builtin_amdgcn_s_setprio(1);
#pragma unroll
    for (int kb = 0; kb < 2; ++kb) {
      short8 pa = *(const short8*)&Ps[(wave * 16 + l15) * LV + kb * 32 + quad * 8];
#pragma unroll
      for (int nt = 0; nt < 8; ++nt) {
        const int f = nt * 16 + l15;
        short8 vb = *(const short8*)&Vt[(f * 16 + ((kb * 4 + quad) ^ (f & 15))) * 8];
        o[nt] = __builtin_amdgcn_mfma_f32_16x16x32_bf16(pa, vb, o[nt], 0, 0, 0);
      }
    }
    __builtin_amdgcn_s_setprio(0);

    // --- P half1 (keys 64..127) -> Ps (same wave-private rows; same-wave DS
    //     ordering puts these writes after the kb0/1 reads) ---
#pragma unroll
    for (int nt = 4; nt < 8; ++nt)
#pragma unroll
      for (int r = 0; r < 4; ++r)
        Ps[(wave * 16 + quad * 4 + r) * LV + (nt - 4) * 16 + l15] = f2bf(sc[nt][r]);
    __builtin_amdgcn_wave_barrier();

    // --- O += P V, keys 64..127 (kb 2,3) ---
    __builtin_amdgcn_s_setprio(1);
#pragma unroll
    for (int kb = 2; kb < 4; ++kb) {
      short8 pa = *(const short8*)&Ps[(wave * 16 + l15) * LV + (kb - 2) * 32 + quad * 8];
#pragma unroll
      for (int nt = 0; nt < 8; ++nt) {
        const int f = nt * 16 + l15;
        short8 vb = *(const short8*)&Vt[(f * 16 + ((kb * 4 + quad) ^ (f & 15))) * 8];
        o[nt] = __builtin_amdgcn_mfma_f32_16x16x32_bf16(pa, vb, o[nt], 0, 0, 0);
      }
    }
    __builtin_amdgcn_s_setprio(0);

    // Phase boundary: flush q-tile A, reload Q for tile B, reset state.
    if (it == nA - 1) {
      EPI(qtA);
      LOADQ(qf, qtB);
#pragma unroll
      for (int r = 0; r < 4; ++r) { m_st[r] = -1e30f; l_st[r] = 0.f; }
#pragma unroll
      for (int nt = 0; nt < 8; ++nt) { f32x4 z = {0.f, 0.f, 0.f, 0.f}; o[nt] = z; }
    }
  }

  EPI(qtB);
}

// ---------------------------------------------------------------------------
// Launch
// ---------------------------------------------------------------------------
extern "C" void kernel_launch(void* const* d_in, const int* in_sizes, int n_in,
                              void* d_out, int out_size, void* d_ws, size_t ws_size,
                              hipStream_t stream) {
  (void)in_sizes; (void)n_in;
  const float* x         = (const float*)d_in[0];
  const float* wq_down   = (const float*)d_in[1];
  const float* q_norm_w  = (const float*)d_in[2];
  const float* wq_up     = (const float*)d_in[3];
  const float* wq_rope   = (const float*)d_in[4];
  const float* wkv_down  = (const float*)d_in[5];
  const float* kv_norm_w = (const float*)d_in[6];
  const float* wkv_up    = (const float*)d_in[7];
  const float* wk_rope   = (const float*)d_in[8];
  const float* wo        = (const float*)d_in[9];
  float* out = (float*)d_out;

  // ---- workspace carve (identical layout to the passing run)
  const size_t SZ_XBF   = (size_t)TOK_ * DIM_ * 2;
  const size_t SZ_WQD   = (size_t)QR_ * DIM_ * 2;
  const size_t SZ_WKVD  = (size_t)KVR_ * DIM_ * 2;
  const size_t SZ_WKR   = (size_t)ROPE_ * DIM_ * 2;
  const size_t SZ_WQU   = (size_t)H_ * NOPE_ * QR_ * 2;
  const size_t SZ_WQR   = (size_t)H_ * ROPE_ * QR_ * 2;
  const size_t SZ_WKVU  = (size_t)H_ * (NOPE_ + VDIM_) * KVR_ * 2;
  const size_t SZ_WO    = (size_t)DIM_ * H_ * VDIM_ * 2;
  const size_t SZ_QC    = (size_t)TOK_ * QR_ * 4;   // aliases: q_pe fp32, then vt_g
  const size_t SZ_KVC   = (size_t)TOK_ * KVR_ * 4;
  const size_t SZ_QCN   = (size_t)TOK_ * QR_ * 2;
  const size_t SZ_KVCN  = (size_t)TOK_ * KVR_ * 2;
  const size_t SZ_QNOPE = (size_t)TOK_ * H_ * NOPE_ * 2; // aliases attn_o bf16
  const size_t SZ_QPEB  = (size_t)TOK_ * H_ * ROPE_ * 2;
  const size_t SZ_KRF   = (size_t)TOK_ * ROPE_ * 4;
  const size_t SZ_KRB   = (size_t)TOK_ * ROPE_ * 2;
  const size_t SZ_KVUP  = (size_t)TOK_ * H_ * (NOPE_ + VDIM_) * 2;
  const size_t NEED = SZ_XBF + SZ_WQD + SZ_WKVD + SZ_WKR + SZ_WQU + SZ_WQR + SZ_WKVU +
                      SZ_WO + SZ_QC + SZ_KVC + SZ_QCN + SZ_KVCN + SZ_QNOPE + SZ_QPEB +
                      SZ_KRF + SZ_KRB + SZ_KVUP;
  if (ws_size < NEED) {
    hipMemsetAsync(d_out, 0, (size_t)out_size * sizeof(float), stream);
    return;
  }
  char* p = (char*)d_ws;
  unsigned short* x_bf    = (unsigned short*)p; p += SZ_XBF;
  unsigned short* wqd_bf  = (unsigned short*)p; p += SZ_WQD;
  unsigned short* wkvd_bf = (unsigned short*)p; p += SZ_WKVD;
  unsigned short* wkr_bf  = (unsigned short*)p; p += SZ_WKR;
  unsigned short* wqu_bf  = (unsigned short*)p; p += SZ_WQU;
  unsigned short* wqr_bf  = (unsigned short*)p; p += SZ_WQR;
  unsigned short* wkvu_bf = (unsigned short*)p; p += SZ_WKVU;
  unsigned short* wo_bf   = (unsigned short*)p; p += SZ_WO;
  float*          q_c     = (float*)p;          p += SZ_QC;
  float*          kv_c    = (float*)p;          p += SZ_KVC;
  unsigned short* q_cn    = (unsigned short*)p; p += SZ_QCN;
  unsigned short* kv_cn   = (unsigned short*)p; p += SZ_KVCN;
  unsigned short* q_nope  = (unsigned short*)p; p += SZ_QNOPE;
  unsigned short* q_pe_bf = (unsigned short*)p; p += SZ_QPEB;
  float*          k_ropef = (float*)p;          p += SZ_KRF;
  unsigned short* k_ropeb = (unsigned short*)p; p += SZ_KRB;
  unsigned short* kv_upbf = (unsigned short*)p; p += SZ_KVUP;
  float*          q_pe_f  = q_c;                   // q_c dead after rmsnorm
  unsigned short* vt_g    = (unsigned short*)q_c;  // q_pe_f dead after rope
  unsigned short* attn_o  = q_nope;                // q_nope dead after flash

  const dim3 blk(256);

  // ---- all fp32->bf16 casts in ONE launch
  cvt_all<<<(C_TOT + 255) / 256, blk, 0, stream>>>(
      x, wq_down, wkv_down, wk_rope, wq_up, wq_rope, wkv_up, wo,
      x_bf, wqd_bf, wkvd_bf, wkr_bf, wqu_bf, wqr_bf, wkvu_bf, wo_bf);

  // ---- fused down projections (q_c | kv_c | k_ropef)
  gemm_down<<<dim3(13, TOK_ / 128), blk, 0, stream>>>(x_bf, wqd_bf, wkvd_bf, wkr_bf,
                                                      q_c, kv_c, k_ropef);

  // ---- both RMSNorms in one launch
  rmsnorm2<<<dim3(TOK_, 2), blk, 0, stream>>>(q_c, q_norm_w, q_cn, kv_c, kv_norm_w, kv_cn);

  // ---- fused q up projections (q_nope bf16 | q_pe_f fp32)
  gemm_upq<<<dim3(24, TOK_ / 128), blk, 0, stream>>>(q_cn, wqu_bf, wqr_bf, q_nope, q_pe_f);

  // ---- kv up projection
  gemm_bf16<unsigned short, 4><<<dim3(H_ * (NOPE_ + VDIM_) / 128, TOK_ / 128), blk, 0, stream>>>(
      kv_cn, wkvu_bf, kv_upbf, TOK_, H_ * (NOPE_ + VDIM_), KVR_);

  // ---- RoPE q+k in one launch
  rope_all<<<(PAIRS_Q + PAIRS_K + 255) / 256, blk, 0, stream>>>(q_pe_f, q_pe_bf, k_ropef, k_ropeb);

  // ---- V transpose (vt_g aliases q_c region; rope_all already consumed q_pe_f)
  transpose_v<<<dim3(S_ / 64, H_, B_), blk, 0, stream>>>(kv_upbf, vt_g);

  // ---- attention (8-wave blocks, 128-row q-tiles, 128-key K/V tiles)
  flash_attn_mfma<<<dim3(8, H_, B_), dim3(512), 0, stream>>>(q_nope, q_pe_bf, kv_upbf, k_ropeb, vt_g, attn_o);

  // ---- output projection
  gemm_bf16<float, 4><<<dim3(DIM_ / 128, TOK_ / 128), blk, 0, stream>>>(attn_o, wo_bf, out, TOK_, DIM_, H_ * VDIM_);
}

// Round 7
// 426.847 us; speedup vs baseline: 1.4664x; 1.0299x over previous
//
#include <hip/hip_runtime.h>
#include <hip/hip_bf16.h>
#include <math.h>

// Problem constants (from reference)
#define B_    2
#define S_    2048
#define DIM_  2048
#define H_    16
#define NOPE_ 128
#define ROPE_ 64
#define VDIM_ 128
#define QR_   1024
#define KVR_  512
#define TOK_  (B_ * S_)   // 4096 token rows

typedef __attribute__((ext_vector_type(8))) short short8;   // 8 bf16 (4 VGPRs)
typedef __attribute__((ext_vector_type(4))) float f32x4;    // MFMA acc

// fp32 -> bf16 (round-to-nearest-even), raw ushort
__device__ __forceinline__ unsigned short f2bf(float f) {
  union { float f; unsigned u; } v; v.f = f;
  unsigned r = v.u + 0x7fffu + ((v.u >> 16) & 1u);
  return (unsigned short)(r >> 16);
}
__device__ __forceinline__ unsigned pk2(float lo, float hi) {
  return (unsigned)f2bf(lo) | ((unsigned)f2bf(hi) << 16);
}

// async global->LDS, 16 B per lane; dest = wave-uniform base + lane*16.
__device__ __forceinline__ void gl_lds16(const unsigned short* g, unsigned short* lds_base) {
  __builtin_amdgcn_global_load_lds(
      (const __attribute__((address_space(1))) void*)g,
      (__attribute__((address_space(3))) void*)lds_base,
      16, 0, 0);
}

// ---------------------------------------------------------------------------
// ONE-SHOT cast: all 8 fp32->bf16 conversions in a single launch.
// ---------------------------------------------------------------------------
#define C_X    (TOK_ * DIM_ / 8)
#define C_WQD  (QR_ * DIM_ / 8)
#define C_WKVD (KVR_ * DIM_ / 8)
#define C_WKR  (ROPE_ * DIM_ / 8)
#define C_WQU  (H_ * NOPE_ * QR_ / 8)
#define C_WQR  (H_ * ROPE_ * QR_ / 8)
#define C_WKVU (H_ * (NOPE_ + VDIM_) * KVR_ / 8)
#define C_WO   (DIM_ * H_ * VDIM_ / 8)
#define C_TOT  (C_X + C_WQD + C_WKVD + C_WKR + C_WQU + C_WQR + C_WKVU + C_WO)

__global__ __launch_bounds__(256) void cvt_all(
    const float* __restrict__ x, const float* __restrict__ wqd, const float* __restrict__ wkvd,
    const float* __restrict__ wkr, const float* __restrict__ wqu, const float* __restrict__ wqr,
    const float* __restrict__ wkvu, const float* __restrict__ wo,
    unsigned short* __restrict__ xo, unsigned short* __restrict__ wqdo,
    unsigned short* __restrict__ wkvdo, unsigned short* __restrict__ wkro,
    unsigned short* __restrict__ wquo, unsigned short* __restrict__ wqro,
    unsigned short* __restrict__ wkvuo, unsigned short* __restrict__ woo) {
  int i = blockIdx.x * 256 + threadIdx.x;
  if (i >= C_TOT) return;
  const float* in; unsigned short* out;
  if (i < C_X) { in = x; out = xo; }
  else if ((i -= C_X) < C_WQD) { in = wqd; out = wqdo; }
  else if ((i -= C_WQD) < C_WKVD) { in = wkvd; out = wkvdo; }
  else if ((i -= C_WKVD) < C_WKR) { in = wkr; out = wkro; }
  else if ((i -= C_WKR) < C_WQU) { in = wqu; out = wquo; }
  else if ((i -= C_WQU) < C_WQR) { in = wqr; out = wqro; }
  else if ((i -= C_WQR) < C_WKVU) { in = wkvu; out = wkvuo; }
  else { i -= C_WKVU; in = wo; out = woo; }
  float4 f0 = *(const float4*)(in + (size_t)i * 8);
  float4 f1 = *(const float4*)(in + (size_t)i * 8 + 4);
  uint4 u;
  u.x = pk2(f0.x, f0.y); u.y = pk2(f0.z, f0.w);
  u.z = pk2(f1.x, f1.y); u.w = pk2(f1.z, f1.w);
  *(uint4*)&out[(size_t)i * 8] = u;
}

// ---------------------------------------------------------------------------
// Pipelined GEMM core: 128x256 tile, BK=64, 512 threads (8 waves, 2M x 4N),
// double-buffered LDS with the flash-proven sync scheme:
//   barrier ; STAGE(next buf) [6 loads/thread] ; vmcnt(6) ; barrier ;
//   16 ds_read_b128 + 32 MFMA per wave
// Counted vmcnt keeps the prefetch in flight across barriers (never drains
// to 0 in the main loop). XOR swizzle = flash Ksr pattern (8 chunks/row).
// K accumulation order identical to the old BK=32 kernel (bit-identical).
// ---------------------------------------------------------------------------
__device__ __forceinline__ void gemm_core_128x256(
    const unsigned short* __restrict__ A, const unsigned short* __restrict__ Bm,
    int K, int NB, int m0, int n0,
    unsigned short (*As)[128 * 64], unsigned short (*Bs)[256 * 64],
    f32x4 acc[4][4]) {
  const int tid  = threadIdx.x;
  const int wave = tid >> 6;
  const int lane = tid & 63;
  const int quad = lane >> 4;
  const int l15  = lane & 15;
  const int wm = (wave & 1) * 64;
  const int wn = (wave >> 1) * 64;

  auto STAGE = [&](int bi, int k0) {
#pragma unroll
    for (int i = 0; i < 2; ++i) {            // A: 128 rows x 8 chunks = 1024 slots
      const int s = i * 512 + tid;
      const int row = s >> 3;
      const int c = (s & 7) ^ (row & 7);
      gl_lds16(A + (size_t)(m0 + row) * K + k0 + c * 8, &As[bi][(i * 512 + wave * 64) * 8]);
    }
#pragma unroll
    for (int i = 0; i < 4; ++i) {            // B: 256 rows x 8 chunks = 2048 slots
      const int s = i * 512 + tid;
      const int row = s >> 3;
      const int c = (s & 7) ^ (row & 7);
      const int rb = min(n0 + row, NB - 1);
      gl_lds16(Bm + (size_t)rb * K + k0 + c * 8, &Bs[bi][(i * 512 + wave * 64) * 8]);
    }
  };

#pragma unroll
  for (int i = 0; i < 4; ++i)
#pragma unroll
    for (int j = 0; j < 4; ++j) { f32x4 z = {0.f, 0.f, 0.f, 0.f}; acc[i][j] = z; }

  const int nk = K >> 6;
  STAGE(0, 0);
  for (int kk = 0; kk < nk; ++kk) {
    const int cur = kk & 1;
    // WAR: all waves done reading buf[cur^1] (previous iteration's compute).
    __builtin_amdgcn_s_barrier();
    asm volatile("" ::: "memory");
    if (kk + 1 < nk) {
      STAGE(cur ^ 1, (kk + 1) * 64);
      asm volatile("s_waitcnt vmcnt(6)" ::: "memory");   // my cur-tile loads landed
    } else {
      asm volatile("s_waitcnt vmcnt(0)" ::: "memory");
    }
    // RAW: ALL waves' cur-tile loads landed.
    __builtin_amdgcn_s_barrier();
    asm volatile("" ::: "memory");
    __builtin_amdgcn_sched_barrier(0);

    short8 a[2][4], b[2][4];
#pragma unroll
    for (int s = 0; s < 2; ++s) {
#pragma unroll
      for (int i = 0; i < 4; ++i) {
        const int r = wm + i * 16 + l15;
        a[s][i] = *(const short8*)&As[cur][(r * 8 + ((s * 4 + quad) ^ (r & 7))) * 8];
      }
#pragma unroll
      for (int j = 0; j < 4; ++j) {
        const int r = wn + j * 16 + l15;
        b[s][j] = *(const short8*)&Bs[cur][(r * 8 + ((s * 4 + quad) ^ (r & 7))) * 8];
      }
    }
    __builtin_amdgcn_s_setprio(1);
#pragma unroll
    for (int s = 0; s < 2; ++s)
#pragma unroll
      for (int i = 0; i < 4; ++i)
#pragma unroll
        for (int j = 0; j < 4; ++j)
          acc[i][j] = __builtin_amdgcn_mfma_f32_16x16x32_bf16(a[s][i], b[s][j], acc[i][j], 0, 0, 0);
    __builtin_amdgcn_s_setprio(0);
  }
}

// ---------------------------------------------------------------------------
// FUSED down projections: x_bf [4096x2048] @ {wq_down, wkv_down, wk_rope}^T
// 7 n-tiles (4 q | 2 kv | 1 kr) x 32 m-tiles. fp32 out.
// ---------------------------------------------------------------------------
__global__ __launch_bounds__(512) void gemm_down_p(const unsigned short* __restrict__ A,
                                                   const unsigned short* __restrict__ Bq,
                                                   const unsigned short* __restrict__ Bkv,
                                                   const unsigned short* __restrict__ Bkr,
                                                   float* __restrict__ Cq,
                                                   float* __restrict__ Ckv,
                                                   float* __restrict__ Ckr) {
  __shared__ unsigned short As[2][128 * 64];  // 32 KB
  __shared__ unsigned short Bs[2][256 * 64];  // 64 KB
  const int t  = blockIdx.x;   // 0..6
  const int m0 = blockIdx.y * 128;
  const unsigned short* Bm; float* C; int n0, NB;
  if (t < 4)      { Bm = Bq;  C = Cq;  n0 = t * 256;        NB = QR_;  }
  else if (t < 6) { Bm = Bkv; C = Ckv; n0 = (t - 4) * 256;  NB = KVR_; }
  else            { Bm = Bkr; C = Ckr; n0 = 0;              NB = ROPE_; }

  f32x4 acc[4][4];
  gemm_core_128x256(A, Bm, DIM_, NB, m0, n0, As, Bs, acc);

  const int lane = threadIdx.x & 63;
  const int wave = threadIdx.x >> 6;
  const int quad = lane >> 4;
  const int l15  = lane & 15;
  const int wm = (wave & 1) * 64;
  const int wn = (wave >> 1) * 64;
#pragma unroll
  for (int i = 0; i < 4; ++i)
#pragma unroll
    for (int j = 0; j < 4; ++j) {
      const int col = n0 + wn + j * 16 + l15;
      if (col < NB) {
#pragma unroll
        for (int r = 0; r < 4; ++r) {
          const int row = m0 + wm + i * 16 + quad * 4 + r;
          C[(size_t)row * NB + col] = acc[i][j][r];
        }
      }
    }
}

// ---------------------------------------------------------------------------
// FUSED up projections (one launch, both A matrices):
//   t 0..7 : q_cn  @ wq_up^T   -> q_nope (bf16, N=2048), K=1024
//   t 8..11: q_cn  @ wq_rope^T -> q_pe_f (fp32, N=1024), K=1024
//   t12..27: kv_cn @ wkv_up^T  -> kv_upbf (bf16, N=4096), K=512
// ---------------------------------------------------------------------------
__global__ __launch_bounds__(512) void gemm_up_p(const unsigned short* __restrict__ Aq,
                                                 const unsigned short* __restrict__ Akv,
                                                 const unsigned short* __restrict__ Bn,
                                                 const unsigned short* __restrict__ Br,
                                                 const unsigned short* __restrict__ Bkv,
                                                 unsigned short* __restrict__ Cn,
                                                 float* __restrict__ Cr,
                                                 unsigned short* __restrict__ Ckv) {
  __shared__ unsigned short As[2][128 * 64];
  __shared__ unsigned short Bs[2][256 * 64];
  const int t  = blockIdx.x;   // 0..27
  const int m0 = blockIdx.y * 128;
  const unsigned short* A; const unsigned short* Bm; int K, n0, NB, mode;
  if (t < 8)       { A = Aq;  Bm = Bn;  K = QR_;  n0 = t * 256;         NB = H_ * NOPE_;           mode = 0; }
  else if (t < 12) { A = Aq;  Bm = Br;  K = QR_;  n0 = (t - 8) * 256;   NB = H_ * ROPE_;           mode = 1; }
  else             { A = Akv; Bm = Bkv; K = KVR_; n0 = (t - 12) * 256;  NB = H_ * (NOPE_ + VDIM_); mode = 2; }

  f32x4 acc[4][4];
  gemm_core_128x256(A, Bm, K, NB, m0, n0, As, Bs, acc);

  const int lane = threadIdx.x & 63;
  const int wave = threadIdx.x >> 6;
  const int quad = lane >> 4;
  const int l15  = lane & 15;
  const int wm = (wave & 1) * 64;
  const int wn = (wave >> 1) * 64;
#pragma unroll
  for (int i = 0; i < 4; ++i)
#pragma unroll
    for (int j = 0; j < 4; ++j) {
      const int col = n0 + wn + j * 16 + l15;
#pragma unroll
      for (int r = 0; r < 4; ++r) {
        const int row = m0 + wm + i * 16 + quad * 4 + r;
        if (mode == 0)      Cn[(size_t)row * (H_ * NOPE_) + col] = f2bf(acc[i][j][r]);
        else if (mode == 1) Cr[(size_t)row * (H_ * ROPE_) + col] = acc[i][j][r];
        else                Ckv[(size_t)row * (H_ * (NOPE_ + VDIM_)) + col] = f2bf(acc[i][j][r]);
      }
    }
}

// ---------------------------------------------------------------------------
// Output projection: attn_o [4096x2048] @ wo^T -> out fp32 [4096x2048]
// ---------------------------------------------------------------------------
__global__ __launch_bounds__(512) void gemm_out_p(const unsigned short* __restrict__ A,
                                                  const unsigned short* __restrict__ Bm,
                                                  float* __restrict__ C) {
  __shared__ unsigned short As[2][128 * 64];
  __shared__ unsigned short Bs[2][256 * 64];
  const int n0 = blockIdx.x * 256;
  const int m0 = blockIdx.y * 128;

  f32x4 acc[4][4];
  gemm_core_128x256(A, Bm, H_ * VDIM_, DIM_, m0, n0, As, Bs, acc);

  const int lane = threadIdx.x & 63;
  const int wave = threadIdx.x >> 6;
  const int quad = lane >> 4;
  const int l15  = lane & 15;
  const int wm = (wave & 1) * 64;
  const int wn = (wave >> 1) * 64;
#pragma unroll
  for (int i = 0; i < 4; ++i)
#pragma unroll
    for (int j = 0; j < 4; ++j) {
      const int col = n0 + wn + j * 16 + l15;
#pragma unroll
      for (int r = 0; r < 4; ++r) {
        const int row = m0 + wm + i * 16 + quad * 4 + r;
        C[(size_t)row * DIM_ + col] = acc[i][j][r];
      }
    }
}

// ---------------------------------------------------------------------------
// RMSNorm (both q and kv in one launch): grid (TOK_, 2).
// ---------------------------------------------------------------------------
__global__ __launch_bounds__(256) void rmsnorm2(const float* __restrict__ xq,
                                                const float* __restrict__ wq,
                                                unsigned short* __restrict__ oq,
                                                const float* __restrict__ xkv,
                                                const float* __restrict__ wkv,
                                                unsigned short* __restrict__ okv) {
  __shared__ float red[256];
  const bool isq = (blockIdx.y == 0);
  const int n = isq ? QR_ : KVR_;
  const float* x = isq ? xq : xkv;
  const float* w = isq ? wq : wkv;
  unsigned short* o = isq ? oq : okv;
  const int row = blockIdx.x;
  const float* p = x + (size_t)row * n;
  float s = 0.f;
  for (int i = threadIdx.x; i < n; i += 256) { float v = p[i]; s += v * v; }
  red[threadIdx.x] = s;
  __syncthreads();
  for (int off = 128; off > 0; off >>= 1) {
    if (threadIdx.x < off) red[threadIdx.x] += red[threadIdx.x + off];
    __syncthreads();
  }
  const float inv = rsqrtf(red[0] / (float)n + 1e-6f);
  unsigned short* po = o + (size_t)row * n;
  for (int i = threadIdx.x; i < n; i += 256) po[i] = f2bf(p[i] * inv * w[i]);
}

// ---------------------------------------------------------------------------
// Interleaved RoPE, q and k fused in one launch. pos = row % S.
// ---------------------------------------------------------------------------
#define PAIRS_Q (TOK_ * H_ * 32)
#define PAIRS_K (TOK_ * 32)

__global__ void rope_all(const float* __restrict__ qin, unsigned short* __restrict__ qout,
                         const float* __restrict__ kin, unsigned short* __restrict__ kout) {
  int idx = blockIdx.x * blockDim.x + threadIdx.x;
  if (idx >= PAIRS_Q + PAIRS_K) return;
  int heads, id;
  const float* xin; unsigned short* xout;
  if (idx < PAIRS_Q) { heads = H_; xin = qin; xout = qout; id = idx; }
  else { heads = 1; xin = kin; xout = kout; id = idx - PAIRS_Q; }
  const int i = id & 31;
  const int h = (id >> 5) % heads;
  const int row = id / (32 * heads);
  const int pos = row & (S_ - 1);
  const float freq = expf(-9.210340371976184f * (float)i / 32.0f);
  const float ang = (float)pos * freq;
  const float c = cosf(ang), sn = sinf(ang);
  const float* p = xin + ((size_t)row * heads + h) * 64 + 2 * i;
  unsigned short* q = xout + ((size_t)row * heads + h) * 64 + 2 * i;
  const float x1 = p[0], x2 = p[1];
  q[0] = f2bf(x1 * c - x2 * sn);
  q[1] = f2bf(x1 * sn + x2 * c);
}

// ---------------------------------------------------------------------------
// One-shot V transpose: kv_up V-part -> vt_g[b][h][feat][key]
// ---------------------------------------------------------------------------
__global__ __launch_bounds__(256) void transpose_v(const unsigned short* __restrict__ kv_up,
                                                   unsigned short* __restrict__ vt_g) {
  __shared__ unsigned short T[128 * 72];
  const int tid = threadIdx.x;
  const int k0 = blockIdx.x * 64;
  const int h = blockIdx.y, b = blockIdx.z;
  const size_t tok0 = (size_t)b * S_;
#pragma unroll
  for (int i = 0; i < 2; ++i) {
    const int u = i * 256 + tid;
    const int kp = u >> 4, c8 = u & 15;
    const unsigned short* p0 =
        kv_up + (tok0 + k0 + 2 * kp) * (size_t)(H_ * 256) + h * 256 + NOPE_ + c8 * 8;
    union { uint4 v; unsigned short s[8]; } r0, r1;
    r0.v = *(const uint4*)p0;
    r1.v = *(const uint4*)(p0 + H_ * 256);
#pragma unroll
    for (int j = 0; j < 8; ++j)
      *(unsigned*)&T[(c8 * 8 + j) * 72 + 2 * kp] = (unsigned)r0.s[j] | ((unsigned)r1.s[j] << 16);
  }
  __syncthreads();
#pragma unroll
  for (int i = 0; i < 4; ++i) {
    const int sl = i * 256 + tid;
    const int f = sl >> 3, c = sl & 7;
    *(uint4*)(vt_g + ((size_t)(b * H_ + h) * 128 + f) * S_ + k0 + c * 8) =
        *(const uint4*)&T[f * 72 + c * 8];
  }
}

// ---------------------------------------------------------------------------
// MFMA flash attention (R6-verified: 99.7 us, FETCH 35 MB). Untouched.
// ---------------------------------------------------------------------------
#define LV 72    // Ps stride (64 + 8 pad)

__global__ __launch_bounds__(512) void flash_attn_mfma(const unsigned short* q_nope,
                                                       const unsigned short* __restrict__ q_pe,
                                                       const unsigned short* __restrict__ kv_up,
                                                       const unsigned short* __restrict__ k_rope,
                                                       const unsigned short* __restrict__ vt_g,
                                                       unsigned short* attn_o) {
  __shared__ unsigned short Ksn[2][128 * 16 * 8];  // 2 x 32 KB
  __shared__ unsigned short Ksr[2][128 * 8 * 8];   // 2 x 16 KB
  __shared__ unsigned short Vt[128 * 16 * 8];      //     32 KB
  __shared__ unsigned short Ps[128 * LV];          //     18 KB

  const int tid  = threadIdx.x;
  const int wave = tid >> 6;    // 0..7
  const int lane = tid & 63;
  const int quad = lane >> 4;
  const int l15  = lane & 15;
  const int l   = blockIdx.x + 8 * blockIdx.y + 128 * blockIdx.z;
  const int c_  = l & 7;
  const int m_  = l >> 3;
  const int pair = m_ & 7;
  const int hb   = c_ * 4 + (m_ >> 3);
  const int h  = hb & 15;
  const int b  = hb >> 4;
  const size_t tok0 = (size_t)b * S_;
  const float scale2 = 0.07216878364870323f * 1.4426950408889634f;
  const int qtA = 15 - pair;
  const int qtB = pair;
  const int nA  = qtA + 1;

  auto LOADQ = [&](short8* qf, int qt) {
    const size_t qrow = tok0 + qt * 128 + wave * 16 + l15;
    const unsigned short* pn = q_nope + qrow * (size_t)(H_ * NOPE_) + h * NOPE_;
    const unsigned short* pp = q_pe + qrow * (size_t)(H_ * ROPE_) + h * ROPE_;
#pragma unroll
    for (int s = 0; s < 4; ++s) qf[s] = *(const short8*)(pn + s * 32 + quad * 8);
#pragma unroll
    for (int s = 4; s < 6; ++s) qf[s] = *(const short8*)(pp + (s - 4) * 32 + quad * 8);
  };

  auto STAGE_K = [&](int bi, int kt) {
    const int k0 = kt * 128;
#pragma unroll
    for (int i = 0; i < 4; ++i) {
      const int sl = i * 512 + tid;
      const int key = sl >> 4;
      const int c = (sl & 15) ^ (key & 15);
      gl_lds16(kv_up + (tok0 + k0 + key) * (size_t)(H_ * 256) + h * 256 + c * 8,
               &Ksn[bi][(i * 512 + wave * 64) * 8]);
    }
#pragma unroll
    for (int i = 0; i < 2; ++i) {
      const int sl = i * 512 + tid;
      const int key = sl >> 3;
      const int c = (sl & 7) ^ (key & 7);
      gl_lds16(k_rope + (tok0 + k0 + key) * (size_t)ROPE_ + c * 8,
               &Ksr[bi][(i * 512 + wave * 64) * 8]);
    }
  };
  auto STAGE_V = [&](int kt) {
    const int k0 = kt * 128;
#pragma unroll
    for (int i = 0; i < 4; ++i) {
      const int sl = i * 512 + tid;
      const int f = sl >> 4;
      const int c = (sl & 15) ^ (f & 15);
      gl_lds16(vt_g + ((size_t)(b * H_ + h) * 128 + f) * S_ + k0 + c * 8,
               &Vt[(i * 512 + wave * 64) * 8]);
    }
  };

  short8 qf[6];
  LOADQ(qf, qtA);

  float m_st[4], l_st[4];
  f32x4 o[8];
#pragma unroll
  for (int r = 0; r < 4; ++r) { m_st[r] = -1e30f; l_st[r] = 0.f; }
#pragma unroll
  for (int nt = 0; nt < 8; ++nt) { f32x4 z = {0.f, 0.f, 0.f, 0.f}; o[nt] = z; }

  auto EPI = [&](int qt) {
    float invl[4];
#pragma unroll
    for (int r = 0; r < 4; ++r) invl[r] = 1.f / l_st[r];
#pragma unroll
    for (int nt = 0; nt < 8; ++nt)
#pragma unroll
      for (int r = 0; r < 4; ++r) {
        const size_t row = tok0 + qt * 128 + wave * 16 + quad * 4 + r;
        attn_o[row * (size_t)(H_ * VDIM_) + h * VDIM_ + nt * 16 + l15] =
            f2bf(o[nt][r] * invl[r]);
      }
  };

  STAGE_K(0, 0);

  for (int it = 0; it < 17; ++it) {
    const int cur = it & 1;
    const int nxt = cur ^ 1;
    const bool ph1 = (it >= nA);
    const int qt = ph1 ? qtB : qtA;
    const int kt = ph1 ? (it - nA) : it;
    const bool last = (it + 1 >= 17);

    __builtin_amdgcn_s_barrier();
    asm volatile("" ::: "memory");

    STAGE_V(kt);
    if (!last) {
      const int it2 = it + 1;
      const int kt2 = (it2 >= nA) ? (it2 - nA) : it2;
      STAGE_K(nxt, kt2);
      asm volatile("s_waitcnt vmcnt(10)" ::: "memory");
    } else {
      asm volatile("s_waitcnt vmcnt(4)" ::: "memory");
    }
    __builtin_amdgcn_s_barrier();
    asm volatile("" ::: "memory");
    __builtin_amdgcn_sched_barrier(0);

    f32x4 sacc[8];
#pragma unroll
    for (int nt = 0; nt < 8; ++nt) { f32x4 z = {0.f, 0.f, 0.f, 0.f}; sacc[nt] = z; }
    __builtin_amdgcn_s_setprio(1);
#pragma unroll
    for (int s = 0; s < 4; ++s) {
#pragma unroll
      for (int nt = 0; nt < 8; ++nt) {
        const int key = nt * 16 + l15;
        short8 kb = *(const short8*)&Ksn[cur][(key * 16 + ((s * 4 + quad) ^ (key & 15))) * 8];
        sacc[nt] = __builtin_amdgcn_mfma_f32_16x16x32_bf16(qf[s], kb, sacc[nt], 0, 0, 0);
      }
    }
#pragma unroll
    for (int s = 4; s < 6; ++s) {
#pragma unroll
      for (int nt = 0; nt < 8; ++nt) {
        const int key = nt * 16 + l15;
        short8 kb = *(const short8*)&Ksr[cur][(key * 8 + (((s - 4) * 4 + quad) ^ (key & 7))) * 8];
        sacc[nt] = __builtin_amdgcn_mfma_f32_16x16x32_bf16(qf[s], kb, sacc[nt], 0, 0, 0);
      }
    }
    __builtin_amdgcn_s_setprio(0);

    float sc[8][4];
#pragma unroll
    for (int nt = 0; nt < 8; ++nt)
#pragma unroll
      for (int r = 0; r < 4; ++r) sc[nt][r] = sacc[nt][r] * scale2;
    if (kt == qt) {
      const int rw = wave * 16 + quad * 4;
#pragma unroll
      for (int nt = 0; nt < 8; ++nt)
#pragma unroll
        for (int r = 0; r < 4; ++r)
          if ((nt * 16 + l15) > (rw + r)) sc[nt][r] = -1e30f;
    }

    float mt[4];
#pragma unroll
    for (int r = 0; r < 4; ++r) {
      float a0 = fmaxf(fmaxf(sc[0][r], sc[1][r]), fmaxf(sc[2][r], sc[3][r]));
      float a1 = fmaxf(fmaxf(sc[4][r], sc[5][r]), fmaxf(sc[6][r], sc[7][r]));
      mt[r] = fmaxf(a0, a1);
    }
#pragma unroll
    for (int mask = 1; mask <= 8; mask <<= 1)
#pragma unroll
      for (int r = 0; r < 4; ++r) mt[r] = fmaxf(mt[r], __shfl_xor(mt[r], mask, 64));

    float al[4], rs[4];
#pragma unroll
    for (int r = 0; r < 4; ++r) {
      const float mn = fmaxf(m_st[r], mt[r]);
      al[r] = exp2f(m_st[r] - mn);
      m_st[r] = mn;
      rs[r] = 0.f;
    }
#pragma unroll
    for (int nt = 0; nt < 8; ++nt)
#pragma unroll
      for (int r = 0; r < 4; ++r) {
        const float p = exp2f(sc[nt][r] - m_st[r]);
        sc[nt][r] = p;
        rs[r] += p;
      }
#pragma unroll
    for (int mask = 1; mask <= 8; mask <<= 1)
#pragma unroll
      for (int r = 0; r < 4; ++r) rs[r] += __shfl_xor(rs[r], mask, 64);
#pragma unroll
    for (int r = 0; r < 4; ++r) l_st[r] = l_st[r] * al[r] + rs[r];

#pragma unroll
    for (int nt = 0; nt < 4; ++nt)
#pragma unroll
      for (int r = 0; r < 4; ++r)
        Ps[(wave * 16 + quad * 4 + r) * LV + nt * 16 + l15] = f2bf(sc[nt][r]);
    __builtin_amdgcn_wave_barrier();

#pragma unroll
    for (int nt = 0; nt < 8; ++nt)
#pragma unroll
      for (int r = 0; r < 4; ++r) o[nt][r] *= al[r];

    if (!last) {
      asm volatile("s_waitcnt vmcnt(6)" ::: "memory");
    } else {
      asm volatile("s_waitcnt vmcnt(0)" ::: "memory");
    }
    __builtin_amdgcn_s_barrier();
    asm volatile("" ::: "memory");
    __builtin_amdgcn_sched_barrier(0);

    __builtin_amdgcn_s_setprio(1);
#pragma unroll
    for (int kb = 0; kb < 2; ++kb) {
      short8 pa = *(const short8*)&Ps[(wave * 16 + l15) * LV + kb * 32 + quad * 8];
#pragma unroll
      for (int nt = 0; nt < 8; ++nt) {
        const int f = nt * 16 + l15;
        short8 vb = *(const short8*)&Vt[(f * 16 + ((kb * 4 + quad) ^ (f & 15))) * 8];
        o[nt] = __builtin_amdgcn_mfma_f32_16x16x32_bf16(pa, vb, o[nt], 0, 0, 0);
      }
    }
    __builtin_amdgcn_s_setprio(0);

#pragma unroll
    for (int nt = 4; nt < 8; ++nt)
#pragma unroll
      for (int r = 0; r < 4; ++r)
        Ps[(wave * 16 + quad * 4 + r) * LV + (nt - 4) * 16 + l15] = f2bf(sc[nt][r]);
    __builtin_amdgcn_wave_barrier();

    __builtin_amdgcn_s_setprio(1);
#pragma unroll
    for (int kb = 2; kb < 4; ++kb) {
      short8 pa = *(const short8*)&Ps[(wave * 16 + l15) * LV + (kb - 2) * 32 + quad * 8];
#pragma unroll
      for (int nt = 0; nt < 8; ++nt) {
        const int f = nt * 16 + l15;
        short8 vb = *(const short8*)&Vt[(f * 16 + ((kb * 4 + quad) ^ (f & 15))) * 8];
        o[nt] = __builtin_amdgcn_mfma_f32_16x16x32_bf16(pa, vb, o[nt], 0, 0, 0);
      }
    }
    __builtin_amdgcn_s_setprio(0);

    if (it == nA - 1) {
      EPI(qtA);
      LOADQ(qf, qtB);
#pragma unroll
      for (int r = 0; r < 4; ++r) { m_st[r] = -1e30f; l_st[r] = 0.f; }
#pragma unroll
      for (int nt = 0; nt < 8; ++nt) { f32x4 z = {0.f, 0.f, 0.f, 0.f}; o[nt] = z; }
    }
  }

  EPI(qtB);
}

// ---------------------------------------------------------------------------
// Launch
// ---------------------------------------------------------------------------
extern "C" void kernel_launch(void* const* d_in, const int* in_sizes, int n_in,
                              void* d_out, int out_size, void* d_ws, size_t ws_size,
                              hipStream_t stream) {
  (void)in_sizes; (void)n_in;
  const float* x         = (const float*)d_in[0];
  const float* wq_down   = (const float*)d_in[1];
  const float* q_norm_w  = (const float*)d_in[2];
  const float* wq_up     = (const float*)d_in[3];
  const float* wq_rope   = (const float*)d_in[4];
  const float* wkv_down  = (const float*)d_in[5];
  const float* kv_norm_w = (const float*)d_in[6];
  const float* wkv_up    = (const float*)d_in[7];
  const float* wk_rope   = (const float*)d_in[8];
  const float* wo        = (const float*)d_in[9];
  float* out = (float*)d_out;

  // ---- workspace carve (identical layout to the passing run)
  const size_t SZ_XBF   = (size_t)TOK_ * DIM_ * 2;
  const size_t SZ_WQD   = (size_t)QR_ * DIM_ * 2;
  const size_t SZ_WKVD  = (size_t)KVR_ * DIM_ * 2;
  const size_t SZ_WKR   = (size_t)ROPE_ * DIM_ * 2;
  const size_t SZ_WQU   = (size_t)H_ * NOPE_ * QR_ * 2;
  const size_t SZ_WQR   = (size_t)H_ * ROPE_ * QR_ * 2;
  const size_t SZ_WKVU  = (size_t)H_ * (NOPE_ + VDIM_) * KVR_ * 2;
  const size_t SZ_WO    = (size_t)DIM_ * H_ * VDIM_ * 2;
  const size_t SZ_QC    = (size_t)TOK_ * QR_ * 4;   // aliases: q_pe fp32, then vt_g
  const size_t SZ_KVC   = (size_t)TOK_ * KVR_ * 4;
  const size_t SZ_QCN   = (size_t)TOK_ * QR_ * 2;
  const size_t SZ_KVCN  = (size_t)TOK_ * KVR_ * 2;
  const size_t SZ_QNOPE = (size_t)TOK_ * H_ * NOPE_ * 2; // aliases attn_o bf16
  const size_t SZ_QPEB  = (size_t)TOK_ * H_ * ROPE_ * 2;
  const size_t SZ_KRF   = (size_t)TOK_ * ROPE_ * 4;
  const size_t SZ_KRB   = (size_t)TOK_ * ROPE_ * 2;
  const size_t SZ_KVUP  = (size_t)TOK_ * H_ * (NOPE_ + VDIM_) * 2;
  const size_t NEED = SZ_XBF + SZ_WQD + SZ_WKVD + SZ_WKR + SZ_WQU + SZ_WQR + SZ_WKVU +
                      SZ_WO + SZ_QC + SZ_KVC + SZ_QCN + SZ_KVCN + SZ_QNOPE + SZ_QPEB +
                      SZ_KRF + SZ_KRB + SZ_KVUP;
  if (ws_size < NEED) {
    hipMemsetAsync(d_out, 0, (size_t)out_size * sizeof(float), stream);
    return;
  }
  char* p = (char*)d_ws;
  unsigned short* x_bf    = (unsigned short*)p; p += SZ_XBF;
  unsigned short* wqd_bf  = (unsigned short*)p; p += SZ_WQD;
  unsigned short* wkvd_bf = (unsigned short*)p; p += SZ_WKVD;
  unsigned short* wkr_bf  = (unsigned short*)p; p += SZ_WKR;
  unsigned short* wqu_bf  = (unsigned short*)p; p += SZ_WQU;
  unsigned short* wqr_bf  = (unsigned short*)p; p += SZ_WQR;
  unsigned short* wkvu_bf = (unsigned short*)p; p += SZ_WKVU;
  unsigned short* wo_bf   = (unsigned short*)p; p += SZ_WO;
  float*          q_c     = (float*)p;          p += SZ_QC;
  float*          kv_c    = (float*)p;          p += SZ_KVC;
  unsigned short* q_cn    = (unsigned short*)p; p += SZ_QCN;
  unsigned short* kv_cn   = (unsigned short*)p; p += SZ_KVCN;
  unsigned short* q_nope  = (unsigned short*)p; p += SZ_QNOPE;
  unsigned short* q_pe_bf = (unsigned short*)p; p += SZ_QPEB;
  float*          k_ropef = (float*)p;          p += SZ_KRF;
  unsigned short* k_ropeb = (unsigned short*)p; p += SZ_KRB;
  unsigned short* kv_upbf = (unsigned short*)p; p += SZ_KVUP;
  float*          q_pe_f  = q_c;                   // q_c dead after rmsnorm
  unsigned short* vt_g    = (unsigned short*)q_c;  // q_pe_f dead after rope
  unsigned short* attn_o  = q_nope;                // q_nope dead after flash

  const dim3 blk(256);

  // ---- all fp32->bf16 casts in ONE launch
  cvt_all<<<(C_TOT + 255) / 256, blk, 0, stream>>>(
      x, wq_down, wkv_down, wk_rope, wq_up, wq_rope, wkv_up, wo,
      x_bf, wqd_bf, wkvd_bf, wkr_bf, wqu_bf, wqr_bf, wkvu_bf, wo_bf);

  // ---- fused down projections (pipelined 128x256): q_c | kv_c | k_ropef
  gemm_down_p<<<dim3(7, TOK_ / 128), dim3(512), 0, stream>>>(x_bf, wqd_bf, wkvd_bf, wkr_bf,
                                                             q_c, kv_c, k_ropef);

  // ---- both RMSNorms in one launch
  rmsnorm2<<<dim3(TOK_, 2), blk, 0, stream>>>(q_c, q_norm_w, q_cn, kv_c, kv_norm_w, kv_cn);

  // ---- ALL up projections in one launch (q_nope | q_pe_f | kv_upbf)
  gemm_up_p<<<dim3(28, TOK_ / 128), dim3(512), 0, stream>>>(q_cn, kv_cn, wqu_bf, wqr_bf, wkvu_bf,
                                                            q_nope, q_pe_f, kv_upbf);

  // ---- RoPE q+k in one launch
  rope_all<<<(PAIRS_Q + PAIRS_K + 255) / 256, blk, 0, stream>>>(q_pe_f, q_pe_bf, k_ropef, k_ropeb);

  // ---- V transpose (vt_g aliases q_c region; rope_all already consumed q_pe_f)
  transpose_v<<<dim3(S_ / 64, H_, B_), blk, 0, stream>>>(kv_upbf, vt_g);

  // ---- attention (8-wave blocks, 128-row q-tiles, 128-key K/V tiles)
  flash_attn_mfma<<<dim3(8, H_, B_), dim3(512), 0, stream>>>(q_nope, q_pe_bf, kv_upbf, k_ropeb, vt_g, attn_o);

  // ---- output projection (pipelined 128x256)
  gemm_out_p<<<dim3(8, TOK_ / 128), dim3(512), 0, stream>>>(attn_o, wo_bf, out);
}

// Round 8
// 413.267 us; speedup vs baseline: 1.5146x; 1.0329x over previous
//
#include <hip/hip_runtime.h>
#include <hip/hip_bf16.h>
#include <math.h>

// Problem constants (from reference)
#define B_    2
#define S_    2048
#define DIM_  2048
#define H_    16
#define NOPE_ 128
#define ROPE_ 64
#define VDIM_ 128
#define QR_   1024
#define KVR_  512
#define TOK_  (B_ * S_)   // 4096 token rows

typedef __attribute__((ext_vector_type(8))) short short8;   // 8 bf16 (4 VGPRs)
typedef __attribute__((ext_vector_type(4))) float f32x4;    // MFMA acc

// fp32 -> bf16 (round-to-nearest-even), raw ushort
__device__ __forceinline__ unsigned short f2bf(float f) {
  union { float f; unsigned u; } v; v.f = f;
  unsigned r = v.u + 0x7fffu + ((v.u >> 16) & 1u);
  return (unsigned short)(r >> 16);
}
__device__ __forceinline__ unsigned pk2(float lo, float hi) {
  return (unsigned)f2bf(lo) | ((unsigned)f2bf(hi) << 16);
}

// async global->LDS, 16 B per lane; dest = wave-uniform base + lane*16.
__device__ __forceinline__ void gl_lds16(const unsigned short* g, unsigned short* lds_base) {
  __builtin_amdgcn_global_load_lds(
      (const __attribute__((address_space(1))) void*)g,
      (__attribute__((address_space(3))) void*)lds_base,
      16, 0, 0);
}

// ---------------------------------------------------------------------------
// ONE-SHOT cast: all 8 fp32->bf16 conversions in a single launch.
// ---------------------------------------------------------------------------
#define C_X    (TOK_ * DIM_ / 8)
#define C_WQD  (QR_ * DIM_ / 8)
#define C_WKVD (KVR_ * DIM_ / 8)
#define C_WKR  (ROPE_ * DIM_ / 8)
#define C_WQU  (H_ * NOPE_ * QR_ / 8)
#define C_WQR  (H_ * ROPE_ * QR_ / 8)
#define C_WKVU (H_ * (NOPE_ + VDIM_) * KVR_ / 8)
#define C_WO   (DIM_ * H_ * VDIM_ / 8)
#define C_TOT  (C_X + C_WQD + C_WKVD + C_WKR + C_WQU + C_WQR + C_WKVU + C_WO)

__global__ __launch_bounds__(256) void cvt_all(
    const float* __restrict__ x, const float* __restrict__ wqd, const float* __restrict__ wkvd,
    const float* __restrict__ wkr, const float* __restrict__ wqu, const float* __restrict__ wqr,
    const float* __restrict__ wkvu, const float* __restrict__ wo,
    unsigned short* __restrict__ xo, unsigned short* __restrict__ wqdo,
    unsigned short* __restrict__ wkvdo, unsigned short* __restrict__ wkro,
    unsigned short* __restrict__ wquo, unsigned short* __restrict__ wqro,
    unsigned short* __restrict__ wkvuo, unsigned short* __restrict__ woo) {
  int i = blockIdx.x * 256 + threadIdx.x;
  if (i >= C_TOT) return;
  const float* in; unsigned short* out;
  if (i < C_X) { in = x; out = xo; }
  else if ((i -= C_X) < C_WQD) { in = wqd; out = wqdo; }
  else if ((i -= C_WQD) < C_WKVD) { in = wkvd; out = wkvdo; }
  else if ((i -= C_WKVD) < C_WKR) { in = wkr; out = wkro; }
  else if ((i -= C_WKR) < C_WQU) { in = wqu; out = wquo; }
  else if ((i -= C_WQU) < C_WQR) { in = wqr; out = wqro; }
  else if ((i -= C_WQR) < C_WKVU) { in = wkvu; out = wkvuo; }
  else { i -= C_WKVU; in = wo; out = woo; }
  float4 f0 = *(const float4*)(in + (size_t)i * 8);
  float4 f1 = *(const float4*)(in + (size_t)i * 8 + 4);
  uint4 u;
  u.x = pk2(f0.x, f0.y); u.y = pk2(f0.z, f0.w);
  u.z = pk2(f1.x, f1.y); u.w = pk2(f1.z, f1.w);
  *(uint4*)&out[(size_t)i * 8] = u;
}

// ---------------------------------------------------------------------------
// Pipelined GEMM core: 128x256 tile, BK=64, 512 threads (8 waves, 2M x 4N),
// double-buffered LDS, counted-vmcnt sync (flash-proven).
// ---------------------------------------------------------------------------
__device__ __forceinline__ void gemm_core_128x256(
    const unsigned short* __restrict__ A, const unsigned short* __restrict__ Bm,
    int K, int NB, int m0, int n0,
    unsigned short (*As)[128 * 64], unsigned short (*Bs)[256 * 64],
    f32x4 acc[4][4]) {
  const int tid  = threadIdx.x;
  const int wave = tid >> 6;
  const int lane = tid & 63;
  const int quad = lane >> 4;
  const int l15  = lane & 15;
  const int wm = (wave & 1) * 64;
  const int wn = (wave >> 1) * 64;

  auto STAGE = [&](int bi, int k0) {
#pragma unroll
    for (int i = 0; i < 2; ++i) {            // A: 128 rows x 8 chunks = 1024 slots
      const int s = i * 512 + tid;
      const int row = s >> 3;
      const int c = (s & 7) ^ (row & 7);
      gl_lds16(A + (size_t)(m0 + row) * K + k0 + c * 8, &As[bi][(i * 512 + wave * 64) * 8]);
    }
#pragma unroll
    for (int i = 0; i < 4; ++i) {            // B: 256 rows x 8 chunks = 2048 slots
      const int s = i * 512 + tid;
      const int row = s >> 3;
      const int c = (s & 7) ^ (row & 7);
      const int rb = min(n0 + row, NB - 1);
      gl_lds16(Bm + (size_t)rb * K + k0 + c * 8, &Bs[bi][(i * 512 + wave * 64) * 8]);
    }
  };

#pragma unroll
  for (int i = 0; i < 4; ++i)
#pragma unroll
    for (int j = 0; j < 4; ++j) { f32x4 z = {0.f, 0.f, 0.f, 0.f}; acc[i][j] = z; }

  const int nk = K >> 6;
  STAGE(0, 0);
  for (int kk = 0; kk < nk; ++kk) {
    const int cur = kk & 1;
    // WAR: all waves done reading buf[cur^1] (previous iteration's compute).
    __builtin_amdgcn_s_barrier();
    asm volatile("" ::: "memory");
    if (kk + 1 < nk) {
      STAGE(cur ^ 1, (kk + 1) * 64);
      asm volatile("s_waitcnt vmcnt(6)" ::: "memory");   // my cur-tile loads landed
    } else {
      asm volatile("s_waitcnt vmcnt(0)" ::: "memory");
    }
    // RAW: ALL waves' cur-tile loads landed.
    __builtin_amdgcn_s_barrier();
    asm volatile("" ::: "memory");
    __builtin_amdgcn_sched_barrier(0);

    short8 a[2][4], b[2][4];
#pragma unroll
    for (int s = 0; s < 2; ++s) {
#pragma unroll
      for (int i = 0; i < 4; ++i) {
        const int r = wm + i * 16 + l15;
        a[s][i] = *(const short8*)&As[cur][(r * 8 + ((s * 4 + quad) ^ (r & 7))) * 8];
      }
#pragma unroll
      for (int j = 0; j < 4; ++j) {
        const int r = wn + j * 16 + l15;
        b[s][j] = *(const short8*)&Bs[cur][(r * 8 + ((s * 4 + quad) ^ (r & 7))) * 8];
      }
    }
    __builtin_amdgcn_s_setprio(1);
#pragma unroll
    for (int s = 0; s < 2; ++s)
#pragma unroll
      for (int i = 0; i < 4; ++i)
#pragma unroll
        for (int j = 0; j < 4; ++j)
          acc[i][j] = __builtin_amdgcn_mfma_f32_16x16x32_bf16(a[s][i], b[s][j], acc[i][j], 0, 0, 0);
    __builtin_amdgcn_s_setprio(0);
  }
}

// ---------------------------------------------------------------------------
// FUSED down projections: x_bf [4096x2048] @ {wq_down, wkv_down, wk_rope}^T
// XCD co-locate-by-m: each XCD owns 4 contiguous m-panels (A L2-resident).
// lhw round-robins over XCDs; slot%7 = n-tile, xcd*4 + slot/7 = m-tile.
// ---------------------------------------------------------------------------
__global__ __launch_bounds__(512) void gemm_down_p(const unsigned short* __restrict__ A,
                                                   const unsigned short* __restrict__ Bq,
                                                   const unsigned short* __restrict__ Bkv,
                                                   const unsigned short* __restrict__ Bkr,
                                                   float* __restrict__ Cq,
                                                   float* __restrict__ Ckv,
                                                   float* __restrict__ Ckr) {
  __shared__ unsigned short As[2][128 * 64];  // 32 KB
  __shared__ unsigned short Bs[2][256 * 64];  // 64 KB
  const int lhw  = blockIdx.x + 7 * blockIdx.y;   // 0..223 (224 % 8 == 0)
  const int xcd  = lhw & 7;
  const int slot = lhw >> 3;                      // 0..27
  const int t    = slot % 7;
  const int m0   = (xcd * 4 + slot / 7) * 128;
  const unsigned short* Bm; float* C; int n0, NB;
  if (t < 4)      { Bm = Bq;  C = Cq;  n0 = t * 256;        NB = QR_;  }
  else if (t < 6) { Bm = Bkv; C = Ckv; n0 = (t - 4) * 256;  NB = KVR_; }
  else            { Bm = Bkr; C = Ckr; n0 = 0;              NB = ROPE_; }

  f32x4 acc[4][4];
  gemm_core_128x256(A, Bm, DIM_, NB, m0, n0, As, Bs, acc);

  const int lane = threadIdx.x & 63;
  const int wave = threadIdx.x >> 6;
  const int quad = lane >> 4;
  const int l15  = lane & 15;
  const int wm = (wave & 1) * 64;
  const int wn = (wave >> 1) * 64;
#pragma unroll
  for (int i = 0; i < 4; ++i)
#pragma unroll
    for (int j = 0; j < 4; ++j) {
      const int col = n0 + wn + j * 16 + l15;
      if (col < NB) {
#pragma unroll
        for (int r = 0; r < 4; ++r) {
          const int row = m0 + wm + i * 16 + quad * 4 + r;
          C[(size_t)row * NB + col] = acc[i][j][r];
        }
      }
    }
}

// ---------------------------------------------------------------------------
// FUSED up projections (XCD co-locate-by-m; 28 n-tiles):
//   t 0..7 : q_cn  @ wq_up^T   -> q_nope (bf16, N=2048), K=1024
//   t 8..11: q_cn  @ wq_rope^T -> q_pe_f (fp32, N=1024), K=1024
//   t12..27: kv_cn @ wkv_up^T  -> kv_upbf (bf16, N=4096), K=512
// ---------------------------------------------------------------------------
__global__ __launch_bounds__(512) void gemm_up_p(const unsigned short* __restrict__ Aq,
                                                 const unsigned short* __restrict__ Akv,
                                                 const unsigned short* __restrict__ Bn,
                                                 const unsigned short* __restrict__ Br,
                                                 const unsigned short* __restrict__ Bkv,
                                                 unsigned short* __restrict__ Cn,
                                                 float* __restrict__ Cr,
                                                 unsigned short* __restrict__ Ckv) {
  __shared__ unsigned short As[2][128 * 64];
  __shared__ unsigned short Bs[2][256 * 64];
  const int lhw  = blockIdx.x + 28 * blockIdx.y;  // 0..895 (896 % 8 == 0)
  const int xcd  = lhw & 7;
  const int slot = lhw >> 3;                      // 0..111
  const int t    = slot % 28;
  const int m0   = (xcd * 4 + slot / 28) * 128;
  const unsigned short* A; const unsigned short* Bm; int K, n0, NB, mode;
  if (t < 8)       { A = Aq;  Bm = Bn;  K = QR_;  n0 = t * 256;         NB = H_ * NOPE_;           mode = 0; }
  else if (t < 12) { A = Aq;  Bm = Br;  K = QR_;  n0 = (t - 8) * 256;   NB = H_ * ROPE_;           mode = 1; }
  else             { A = Akv; Bm = Bkv; K = KVR_; n0 = (t - 12) * 256;  NB = H_ * (NOPE_ + VDIM_); mode = 2; }

  f32x4 acc[4][4];
  gemm_core_128x256(A, Bm, K, NB, m0, n0, As, Bs, acc);

  const int lane = threadIdx.x & 63;
  const int wave = threadIdx.x >> 6;
  const int quad = lane >> 4;
  const int l15  = lane & 15;
  const int wm = (wave & 1) * 64;
  const int wn = (wave >> 1) * 64;
#pragma unroll
  for (int i = 0; i < 4; ++i)
#pragma unroll
    for (int j = 0; j < 4; ++j) {
      const int col = n0 + wn + j * 16 + l15;
#pragma unroll
      for (int r = 0; r < 4; ++r) {
        const int row = m0 + wm + i * 16 + quad * 4 + r;
        if (mode == 0)      Cn[(size_t)row * (H_ * NOPE_) + col] = f2bf(acc[i][j][r]);
        else if (mode == 1) Cr[(size_t)row * (H_ * ROPE_) + col] = acc[i][j][r];
        else                Ckv[(size_t)row * (H_ * (NOPE_ + VDIM_)) + col] = f2bf(acc[i][j][r]);
      }
    }
}

// ---------------------------------------------------------------------------
// Output projection (XCD co-locate-by-m): attn_o @ wo^T -> out fp32
// ---------------------------------------------------------------------------
__global__ __launch_bounds__(512) void gemm_out_p(const unsigned short* __restrict__ A,
                                                  const unsigned short* __restrict__ Bm,
                                                  float* __restrict__ C) {
  __shared__ unsigned short As[2][128 * 64];
  __shared__ unsigned short Bs[2][256 * 64];
  const int lhw  = blockIdx.x + 8 * blockIdx.y;   // 0..255
  const int xcd  = lhw & 7;
  const int slot = lhw >> 3;                      // 0..31
  const int n0   = (slot % 8) * 256;
  const int m0   = (xcd * 4 + slot / 8) * 128;

  f32x4 acc[4][4];
  gemm_core_128x256(A, Bm, H_ * VDIM_, DIM_, m0, n0, As, Bs, acc);

  const int lane = threadIdx.x & 63;
  const int wave = threadIdx.x >> 6;
  const int quad = lane >> 4;
  const int l15  = lane & 15;
  const int wm = (wave & 1) * 64;
  const int wn = (wave >> 1) * 64;
#pragma unroll
  for (int i = 0; i < 4; ++i)
#pragma unroll
    for (int j = 0; j < 4; ++j) {
      const int col = n0 + wn + j * 16 + l15;
#pragma unroll
      for (int r = 0; r < 4; ++r) {
        const int row = m0 + wm + i * 16 + quad * 4 + r;
        C[(size_t)row * DIM_ + col] = acc[i][j][r];
      }
    }
}

// ---------------------------------------------------------------------------
// RMSNorm (both q and kv in one launch): grid (TOK_, 2).
// ---------------------------------------------------------------------------
__global__ __launch_bounds__(256) void rmsnorm2(const float* __restrict__ xq,
                                                const float* __restrict__ wq,
                                                unsigned short* __restrict__ oq,
                                                const float* __restrict__ xkv,
                                                const float* __restrict__ wkv,
                                                unsigned short* __restrict__ okv) {
  __shared__ float red[256];
  const bool isq = (blockIdx.y == 0);
  const int n = isq ? QR_ : KVR_;
  const float* x = isq ? xq : xkv;
  const float* w = isq ? wq : wkv;
  unsigned short* o = isq ? oq : okv;
  const int row = blockIdx.x;
  const float* p = x + (size_t)row * n;
  float s = 0.f;
  for (int i = threadIdx.x; i < n; i += 256) { float v = p[i]; s += v * v; }
  red[threadIdx.x] = s;
  __syncthreads();
  for (int off = 128; off > 0; off >>= 1) {
    if (threadIdx.x < off) red[threadIdx.x] += red[threadIdx.x + off];
    __syncthreads();
  }
  const float inv = rsqrtf(red[0] / (float)n + 1e-6f);
  unsigned short* po = o + (size_t)row * n;
  for (int i = threadIdx.x; i < n; i += 256) po[i] = f2bf(p[i] * inv * w[i]);
}

// ---------------------------------------------------------------------------
// MERGED RoPE (q+k) + V transpose: one launch (same dependency set).
// Blocks [0, ROPE_BLKS) do rope pairs; blocks [ROPE_BLKS, +1024) do V-transpose.
// ---------------------------------------------------------------------------
#define PAIRS_Q (TOK_ * H_ * 32)
#define PAIRS_K (TOK_ * 32)
#define ROPE_BLKS ((PAIRS_Q + PAIRS_K) / 256)    // 8704 exactly
#define TR_BLKS   (32 * H_ * B_)                 // 1024

__global__ __launch_bounds__(256) void rope_tr(const float* __restrict__ qin,
                                               unsigned short* __restrict__ qout,
                                               const float* __restrict__ kin,
                                               unsigned short* __restrict__ kout,
                                               const unsigned short* __restrict__ kv_up,
                                               unsigned short* __restrict__ vt_g) {
  __shared__ unsigned short T[128 * 72];
  if (blockIdx.x < ROPE_BLKS) {
    int idx = blockIdx.x * 256 + threadIdx.x;
    int heads, id;
    const float* xin; unsigned short* xout;
    if (idx < PAIRS_Q) { heads = H_; xin = qin; xout = qout; id = idx; }
    else { heads = 1; xin = kin; xout = kout; id = idx - PAIRS_Q; }
    const int i = id & 31;
    const int h = (id >> 5) % heads;
    const int row = id / (32 * heads);
    const int pos = row & (S_ - 1);
    const float freq = expf(-9.210340371976184f * (float)i / 32.0f);
    const float ang = (float)pos * freq;
    const float c = cosf(ang), sn = sinf(ang);
    const float* p = xin + ((size_t)row * heads + h) * 64 + 2 * i;
    unsigned short* q = xout + ((size_t)row * heads + h) * 64 + 2 * i;
    const float x1 = p[0], x2 = p[1];
    q[0] = f2bf(x1 * c - x2 * sn);
    q[1] = f2bf(x1 * sn + x2 * c);
    return;
  }
  // ---- V transpose part ----
  const int u = blockIdx.x - ROPE_BLKS;          // 0..1023
  const int tid = threadIdx.x;
  const int k0 = (u & 31) * 64;
  const int h = (u >> 5) & 15;
  const int b = u >> 9;
  const size_t tok0 = (size_t)b * S_;
#pragma unroll
  for (int i = 0; i < 2; ++i) {
    const int uu = i * 256 + tid;
    const int kp = uu >> 4, c8 = uu & 15;
    const unsigned short* p0 =
        kv_up + (tok0 + k0 + 2 * kp) * (size_t)(H_ * 256) + h * 256 + NOPE_ + c8 * 8;
    union { uint4 v; unsigned short s[8]; } r0, r1;
    r0.v = *(const uint4*)p0;
    r1.v = *(const uint4*)(p0 + H_ * 256);
#pragma unroll
    for (int j = 0; j < 8; ++j)
      *(unsigned*)&T[(c8 * 8 + j) * 72 + 2 * kp] = (unsigned)r0.s[j] | ((unsigned)r1.s[j] << 16);
  }
  __syncthreads();
#pragma unroll
  for (int i = 0; i < 4; ++i) {
    const int sl = i * 256 + tid;
    const int f = sl >> 3, c = sl & 7;
    *(uint4*)(vt_g + ((size_t)(b * H_ + h) * 128 + f) * S_ + k0 + c * 8) =
        *(const uint4*)&T[f * 72 + c * 8];
  }
}

// ---------------------------------------------------------------------------
// MFMA flash attention (R6-verified: 97 us, FETCH 35 MB). Untouched.
// ---------------------------------------------------------------------------
#define LV 72    // Ps stride (64 + 8 pad)

__global__ __launch_bounds__(512) void flash_attn_mfma(const unsigned short* q_nope,
                                                       const unsigned short* __restrict__ q_pe,
                                                       const unsigned short* __restrict__ kv_up,
                                                       const unsigned short* __restrict__ k_rope,
                                                       const unsigned short* __restrict__ vt_g,
                                                       unsigned short* attn_o) {
  __shared__ unsigned short Ksn[2][128 * 16 * 8];  // 2 x 32 KB
  __shared__ unsigned short Ksr[2][128 * 8 * 8];   // 2 x 16 KB
  __shared__ unsigned short Vt[128 * 16 * 8];      //     32 KB
  __shared__ unsigned short Ps[128 * LV];          //     18 KB

  const int tid  = threadIdx.x;
  const int wave = tid >> 6;    // 0..7
  const int lane = tid & 63;
  const int quad = lane >> 4;
  const int l15  = lane & 15;
  const int l   = blockIdx.x + 8 * blockIdx.y + 128 * blockIdx.z;
  const int c_  = l & 7;
  const int m_  = l >> 3;
  const int pair = m_ & 7;
  const int hb   = c_ * 4 + (m_ >> 3);
  const int h  = hb & 15;
  const int b  = hb >> 4;
  const size_t tok0 = (size_t)b * S_;
  const float scale2 = 0.07216878364870323f * 1.4426950408889634f;
  const int qtA = 15 - pair;
  const int qtB = pair;
  const int nA  = qtA + 1;

  auto LOADQ = [&](short8* qf, int qt) {
    const size_t qrow = tok0 + qt * 128 + wave * 16 + l15;
    const unsigned short* pn = q_nope + qrow * (size_t)(H_ * NOPE_) + h * NOPE_;
    const unsigned short* pp = q_pe + qrow * (size_t)(H_ * ROPE_) + h * ROPE_;
#pragma unroll
    for (int s = 0; s < 4; ++s) qf[s] = *(const short8*)(pn + s * 32 + quad * 8);
#pragma unroll
    for (int s = 4; s < 6; ++s) qf[s] = *(const short8*)(pp + (s - 4) * 32 + quad * 8);
  };

  auto STAGE_K = [&](int bi, int kt) {
    const int k0 = kt * 128;
#pragma unroll
    for (int i = 0; i < 4; ++i) {
      const int sl = i * 512 + tid;
      const int key = sl >> 4;
      const int c = (sl & 15) ^ (key & 15);
      gl_lds16(kv_up + (tok0 + k0 + key) * (size_t)(H_ * 256) + h * 256 + c * 8,
               &Ksn[bi][(i * 512 + wave * 64) * 8]);
    }
#pragma unroll
    for (int i = 0; i < 2; ++i) {
      const int sl = i * 512 + tid;
      const int key = sl >> 3;
      const int c = (sl & 7) ^ (key & 7);
      gl_lds16(k_rope + (tok0 + k0 + key) * (size_t)ROPE_ + c * 8,
               &Ksr[bi][(i * 512 + wave * 64) * 8]);
    }
  };
  auto STAGE_V = [&](int kt) {
    const int k0 = kt * 128;
#pragma unroll
    for (int i = 0; i < 4; ++i) {
      const int sl = i * 512 + tid;
      const int f = sl >> 4;
      const int c = (sl & 15) ^ (f & 15);
      gl_lds16(vt_g + ((size_t)(b * H_ + h) * 128 + f) * S_ + k0 + c * 8,
               &Vt[(i * 512 + wave * 64) * 8]);
    }
  };

  short8 qf[6];
  LOADQ(qf, qtA);

  float m_st[4], l_st[4];
  f32x4 o[8];
#pragma unroll
  for (int r = 0; r < 4; ++r) { m_st[r] = -1e30f; l_st[r] = 0.f; }
#pragma unroll
  for (int nt = 0; nt < 8; ++nt) { f32x4 z = {0.f, 0.f, 0.f, 0.f}; o[nt] = z; }

  auto EPI = [&](int qt) {
    float invl[4];
#pragma unroll
    for (int r = 0; r < 4; ++r) invl[r] = 1.f / l_st[r];
#pragma unroll
    for (int nt = 0; nt < 8; ++nt)
#pragma unroll
      for (int r = 0; r < 4; ++r) {
        const size_t row = tok0 + qt * 128 + wave * 16 + quad * 4 + r;
        attn_o[row * (size_t)(H_ * VDIM_) + h * VDIM_ + nt * 16 + l15] =
            f2bf(o[nt][r] * invl[r]);
      }
  };

  STAGE_K(0, 0);

  for (int it = 0; it < 17; ++it) {
    const int cur = it & 1;
    const int nxt = cur ^ 1;
    const bool ph1 = (it >= nA);
    const int qt = ph1 ? qtB : qtA;
    const int kt = ph1 ? (it - nA) : it;
    const bool last = (it + 1 >= 17);

    __builtin_amdgcn_s_barrier();
    asm volatile("" ::: "memory");

    STAGE_V(kt);
    if (!last) {
      const int it2 = it + 1;
      const int kt2 = (it2 >= nA) ? (it2 - nA) : it2;
      STAGE_K(nxt, kt2);
      asm volatile("s_waitcnt vmcnt(10)" ::: "memory");
    } else {
      asm volatile("s_waitcnt vmcnt(4)" ::: "memory");
    }
    __builtin_amdgcn_s_barrier();
    asm volatile("" ::: "memory");
    __builtin_amdgcn_sched_barrier(0);

    f32x4 sacc[8];
#pragma unroll
    for (int nt = 0; nt < 8; ++nt) { f32x4 z = {0.f, 0.f, 0.f, 0.f}; sacc[nt] = z; }
    __builtin_amdgcn_s_setprio(1);
#pragma unroll
    for (int s = 0; s < 4; ++s) {
#pragma unroll
      for (int nt = 0; nt < 8; ++nt) {
        const int key = nt * 16 + l15;
        short8 kb = *(const short8*)&Ksn[cur][(key * 16 + ((s * 4 + quad) ^ (key & 15))) * 8];
        sacc[nt] = __builtin_amdgcn_mfma_f32_16x16x32_bf16(qf[s], kb, sacc[nt], 0, 0, 0);
      }
    }
#pragma unroll
    for (int s = 4; s < 6; ++s) {
#pragma unroll
      for (int nt = 0; nt < 8; ++nt) {
        const int key = nt * 16 + l15;
        short8 kb = *(const short8*)&Ksr[cur][(key * 8 + (((s - 4) * 4 + quad) ^ (key & 7))) * 8];
        sacc[nt] = __builtin_amdgcn_mfma_f32_16x16x32_bf16(qf[s], kb, sacc[nt], 0, 0, 0);
      }
    }
    __builtin_amdgcn_s_setprio(0);

    float sc[8][4];
#pragma unroll
    for (int nt = 0; nt < 8; ++nt)
#pragma unroll
      for (int r = 0; r < 4; ++r) sc[nt][r] = sacc[nt][r] * scale2;
    if (kt == qt) {
      const int rw = wave * 16 + quad * 4;
#pragma unroll
      for (int nt = 0; nt < 8; ++nt)
#pragma unroll
        for (int r = 0; r < 4; ++r)
          if ((nt * 16 + l15) > (rw + r)) sc[nt][r] = -1e30f;
    }

    float mt[4];
#pragma unroll
    for (int r = 0; r < 4; ++r) {
      float a0 = fmaxf(fmaxf(sc[0][r], sc[1][r]), fmaxf(sc[2][r], sc[3][r]));
      float a1 = fmaxf(fmaxf(sc[4][r], sc[5][r]), fmaxf(sc[6][r], sc[7][r]));
      mt[r] = fmaxf(a0, a1);
    }
#pragma unroll
    for (int mask = 1; mask <= 8; mask <<= 1)
#pragma unroll
      for (int r = 0; r < 4; ++r) mt[r] = fmaxf(mt[r], __shfl_xor(mt[r], mask, 64));

    float al[4], rs[4];
#pragma unroll
    for (int r = 0; r < 4; ++r) {
      const float mn = fmaxf(m_st[r], mt[r]);
      al[r] = exp2f(m_st[r] - mn);
      m_st[r] = mn;
      rs[r] = 0.f;
    }
#pragma unroll
    for (int nt = 0; nt < 8; ++nt)
#pragma unroll
      for (int r = 0; r < 4; ++r) {
        const float p = exp2f(sc[nt][r] - m_st[r]);
        sc[nt][r] = p;
        rs[r] += p;
      }
#pragma unroll
    for (int mask = 1; mask <= 8; mask <<= 1)
#pragma unroll
      for (int r = 0; r < 4; ++r) rs[r] += __shfl_xor(rs[r], mask, 64);
#pragma unroll
    for (int r = 0; r < 4; ++r) l_st[r] = l_st[r] * al[r] + rs[r];

#pragma unroll
    for (int nt = 0; nt < 4; ++nt)
#pragma unroll
      for (int r = 0; r < 4; ++r)
        Ps[(wave * 16 + quad * 4 + r) * LV + nt * 16 + l15] = f2bf(sc[nt][r]);
    __builtin_amdgcn_wave_barrier();

#pragma unroll
    for (int nt = 0; nt < 8; ++nt)
#pragma unroll
      for (int r = 0; r < 4; ++r) o[nt][r] *= al[r];

    if (!last) {
      asm volatile("s_waitcnt vmcnt(6)" ::: "memory");
    } else {
      asm volatile("s_waitcnt vmcnt(0)" ::: "memory");
    }
    __builtin_amdgcn_s_barrier();
    asm volatile("" ::: "memory");
    __builtin_amdgcn_sched_barrier(0);

    __builtin_amdgcn_s_setprio(1);
#pragma unroll
    for (int kb = 0; kb < 2; ++kb) {
      short8 pa = *(const short8*)&Ps[(wave * 16 + l15) * LV + kb * 32 + quad * 8];
#pragma unroll
      for (int nt = 0; nt < 8; ++nt) {
        const int f = nt * 16 + l15;
        short8 vb = *(const short8*)&Vt[(f * 16 + ((kb * 4 + quad) ^ (f & 15))) * 8];
        o[nt] = __builtin_amdgcn_mfma_f32_16x16x32_bf16(pa, vb, o[nt], 0, 0, 0);
      }
    }
    __builtin_amdgcn_s_setprio(0);

#pragma unroll
    for (int nt = 4; nt < 8; ++nt)
#pragma unroll
      for (int r = 0; r < 4; ++r)
        Ps[(wave * 16 + quad * 4 + r) * LV + (nt - 4) * 16 + l15] = f2bf(sc[nt][r]);
    __builtin_amdgcn_wave_barrier();

    __builtin_amdgcn_s_setprio(1);
#pragma unroll
    for (int kb = 2; kb < 4; ++kb) {
      short8 pa = *(const short8*)&Ps[(wave * 16 + l15) * LV + (kb - 2) * 32 + quad * 8];
#pragma unroll
      for (int nt = 0; nt < 8; ++nt) {
        const int f = nt * 16 + l15;
        short8 vb = *(const short8*)&Vt[(f * 16 + ((kb * 4 + quad) ^ (f & 15))) * 8];
        o[nt] = __builtin_amdgcn_mfma_f32_16x16x32_bf16(pa, vb, o[nt], 0, 0, 0);
      }
    }
    __builtin_amdgcn_s_setprio(0);

    if (it == nA - 1) {
      EPI(qtA);
      LOADQ(qf, qtB);
#pragma unroll
      for (int r = 0; r < 4; ++r) { m_st[r] = -1e30f; l_st[r] = 0.f; }
#pragma unroll
      for (int nt = 0; nt < 8; ++nt) { f32x4 z = {0.f, 0.f, 0.f, 0.f}; o[nt] = z; }
    }
  }

  EPI(qtB);
}

// ---------------------------------------------------------------------------
// Launch
// ---------------------------------------------------------------------------
extern "C" void kernel_launch(void* const* d_in, const int* in_sizes, int n_in,
                              void* d_out, int out_size, void* d_ws, size_t ws_size,
                              hipStream_t stream) {
  (void)in_sizes; (void)n_in;
  const float* x         = (const float*)d_in[0];
  const float* wq_down   = (const float*)d_in[1];
  const float* q_norm_w  = (const float*)d_in[2];
  const float* wq_up     = (const float*)d_in[3];
  const float* wq_rope   = (const float*)d_in[4];
  const float* wkv_down  = (const float*)d_in[5];
  const float* kv_norm_w = (const float*)d_in[6];
  const float* wkv_up    = (const float*)d_in[7];
  const float* wk_rope   = (const float*)d_in[8];
  const float* wo        = (const float*)d_in[9];
  float* out = (float*)d_out;

  // ---- workspace carve (identical layout to the passing run)
  const size_t SZ_XBF   = (size_t)TOK_ * DIM_ * 2;
  const size_t SZ_WQD   = (size_t)QR_ * DIM_ * 2;
  const size_t SZ_WKVD  = (size_t)KVR_ * DIM_ * 2;
  const size_t SZ_WKR   = (size_t)ROPE_ * DIM_ * 2;
  const size_t SZ_WQU   = (size_t)H_ * NOPE_ * QR_ * 2;
  const size_t SZ_WQR   = (size_t)H_ * ROPE_ * QR_ * 2;
  const size_t SZ_WKVU  = (size_t)H_ * (NOPE_ + VDIM_) * KVR_ * 2;
  const size_t SZ_WO    = (size_t)DIM_ * H_ * VDIM_ * 2;
  const size_t SZ_QC    = (size_t)TOK_ * QR_ * 4;   // aliases: q_pe fp32, then vt_g
  const size_t SZ_KVC   = (size_t)TOK_ * KVR_ * 4;
  const size_t SZ_QCN   = (size_t)TOK_ * QR_ * 2;
  const size_t SZ_KVCN  = (size_t)TOK_ * KVR_ * 2;
  const size_t SZ_QNOPE = (size_t)TOK_ * H_ * NOPE_ * 2; // aliases attn_o bf16
  const size_t SZ_QPEB  = (size_t)TOK_ * H_ * ROPE_ * 2;
  const size_t SZ_KRF   = (size_t)TOK_ * ROPE_ * 4;
  const size_t SZ_KRB   = (size_t)TOK_ * ROPE_ * 2;
  const size_t SZ_KVUP  = (size_t)TOK_ * H_ * (NOPE_ + VDIM_) * 2;
  const size_t NEED = SZ_XBF + SZ_WQD + SZ_WKVD + SZ_WKR + SZ_WQU + SZ_WQR + SZ_WKVU +
                      SZ_WO + SZ_QC + SZ_KVC + SZ_QCN + SZ_KVCN + SZ_QNOPE + SZ_QPEB +
                      SZ_KRF + SZ_KRB + SZ_KVUP;
  if (ws_size < NEED) {
    hipMemsetAsync(d_out, 0, (size_t)out_size * sizeof(float), stream);
    return;
  }
  char* p = (char*)d_ws;
  unsigned short* x_bf    = (unsigned short*)p; p += SZ_XBF;
  unsigned short* wqd_bf  = (unsigned short*)p; p += SZ_WQD;
  unsigned short* wkvd_bf = (unsigned short*)p; p += SZ_WKVD;
  unsigned short* wkr_bf  = (unsigned short*)p; p += SZ_WKR;
  unsigned short* wqu_bf  = (unsigned short*)p; p += SZ_WQU;
  unsigned short* wqr_bf  = (unsigned short*)p; p += SZ_WQR;
  unsigned short* wkvu_bf = (unsigned short*)p; p += SZ_WKVU;
  unsigned short* wo_bf   = (unsigned short*)p; p += SZ_WO;
  float*          q_c     = (float*)p;          p += SZ_QC;
  float*          kv_c    = (float*)p;          p += SZ_KVC;
  unsigned short* q_cn    = (unsigned short*)p; p += SZ_QCN;
  unsigned short* kv_cn   = (unsigned short*)p; p += SZ_KVCN;
  unsigned short* q_nope  = (unsigned short*)p; p += SZ_QNOPE;
  unsigned short* q_pe_bf = (unsigned short*)p; p += SZ_QPEB;
  float*          k_ropef = (float*)p;          p += SZ_KRF;
  unsigned short* k_ropeb = (unsigned short*)p; p += SZ_KRB;
  unsigned short* kv_upbf = (unsigned short*)p; p += SZ_KVUP;
  float*          q_pe_f  = q_c;                   // q_c dead after rmsnorm
  unsigned short* vt_g    = (unsigned short*)q_c;  // q_pe_f dead after rope
  unsigned short* attn_o  = q_nope;                // q_nope dead after flash

  const dim3 blk(256);

  // ---- all fp32->bf16 casts in ONE launch
  cvt_all<<<(C_TOT + 255) / 256, blk, 0, stream>>>(
      x, wq_down, wkv_down, wk_rope, wq_up, wq_rope, wkv_up, wo,
      x_bf, wqd_bf, wkvd_bf, wkr_bf, wqu_bf, wqr_bf, wkvu_bf, wo_bf);

  // ---- fused down projections (pipelined 128x256, XCD co-locate-by-m)
  gemm_down_p<<<dim3(7, TOK_ / 128), dim3(512), 0, stream>>>(x_bf, wqd_bf, wkvd_bf, wkr_bf,
                                                             q_c, kv_c, k_ropef);

  // ---- both RMSNorms in one launch
  rmsnorm2<<<dim3(TOK_, 2), blk, 0, stream>>>(q_c, q_norm_w, q_cn, kv_c, kv_norm_w, kv_cn);

  // ---- ALL up projections in one launch (q_nope | q_pe_f | kv_upbf)
  gemm_up_p<<<dim3(28, TOK_ / 128), dim3(512), 0, stream>>>(q_cn, kv_cn, wqu_bf, wqr_bf, wkvu_bf,
                                                            q_nope, q_pe_f, kv_upbf);

  // ---- RoPE (q+k) + V transpose merged into one launch
  rope_tr<<<ROPE_BLKS + TR_BLKS, blk, 0, stream>>>(q_pe_f, q_pe_bf, k_ropef, k_ropeb,
                                                   kv_upbf, vt_g);

  // ---- attention (8-wave blocks, 128-row q-tiles, 128-key K/V tiles)
  flash_attn_mfma<<<dim3(8, H_, B_), dim3(512), 0, stream>>>(q_nope, q_pe_bf, kv_upbf, k_ropeb, vt_g, attn_o);

  // ---- output projection (pipelined 128x256, XCD co-locate-by-m)
  gemm_out_p<<<dim3(8, TOK_ / 128), dim3(512), 0, stream>>>(attn_o, wo_bf, out);
}